// Round 1
// baseline (5596.383 us; speedup 1.0000x reference)
//
#include <hip/hip_runtime.h>
#include <hip/hip_bf16.h>

#define N_NODES 80000
#define N_EDGES 1280000
constexpr int DN = 128;   // node input dim
constexpr int DE = 32;    // edge input dim
constexpr int H  = 64;    // hidden
constexpr int H2 = 128;   // 2*hidden
constexpr float EPS_GEN = 1e-7f;
constexpr float EPS_BN  = 1e-5f;

__device__ __forceinline__ int rfl(int x) { return __builtin_amdgcn_readfirstlane(x); }

__device__ __forceinline__ void atomAddF(float* p, float v) {
  __hip_atomic_fetch_add(p, v, __ATOMIC_RELAXED, __HIP_MEMORY_SCOPE_AGENT);
}

// ---------------- edge encoder: ea[e,:] = edge_attr[e,:] @ W(32x64) + b ----------------
__global__ void k_edge_enc(const float* __restrict__ attr, const float* __restrict__ W,
                           const float* __restrict__ b, float* __restrict__ ea) {
  __shared__ float sW[DE * H];
  __shared__ float sb[H];
  for (int i = threadIdx.x; i < DE * H; i += blockDim.x) sW[i] = W[i];
  if (threadIdx.x < H) sb[threadIdx.x] = b[threadIdx.x];
  __syncthreads();
  int lane = threadIdx.x & 63;
  int wid  = (int)((blockIdx.x * blockDim.x + threadIdx.x) >> 6);
  int nw   = (int)((gridDim.x * blockDim.x) >> 6);
  for (int e = wid; e < N_EDGES; e += nw) {
    int eu = rfl(e);
    const float* arow = attr + (size_t)eu * DE;
    float acc = sb[lane];
#pragma unroll
    for (int k = 0; k < DE; ++k) acc = fmaf(arow[k], sW[k * H + lane], acc);
    ea[(size_t)eu * H + lane] = acc;
  }
}

// ---------------- node encoder: h[n,:] = x[n,:] @ W(128x64) + b ----------------
__global__ void k_node_enc(const float* __restrict__ x, const float* __restrict__ W,
                           const float* __restrict__ b, float* __restrict__ h) {
  __shared__ float sW[DN * H];   // 32 KB
  __shared__ float sb[H];
  for (int i = threadIdx.x; i < DN * H; i += blockDim.x) sW[i] = W[i];
  if (threadIdx.x < H) sb[threadIdx.x] = b[threadIdx.x];
  __syncthreads();
  int lane = threadIdx.x & 63;
  int wid  = (int)((blockIdx.x * blockDim.x + threadIdx.x) >> 6);
  int nw   = (int)((gridDim.x * blockDim.x) >> 6);
  for (int n = wid; n < N_NODES; n += nw) {
    int nu = rfl(n);
    const float* xrow = x + (size_t)nu * DN;
    float acc = sb[lane];
#pragma unroll 16
    for (int k = 0; k < DN; ++k) acc = fmaf(xrow[k], sW[k * H + lane], acc);
    h[(size_t)nu * H + lane] = acc;
  }
}

// ---------------- fused softmax-aggregation (single pass, no max shift) ----------------
// msg = relu(h[src]+ea)+eps; denom += exp(msg); numer += msg*exp(msg)
__global__ void k_agg(const float* __restrict__ h, const float* __restrict__ ea,
                      const int* __restrict__ src, const int* __restrict__ dst,
                      float* numer, float* denom) {
  int lane = threadIdx.x & 63;
  int wid  = (int)((blockIdx.x * blockDim.x + threadIdx.x) >> 6);
  int nw   = (int)((gridDim.x * blockDim.x) >> 6);
  for (int e = wid; e < N_EDGES; e += nw) {
    int eu = rfl(e);
    int s = src[eu];
    int d = dst[eu];
    float m = h[(size_t)s * H + lane] + ea[(size_t)eu * H + lane];
    m = fmaxf(m, 0.0f) + EPS_GEN;
    float ex = expf(m);
    atomAddF(&denom[(size_t)d * H + lane], ex);
    atomAddF(&numer[(size_t)d * H + lane], m * ex);
  }
}

// ---------------- h3[n,:] = (numer/denom + h)[n,:] @ W1(64x128) ----------------
__global__ void k_mlp1(const float* __restrict__ numer, const float* __restrict__ denom,
                       const float* __restrict__ h, const float* __restrict__ W1,
                       float* __restrict__ h3) {
  __shared__ float sW[H * H2];   // 32 KB
  for (int i = threadIdx.x; i < H * H2; i += blockDim.x) sW[i] = W1[i];
  __syncthreads();
  int lane = threadIdx.x & 63;
  int wid  = (int)((blockIdx.x * blockDim.x + threadIdx.x) >> 6);
  int nw   = (int)((gridDim.x * blockDim.x) >> 6);
  for (int n = wid; n < N_NODES; n += nw) {
    int nu = rfl(n);
    const float* nr = numer + (size_t)nu * H;
    const float* dr = denom + (size_t)nu * H;
    const float* hr = h + (size_t)nu * H;
    float a0 = 0.0f, a1 = 0.0f;
#pragma unroll 8
    for (int k = 0; k < H; ++k) {
      float h2v = nr[k] / (dr[k] + 1e-16f) + hr[k];
      a0 = fmaf(h2v, sW[k * H2 + lane], a0);
      a1 = fmaf(h2v, sW[k * H2 + 64 + lane], a1);
    }
    h3[(size_t)nu * H2 + lane] = a0;
    h3[(size_t)nu * H2 + 64 + lane] = a1;
  }
}

// ---------------- BN stats: per-feature sum and sumsq over N ----------------
__global__ void k_bnstats(const float* __restrict__ h3, float* sums) {
  int f = threadIdx.x & (H2 - 1);
  int half = threadIdx.x >> 7;   // block = 256 -> 2 rows in parallel
  float s = 0.0f, q = 0.0f;
  for (int n = blockIdx.x * 2 + half; n < N_NODES; n += gridDim.x * 2) {
    float v = h3[(size_t)n * H2 + f];
    s += v;
    q = fmaf(v, v, q);
  }
  __shared__ float sh[2][2][H2];
  sh[0][half][f] = s;
  sh[1][half][f] = q;
  __syncthreads();
  if (threadIdx.x < H2) {
    atomAddF(&sums[f], sh[0][0][f] + sh[0][1][f]);
    atomAddF(&sums[H2 + f], sh[1][0][f] + sh[1][1][f]);
  }
}

__global__ void k_bnfinal(const float* __restrict__ sums, float* __restrict__ musig) {
  int f = threadIdx.x;
  if (f < H2) {
    float mu  = sums[f] / (float)N_NODES;
    float var = sums[H2 + f] / (float)N_NODES - mu * mu;
    musig[f] = mu;
    musig[H2 + f] = 1.0f / sqrtf(var + EPS_BN);
  }
}

// ---------------- h_out = relu( relu(bn(h3)) @ W2(128x64) ) ----------------
__global__ void k_mlp2(const float* __restrict__ h3, const float* __restrict__ musig,
                       const float* __restrict__ g, const float* __restrict__ be,
                       const float* __restrict__ W2, float* __restrict__ hout) {
  __shared__ float sW[H2 * H];   // 32 KB
  __shared__ float ssc[H2], ssh[H2];
  for (int i = threadIdx.x; i < H2 * H; i += blockDim.x) sW[i] = W2[i];
  for (int i = threadIdx.x; i < H2; i += blockDim.x) {
    float rs = musig[H2 + i];
    float sc = rs * g[i];
    ssc[i] = sc;
    ssh[i] = be[i] - musig[i] * sc;
  }
  __syncthreads();
  int lane = threadIdx.x & 63;
  int wid  = (int)((blockIdx.x * blockDim.x + threadIdx.x) >> 6);
  int nw   = (int)((gridDim.x * blockDim.x) >> 6);
  for (int n = wid; n < N_NODES; n += nw) {
    int nu = rfl(n);
    const float* r = h3 + (size_t)nu * H2;
    float acc = 0.0f;
#pragma unroll 8
    for (int m = 0; m < H2; ++m) {
      float y = fmaxf(fmaf(r[m], ssc[m], ssh[m]), 0.0f);
      acc = fmaf(y, sW[m * H + lane], acc);
    }
    hout[(size_t)nu * H + lane] = fmaxf(acc, 0.0f);
  }
}

// ---------------- edge update: out[e,:] = concat(h[src],ea,h[dst]) @ lW(192xOC) + lb ----------------
template <int OC>
__global__ void k_edge_upd(const float* __restrict__ h, const float* ea,
                           const int* __restrict__ src, const int* __restrict__ dst,
                           const float* __restrict__ lW, const float* __restrict__ lb,
                           float* eout) {
  __shared__ float sW[3 * H * OC];
  __shared__ float sb[OC];
  for (int i = threadIdx.x; i < 3 * H * OC; i += blockDim.x) sW[i] = lW[i];
  if (threadIdx.x < OC) sb[threadIdx.x] = lb[threadIdx.x];
  __syncthreads();
  int lane = threadIdx.x & 63;
  int wid  = (int)((blockIdx.x * blockDim.x + threadIdx.x) >> 6);
  int nw   = (int)((gridDim.x * blockDim.x) >> 6);
  for (int e = wid; e < N_EDGES; e += nw) {
    int eu = rfl(e);
    int s = src[eu];
    int d = dst[eu];
    const float* hs = h + (size_t)s * H;
    const float* er = ea + (size_t)eu * H;
    const float* hd = h + (size_t)d * H;
    if constexpr (OC == 64) {
      float acc = sb[lane];
#pragma unroll 8
      for (int k = 0; k < H; ++k) acc = fmaf(hs[k], sW[k * 64 + lane], acc);
#pragma unroll 8
      for (int k = 0; k < H; ++k) acc = fmaf(er[k], sW[(64 + k) * 64 + lane], acc);
#pragma unroll 8
      for (int k = 0; k < H; ++k) acc = fmaf(hd[k], sW[(128 + k) * 64 + lane], acc);
      eout[(size_t)eu * 64 + lane] = acc;
    } else {
      // OC == 32: split k across the two half-waves, combine with shfl
      int col = lane & 31;
      int t   = lane >> 5;
      float acc = 0.0f;
#pragma unroll 8
      for (int i = 0; i < 32; ++i) {
        int k = t * 32 + i;
        acc = fmaf(hs[k], sW[k * 32 + col], acc);
        acc = fmaf(er[k], sW[(64 + k) * 32 + col], acc);
        acc = fmaf(hd[k], sW[(128 + k) * 32 + col], acc);
      }
      acc += __shfl_xor(acc, 32);
      if (t == 0) eout[(size_t)eu * 32 + col] = acc + sb[col];
    }
  }
}

extern "C" void kernel_launch(void* const* d_in, const int* in_sizes, int n_in,
                              void* d_out, int out_size, void* d_ws, size_t ws_size,
                              hipStream_t stream) {
  (void)in_sizes; (void)n_in; (void)out_size; (void)ws_size;
  const float* x      = (const float*)d_in[0];
  const int*   eidx   = (const int*)d_in[1];
  const float* eattr  = (const float*)d_in[2];
  const float* node_W = (const float*)d_in[3];
  const float* node_b = (const float*)d_in[4];
  const float* edge_W = (const float*)d_in[5];
  const float* edge_b = (const float*)d_in[6];
  const float* c1_W1  = (const float*)d_in[7];
  const float* c1_g   = (const float*)d_in[8];
  const float* c1_be  = (const float*)d_in[9];
  const float* c1_W2  = (const float*)d_in[10];
  const float* c2_W1  = (const float*)d_in[11];
  const float* c2_g   = (const float*)d_in[12];
  const float* c2_be  = (const float*)d_in[13];
  const float* c2_W2  = (const float*)d_in[14];
  const float* l1_W   = (const float*)d_in[15];
  const float* l1_b   = (const float*)d_in[16];
  const float* l2_W   = (const float*)d_in[17];
  const float* l2_b   = (const float*)d_in[18];

  const int* src = eidx;
  const int* dst = eidx + N_EDGES;

  float* ws = (float*)d_ws;
  size_t off = 0;
  float* ea    = ws + off; off += (size_t)N_EDGES * H;   // 81.92M
  float* hA    = ws + off; off += (size_t)N_NODES * H;
  float* hB    = ws + off; off += (size_t)N_NODES * H;
  float* numer = ws + off; off += (size_t)N_NODES * H;
  float* denom = ws + off; off += (size_t)N_NODES * H;
  float* h3    = ws + off; off += (size_t)N_NODES * H2;
  float* sums  = ws + off; off += 256;
  float* musig = ws + off; off += 256;

  float* h_out  = (float*)d_out;                            // [N,64]
  float* ea_out = (float*)d_out + (size_t)N_NODES * H;      // [E,32]

  k_edge_enc<<<2048, 256, 0, stream>>>(eattr, edge_W, edge_b, ea);
  k_node_enc<<<1024, 256, 0, stream>>>(x, node_W, node_b, hA);

  // ---- conv layer 1 ----
  hipMemsetAsync(numer, 0, (size_t)N_NODES * H * 4, stream);
  hipMemsetAsync(denom, 0, (size_t)N_NODES * H * 4, stream);
  hipMemsetAsync(sums, 0, 256 * 4, stream);
  k_agg<<<4096, 256, 0, stream>>>(hA, ea, src, dst, numer, denom);
  k_mlp1<<<1024, 256, 0, stream>>>(numer, denom, hA, c1_W1, h3);
  k_bnstats<<<1280, 256, 0, stream>>>(h3, sums);
  k_bnfinal<<<1, 128, 0, stream>>>(sums, musig);
  k_mlp2<<<1024, 256, 0, stream>>>(h3, musig, c1_g, c1_be, c1_W2, hB);
  k_edge_upd<64><<<4096, 256, 0, stream>>>(hB, ea, src, dst, l1_W, l1_b, ea);  // in-place, row-local

  // ---- conv layer 2 ----
  hipMemsetAsync(numer, 0, (size_t)N_NODES * H * 4, stream);
  hipMemsetAsync(denom, 0, (size_t)N_NODES * H * 4, stream);
  hipMemsetAsync(sums, 0, 256 * 4, stream);
  k_agg<<<4096, 256, 0, stream>>>(hB, ea, src, dst, numer, denom);
  k_mlp1<<<1024, 256, 0, stream>>>(numer, denom, hB, c2_W1, h3);
  k_bnstats<<<1280, 256, 0, stream>>>(h3, sums);
  k_bnfinal<<<1, 128, 0, stream>>>(sums, musig);
  k_mlp2<<<1024, 256, 0, stream>>>(h3, musig, c2_g, c2_be, c2_W2, h_out);
  k_edge_upd<32><<<4096, 256, 0, stream>>>(h_out, ea, src, dst, l2_W, l2_b, ea_out);
}

// Round 2
// 2506.991 us; speedup vs baseline: 2.2323x; 2.2323x over previous
//
#include <hip/hip_runtime.h>
#include <hip/hip_bf16.h>

#define N_NODES 80000
#define N_EDGES 1280000
constexpr int DN = 128;   // node input dim
constexpr int DE = 32;    // edge input dim
constexpr int H  = 64;    // hidden
constexpr int H2 = 128;   // 2*hidden
constexpr float EPS_GEN = 1e-7f;
constexpr float EPS_BN  = 1e-5f;

typedef _Float16 f16x8 __attribute__((ext_vector_type(8)));
typedef _Float16 f16x4 __attribute__((ext_vector_type(4)));
typedef float f32x4 __attribute__((ext_vector_type(4)));

__device__ __forceinline__ int rfl(int x) { return __builtin_amdgcn_readfirstlane(x); }

__device__ __forceinline__ void atomAddF(float* p, float v) {
  __hip_atomic_fetch_add(p, v, __ATOMIC_RELAXED, __HIP_MEMORY_SCOPE_AGENT);
}

// ---------------- edge encoder: ea[e,:] = edge_attr[e,:] @ W(32x64) + b ----------------
__global__ void k_edge_enc(const float* __restrict__ attr, const float* __restrict__ W,
                           const float* __restrict__ b, float* __restrict__ ea) {
  __shared__ float sW[DE * H];
  __shared__ float sb[H];
  for (int i = threadIdx.x; i < DE * H; i += blockDim.x) sW[i] = W[i];
  if (threadIdx.x < H) sb[threadIdx.x] = b[threadIdx.x];
  __syncthreads();
  int lane = threadIdx.x & 63;
  int wid  = (int)((blockIdx.x * blockDim.x + threadIdx.x) >> 6);
  int nw   = (int)((gridDim.x * blockDim.x) >> 6);
  for (int e = wid; e < N_EDGES; e += nw) {
    int eu = rfl(e);
    const float* arow = attr + (size_t)eu * DE;
    float acc = sb[lane];
#pragma unroll
    for (int k = 0; k < DE; ++k) acc = fmaf(arow[k], sW[k * H + lane], acc);
    ea[(size_t)eu * H + lane] = acc;
  }
}

// ---------------- node encoder: h[n,:] = x[n,:] @ W(128x64) + b ----------------
__global__ void k_node_enc(const float* __restrict__ x, const float* __restrict__ W,
                           const float* __restrict__ b, float* __restrict__ h) {
  __shared__ float sW[DN * H];   // 32 KB
  __shared__ float sb[H];
  for (int i = threadIdx.x; i < DN * H; i += blockDim.x) sW[i] = W[i];
  if (threadIdx.x < H) sb[threadIdx.x] = b[threadIdx.x];
  __syncthreads();
  int lane = threadIdx.x & 63;
  int wid  = (int)((blockIdx.x * blockDim.x + threadIdx.x) >> 6);
  int nw   = (int)((gridDim.x * blockDim.x) >> 6);
  for (int n = wid; n < N_NODES; n += nw) {
    int nu = rfl(n);
    const float* xrow = x + (size_t)nu * DN;
    float acc = sb[lane];
#pragma unroll 16
    for (int k = 0; k < DN; ++k) acc = fmaf(xrow[k], sW[k * H + lane], acc);
    h[(size_t)nu * H + lane] = acc;
  }
}

// ---------------- fused softmax-aggregation (single pass, no max shift) ----------------
// msg = relu(h[src]+ea)+eps; denom += exp(msg); numer += msg*exp(msg)
__global__ void k_agg(const float* __restrict__ h, const float* __restrict__ ea,
                      const int* __restrict__ src, const int* __restrict__ dst,
                      float* numer, float* denom) {
  int lane = threadIdx.x & 63;
  int wid  = (int)((blockIdx.x * blockDim.x + threadIdx.x) >> 6);
  int nw   = (int)((gridDim.x * blockDim.x) >> 6);
  for (int e = wid; e < N_EDGES; e += nw) {
    int eu = rfl(e);
    int s = src[eu];
    int d = dst[eu];
    float m = h[(size_t)s * H + lane] + ea[(size_t)eu * H + lane];
    m = fmaxf(m, 0.0f) + EPS_GEN;
    float ex = expf(m);
    atomAddF(&denom[(size_t)d * H + lane], ex);
    atomAddF(&numer[(size_t)d * H + lane], m * ex);
  }
}

// ---------------- h3[n,:] = (numer/denom + h)[n,:] @ W1(64x128) ----------------
__global__ void k_mlp1(const float* __restrict__ numer, const float* __restrict__ denom,
                       const float* __restrict__ h, const float* __restrict__ W1,
                       float* __restrict__ h3) {
  __shared__ float sW[H * H2];   // 32 KB
  for (int i = threadIdx.x; i < H * H2; i += blockDim.x) sW[i] = W1[i];
  __syncthreads();
  int lane = threadIdx.x & 63;
  int wid  = (int)((blockIdx.x * blockDim.x + threadIdx.x) >> 6);
  int nw   = (int)((gridDim.x * blockDim.x) >> 6);
  for (int n = wid; n < N_NODES; n += nw) {
    int nu = rfl(n);
    const float* nr = numer + (size_t)nu * H;
    const float* dr = denom + (size_t)nu * H;
    const float* hr = h + (size_t)nu * H;
    float a0 = 0.0f, a1 = 0.0f;
#pragma unroll 8
    for (int k = 0; k < H; ++k) {
      float h2v = nr[k] / (dr[k] + 1e-16f) + hr[k];
      a0 = fmaf(h2v, sW[k * H2 + lane], a0);
      a1 = fmaf(h2v, sW[k * H2 + 64 + lane], a1);
    }
    h3[(size_t)nu * H2 + lane] = a0;
    h3[(size_t)nu * H2 + 64 + lane] = a1;
  }
}

// ---------------- BN stats: per-feature sum and sumsq over N ----------------
__global__ void k_bnstats(const float* __restrict__ h3, float* sums) {
  int f = threadIdx.x & (H2 - 1);
  int half = threadIdx.x >> 7;   // block = 256 -> 2 rows in parallel
  float s = 0.0f, q = 0.0f;
  for (int n = blockIdx.x * 2 + half; n < N_NODES; n += gridDim.x * 2) {
    float v = h3[(size_t)n * H2 + f];
    s += v;
    q = fmaf(v, v, q);
  }
  __shared__ float sh[2][2][H2];
  sh[0][half][f] = s;
  sh[1][half][f] = q;
  __syncthreads();
  if (threadIdx.x < H2) {
    atomAddF(&sums[f], sh[0][0][f] + sh[0][1][f]);
    atomAddF(&sums[H2 + f], sh[1][0][f] + sh[1][1][f]);
  }
}

__global__ void k_bnfinal(const float* __restrict__ sums, float* __restrict__ musig) {
  int f = threadIdx.x;
  if (f < H2) {
    float mu  = sums[f] / (float)N_NODES;
    float var = sums[H2 + f] / (float)N_NODES - mu * mu;
    musig[f] = mu;
    musig[H2 + f] = 1.0f / sqrtf(var + EPS_BN);
  }
}

// ---------------- h_out = relu( relu(bn(h3)) @ W2(128x64) ) ----------------
__global__ void k_mlp2(const float* __restrict__ h3, const float* __restrict__ musig,
                       const float* __restrict__ g, const float* __restrict__ be,
                       const float* __restrict__ W2, float* __restrict__ hout) {
  __shared__ float sW[H2 * H];   // 32 KB
  __shared__ float ssc[H2], ssh[H2];
  for (int i = threadIdx.x; i < H2 * H; i += blockDim.x) sW[i] = W2[i];
  for (int i = threadIdx.x; i < H2; i += blockDim.x) {
    float rs = musig[H2 + i];
    float sc = rs * g[i];
    ssc[i] = sc;
    ssh[i] = be[i] - musig[i] * sc;
  }
  __syncthreads();
  int lane = threadIdx.x & 63;
  int wid  = (int)((blockIdx.x * blockDim.x + threadIdx.x) >> 6);
  int nw   = (int)((gridDim.x * blockDim.x) >> 6);
  for (int n = wid; n < N_NODES; n += nw) {
    int nu = rfl(n);
    const float* r = h3 + (size_t)nu * H2;
    float acc = 0.0f;
#pragma unroll 8
    for (int m = 0; m < H2; ++m) {
      float y = fmaxf(fmaf(r[m], ssc[m], ssh[m]), 0.0f);
      acc = fmaf(y, sW[m * H + lane], acc);
    }
    hout[(size_t)nu * H + lane] = fmaxf(acc, 0.0f);
  }
}

// ---------------- edge update via MFMA (fp16 inputs, f32 accum) ----------------
// out[e,:] = concat(h[src],ea,h[dst]) @ lW(192xOC) + lb
// Tile: 64 edges/block, 256 threads (4 waves x 16 edges).
// A in LDS: [64][200] fp16 (pad 200 -> 2-way max bank aliasing = free)
// B in LDS: transposed [OC][200] fp16 so B-frags are contiguous b128 reads.
template <int OC>
__global__ __launch_bounds__(256) void k_edge_upd_mfma(
    const float* __restrict__ h, const float* __restrict__ ea,
    const int* __restrict__ src, const int* __restrict__ dst,
    const float* __restrict__ lW, const float* __restrict__ lb,
    float* __restrict__ eout) {
  constexpr int RP = 200;                 // padded row length in halves
  __shared__ _Float16 sA[64 * RP];        // 25600 B
  __shared__ _Float16 sB[OC * RP];        // OC=64: 25600 B, OC=32: 12800 B
  __shared__ int2 sSD[64];

  const int tid  = threadIdx.x;
  const int ebase = blockIdx.x * 64;

  if (tid < 64) sSD[tid] = make_int2(src[ebase + tid], dst[ebase + tid]);
  __syncthreads();

  // ---- stage weights (transposed) ----
  for (int idx = tid; idx < 192 * OC; idx += 256) {
    int k = idx / OC, n = idx % OC;
    sB[n * RP + k] = (_Float16)lW[idx];
  }

  // ---- gather A: 64 edges x 192 cols; seg-units su = edge*3+seg ----
  const int wv = tid >> 6, lane = tid & 63;
  const int part = lane & 15, u = lane >> 4;   // 16 lanes per seg-unit
  float4 v[12];
#pragma unroll
  for (int it = 0; it < 12; ++it) {
    int su = wv * 48 + it * 4 + u;       // 0..191
    int el = su / 3;                     // local edge 0..63
    int sg = su % 3;                     // 0: h[src] 1: ea[e] 2: h[dst]
    int2 sd = sSD[el];
    const float* base = (sg == 0) ? (h + (size_t)sd.x * H)
                      : (sg == 1) ? (ea + (size_t)(ebase + el) * H)
                                  : (h + (size_t)sd.y * H);
    v[it] = *(const float4*)(base + part * 4);
  }
#pragma unroll
  for (int it = 0; it < 12; ++it) {
    int su = wv * 48 + it * 4 + u;
    int el = su / 3;
    int sg = su % 3;
    f16x4 hv = { (_Float16)v[it].x, (_Float16)v[it].y, (_Float16)v[it].z, (_Float16)v[it].w };
    *(f16x4*)&sA[el * RP + sg * 64 + part * 4] = hv;
  }
  __syncthreads();

  // ---- MFMA: wave wv computes edges [wv*16, wv*16+16) x OC ----
  const int m16 = lane & 15;    // A-row / B-col / D-col
  const int kg  = lane >> 4;    // k-group
  constexpr int NF = OC / 16;
  f32x4 acc[NF];
#pragma unroll
  for (int n2 = 0; n2 < NF; ++n2) {
    float bv = lb[n2 * 16 + m16];
    acc[n2] = (f32x4){bv, bv, bv, bv};
  }
#pragma unroll
  for (int kk = 0; kk < 6; ++kk) {
    int k0 = kk * 32 + kg * 8;
    f16x8 a = *(const f16x8*)&sA[(wv * 16 + m16) * RP + k0];
#pragma unroll
    for (int n2 = 0; n2 < NF; ++n2) {
      f16x8 b = *(const f16x8*)&sB[(n2 * 16 + m16) * RP + k0];
      acc[n2] = __builtin_amdgcn_mfma_f32_16x16x32_f16(a, b, acc[n2], 0, 0, 0);
    }
  }

  // ---- store: D[row][col], col = lane&15, row = (lane>>4)*4 + r ----
#pragma unroll
  for (int n2 = 0; n2 < NF; ++n2) {
#pragma unroll
    for (int r = 0; r < 4; ++r) {
      int row = wv * 16 + kg * 4 + r;
      int col = n2 * 16 + m16;
      eout[(size_t)(ebase + row) * OC + col] = acc[n2][r];
    }
  }
}

extern "C" void kernel_launch(void* const* d_in, const int* in_sizes, int n_in,
                              void* d_out, int out_size, void* d_ws, size_t ws_size,
                              hipStream_t stream) {
  (void)in_sizes; (void)n_in; (void)out_size; (void)ws_size;
  const float* x      = (const float*)d_in[0];
  const int*   eidx   = (const int*)d_in[1];
  const float* eattr  = (const float*)d_in[2];
  const float* node_W = (const float*)d_in[3];
  const float* node_b = (const float*)d_in[4];
  const float* edge_W = (const float*)d_in[5];
  const float* edge_b = (const float*)d_in[6];
  const float* c1_W1  = (const float*)d_in[7];
  const float* c1_g   = (const float*)d_in[8];
  const float* c1_be  = (const float*)d_in[9];
  const float* c1_W2  = (const float*)d_in[10];
  const float* c2_W1  = (const float*)d_in[11];
  const float* c2_g   = (const float*)d_in[12];
  const float* c2_be  = (const float*)d_in[13];
  const float* c2_W2  = (const float*)d_in[14];
  const float* l1_W   = (const float*)d_in[15];
  const float* l1_b   = (const float*)d_in[16];
  const float* l2_W   = (const float*)d_in[17];
  const float* l2_b   = (const float*)d_in[18];

  const int* src = eidx;
  const int* dst = eidx + N_EDGES;

  float* ws = (float*)d_ws;
  size_t off = 0;
  float* ea    = ws + off; off += (size_t)N_EDGES * H;   // 81.92M
  float* hA    = ws + off; off += (size_t)N_NODES * H;
  float* hB    = ws + off; off += (size_t)N_NODES * H;
  float* numer = ws + off; off += (size_t)N_NODES * H;
  float* denom = ws + off; off += (size_t)N_NODES * H;
  float* h3    = ws + off; off += (size_t)N_NODES * H2;
  float* sums  = ws + off; off += 256;
  float* musig = ws + off; off += 256;

  float* h_out  = (float*)d_out;                            // [N,64]
  float* ea_out = (float*)d_out + (size_t)N_NODES * H;      // [E,32]

  k_edge_enc<<<2048, 256, 0, stream>>>(eattr, edge_W, edge_b, ea);
  k_node_enc<<<1024, 256, 0, stream>>>(x, node_W, node_b, hA);

  // ---- conv layer 1 ----
  hipMemsetAsync(numer, 0, (size_t)N_NODES * H * 4, stream);
  hipMemsetAsync(denom, 0, (size_t)N_NODES * H * 4, stream);
  hipMemsetAsync(sums, 0, 256 * 4, stream);
  k_agg<<<4096, 256, 0, stream>>>(hA, ea, src, dst, numer, denom);
  k_mlp1<<<1024, 256, 0, stream>>>(numer, denom, hA, c1_W1, h3);
  k_bnstats<<<1280, 256, 0, stream>>>(h3, sums);
  k_bnfinal<<<1, 128, 0, stream>>>(sums, musig);
  k_mlp2<<<1024, 256, 0, stream>>>(h3, musig, c1_g, c1_be, c1_W2, hB);
  k_edge_upd_mfma<64><<<N_EDGES / 64, 256, 0, stream>>>(hB, ea, src, dst, l1_W, l1_b, ea);  // in-place, row-local

  // ---- conv layer 2 ----
  hipMemsetAsync(numer, 0, (size_t)N_NODES * H * 4, stream);
  hipMemsetAsync(denom, 0, (size_t)N_NODES * H * 4, stream);
  hipMemsetAsync(sums, 0, 256 * 4, stream);
  k_agg<<<4096, 256, 0, stream>>>(hB, ea, src, dst, numer, denom);
  k_mlp1<<<1024, 256, 0, stream>>>(numer, denom, hB, c2_W1, h3);
  k_bnstats<<<1280, 256, 0, stream>>>(h3, sums);
  k_bnfinal<<<1, 128, 0, stream>>>(sums, musig);
  k_mlp2<<<1024, 256, 0, stream>>>(h3, musig, c2_g, c2_be, c2_W2, h_out);
  k_edge_upd_mfma<32><<<N_EDGES / 64, 256, 0, stream>>>(h_out, ea, src, dst, l2_W, l2_b, ea_out);
}

// Round 3
// 1669.281 us; speedup vs baseline: 3.3526x; 1.5018x over previous
//
#include <hip/hip_runtime.h>
#include <hip/hip_bf16.h>

#define N_NODES 80000
#define N_EDGES 1280000
constexpr int DN = 128;   // node input dim
constexpr int DE = 32;    // edge input dim
constexpr int H  = 64;    // hidden
constexpr int H2 = 128;   // 2*hidden
constexpr float EPS_GEN = 1e-7f;
constexpr float EPS_BN  = 1e-5f;

typedef _Float16 f16x8 __attribute__((ext_vector_type(8)));
typedef _Float16 f16x4 __attribute__((ext_vector_type(4)));
typedef float f32x4 __attribute__((ext_vector_type(4)));

__device__ __forceinline__ int rfl(int x) { return __builtin_amdgcn_readfirstlane(x); }

__device__ __forceinline__ void atomAddF(float* p, float v) {
  __hip_atomic_fetch_add(p, v, __ATOMIC_RELAXED, __HIP_MEMORY_SCOPE_AGENT);
}

// ---------------- edge encoder: ea[e,:] = edge_attr[e,:] @ W(32x64) + b ----------------
__global__ void k_edge_enc(const float* __restrict__ attr, const float* __restrict__ W,
                           const float* __restrict__ b, float* __restrict__ ea) {
  __shared__ float sW[DE * H];
  __shared__ float sb[H];
  for (int i = threadIdx.x; i < DE * H; i += blockDim.x) sW[i] = W[i];
  if (threadIdx.x < H) sb[threadIdx.x] = b[threadIdx.x];
  __syncthreads();
  int lane = threadIdx.x & 63;
  int wid  = (int)((blockIdx.x * blockDim.x + threadIdx.x) >> 6);
  int nw   = (int)((gridDim.x * blockDim.x) >> 6);
  for (int e = wid; e < N_EDGES; e += nw) {
    int eu = rfl(e);
    const float* arow = attr + (size_t)eu * DE;
    float acc = sb[lane];
#pragma unroll
    for (int k = 0; k < DE; ++k) acc = fmaf(arow[k], sW[k * H + lane], acc);
    ea[(size_t)eu * H + lane] = acc;
  }
}

// ---------------- node encoder: h[n,:] = x[n,:] @ W(128x64) + b ----------------
__global__ void k_node_enc(const float* __restrict__ x, const float* __restrict__ W,
                           const float* __restrict__ b, float* __restrict__ h) {
  __shared__ float sW[DN * H];   // 32 KB
  __shared__ float sb[H];
  for (int i = threadIdx.x; i < DN * H; i += blockDim.x) sW[i] = W[i];
  if (threadIdx.x < H) sb[threadIdx.x] = b[threadIdx.x];
  __syncthreads();
  int lane = threadIdx.x & 63;
  int wid  = (int)((blockIdx.x * blockDim.x + threadIdx.x) >> 6);
  int nw   = (int)((gridDim.x * blockDim.x) >> 6);
  for (int n = wid; n < N_NODES; n += nw) {
    int nu = rfl(n);
    const float* xrow = x + (size_t)nu * DN;
    float acc = sb[lane];
#pragma unroll 16
    for (int k = 0; k < DN; ++k) acc = fmaf(xrow[k], sW[k * H + lane], acc);
    h[(size_t)nu * H + lane] = acc;
  }
}

// ---------------- CSR build: histogram -> scan -> scatter ----------------
__global__ void k_hist(const int* __restrict__ dst, int* cnt) {
  int e = blockIdx.x * blockDim.x + threadIdx.x;
  if (e < N_EDGES) atomicAdd(&cnt[dst[e]], 1);
}

__global__ void k_scan_blk(const int* __restrict__ cnt, int* __restrict__ bsum) {
  __shared__ int sh[256];
  int i = blockIdx.x * 256 + threadIdx.x;
  sh[threadIdx.x] = (i < N_NODES) ? cnt[i] : 0;
  __syncthreads();
  for (int s = 128; s > 0; s >>= 1) {
    if (threadIdx.x < s) sh[threadIdx.x] += sh[threadIdx.x + s];
    __syncthreads();
  }
  if (threadIdx.x == 0) bsum[blockIdx.x] = sh[0];
}

__global__ void k_scan_top(int* bsum, int nb) {  // 1 block x 512, exclusive scan
  __shared__ int sh[512];
  int t = threadIdx.x;
  int orig = (t < nb) ? bsum[t] : 0;
  sh[t] = orig;
  __syncthreads();
  for (int off = 1; off < 512; off <<= 1) {
    int v = (t >= off) ? sh[t - off] : 0;
    __syncthreads();
    sh[t] += v;
    __syncthreads();
  }
  if (t < nb) bsum[t] = sh[t] - orig;
}

__global__ void k_scan_fin(const int* __restrict__ cnt, const int* __restrict__ bsum,
                           int* __restrict__ start, int* __restrict__ cursor) {
  __shared__ int sh[256];
  int i = blockIdx.x * 256 + threadIdx.x;
  int t = threadIdx.x;
  int orig = (i < N_NODES) ? cnt[i] : 0;
  sh[t] = orig;
  __syncthreads();
  for (int off = 1; off < 256; off <<= 1) {
    int v = (t >= off) ? sh[t - off] : 0;
    __syncthreads();
    sh[t] += v;
    __syncthreads();
  }
  if (i < N_NODES) {
    int st = bsum[blockIdx.x] + sh[t] - orig;
    start[i] = st;
    cursor[i] = st;
  }
}

__global__ void k_scatter(const int* __restrict__ src, const int* __restrict__ dst,
                          int* cursor, int2* __restrict__ eids) {
  int e = blockIdx.x * blockDim.x + threadIdx.x;
  if (e < N_EDGES) {
    int pos = atomicAdd(&cursor[dst[e]], 1);
    eids[pos] = make_int2(e, src[e]);
  }
}

// ---------------- CSR softmax-aggregation: one wave per node ----------------
// hsum[n,:] = (sum_e m*e^m) / (sum_e e^m + 1e-16) + h[n,:],  m = relu(h[src]+ea)+eps
__global__ __launch_bounds__(256) void k_agg_csr(
    const float* __restrict__ h, const float* __restrict__ ea,
    const int2* __restrict__ eids, const int* __restrict__ start,
    const int* __restrict__ cnt, float* __restrict__ hsum) {
  int lane = threadIdx.x & 63;
  int wid  = (int)((blockIdx.x * blockDim.x + threadIdx.x) >> 6);
  if (wid >= N_NODES) return;
  int s0 = start[wid], c = cnt[wid];
  float num = 0.0f, den = 0.0f;
  int2 es = (c > 0) ? eids[s0] : make_int2(0, 0);
  for (int i = 0; i < c; ++i) {
    int2 cur = es;
    if (i + 1 < c) es = eids[s0 + i + 1];   // prefetch next edge id
    float m = h[(size_t)cur.y * H + lane] + ea[(size_t)cur.x * H + lane];
    m = fmaxf(m, 0.0f) + EPS_GEN;
    float ex = expf(m);
    num = fmaf(m, ex, num);
    den += ex;
  }
  hsum[(size_t)wid * H + lane] = num / (den + 1e-16f) + h[(size_t)wid * H + lane];
}

// ---------------- h3[n,:] = hsum[n,:] @ W1(64x128) ----------------
__global__ void k_mlp1(const float* __restrict__ hsum, const float* __restrict__ W1,
                       float* __restrict__ h3) {
  __shared__ float sW[H * H2];   // 32 KB
  for (int i = threadIdx.x; i < H * H2; i += blockDim.x) sW[i] = W1[i];
  __syncthreads();
  int lane = threadIdx.x & 63;
  int wid  = (int)((blockIdx.x * blockDim.x + threadIdx.x) >> 6);
  int nw   = (int)((gridDim.x * blockDim.x) >> 6);
  for (int n = wid; n < N_NODES; n += nw) {
    int nu = rfl(n);
    const float* hr = hsum + (size_t)nu * H;
    float a0 = 0.0f, a1 = 0.0f;
#pragma unroll 8
    for (int k = 0; k < H; ++k) {
      float h2v = hr[k];
      a0 = fmaf(h2v, sW[k * H2 + lane], a0);
      a1 = fmaf(h2v, sW[k * H2 + 64 + lane], a1);
    }
    h3[(size_t)nu * H2 + lane] = a0;
    h3[(size_t)nu * H2 + 64 + lane] = a1;
  }
}

// ---------------- BN stats: per-feature sum and sumsq over N ----------------
__global__ void k_bnstats(const float* __restrict__ h3, float* sums) {
  int f = threadIdx.x & (H2 - 1);
  int half = threadIdx.x >> 7;   // block = 256 -> 2 rows in parallel
  float s = 0.0f, q = 0.0f;
  for (int n = blockIdx.x * 2 + half; n < N_NODES; n += gridDim.x * 2) {
    float v = h3[(size_t)n * H2 + f];
    s += v;
    q = fmaf(v, v, q);
  }
  __shared__ float sh[2][2][H2];
  sh[0][half][f] = s;
  sh[1][half][f] = q;
  __syncthreads();
  if (threadIdx.x < H2) {
    atomAddF(&sums[f], sh[0][0][f] + sh[0][1][f]);
    atomAddF(&sums[H2 + f], sh[1][0][f] + sh[1][1][f]);
  }
}

__global__ void k_bnfinal(const float* __restrict__ sums, float* __restrict__ musig) {
  int f = threadIdx.x;
  if (f < H2) {
    float mu  = sums[f] / (float)N_NODES;
    float var = sums[H2 + f] / (float)N_NODES - mu * mu;
    musig[f] = mu;
    musig[H2 + f] = 1.0f / sqrtf(var + EPS_BN);
  }
}

// ---------------- h_out = relu( relu(bn(h3)) @ W2(128x64) ) ----------------
__global__ void k_mlp2(const float* __restrict__ h3, const float* __restrict__ musig,
                       const float* __restrict__ g, const float* __restrict__ be,
                       const float* __restrict__ W2, float* __restrict__ hout) {
  __shared__ float sW[H2 * H];   // 32 KB
  __shared__ float ssc[H2], ssh[H2];
  for (int i = threadIdx.x; i < H2 * H; i += blockDim.x) sW[i] = W2[i];
  for (int i = threadIdx.x; i < H2; i += blockDim.x) {
    float rs = musig[H2 + i];
    float sc = rs * g[i];
    ssc[i] = sc;
    ssh[i] = be[i] - musig[i] * sc;
  }
  __syncthreads();
  int lane = threadIdx.x & 63;
  int wid  = (int)((blockIdx.x * blockDim.x + threadIdx.x) >> 6);
  int nw   = (int)((gridDim.x * blockDim.x) >> 6);
  for (int n = wid; n < N_NODES; n += nw) {
    int nu = rfl(n);
    const float* r = h3 + (size_t)nu * H2;
    float acc = 0.0f;
#pragma unroll 8
    for (int m = 0; m < H2; ++m) {
      float y = fmaxf(fmaf(r[m], ssc[m], ssh[m]), 0.0f);
      acc = fmaf(y, sW[m * H + lane], acc);
    }
    hout[(size_t)nu * H + lane] = fmaxf(acc, 0.0f);
  }
}

// ---------------- edge update via MFMA (fp16 inputs, f32 accum) ----------------
template <int OC>
__global__ __launch_bounds__(256) void k_edge_upd_mfma(
    const float* __restrict__ h, const float* __restrict__ ea,
    const int* __restrict__ src, const int* __restrict__ dst,
    const float* __restrict__ lW, const float* __restrict__ lb,
    float* __restrict__ eout) {
  constexpr int RP = 200;                 // padded row length in halves
  __shared__ _Float16 sA[64 * RP];        // 25600 B
  __shared__ _Float16 sB[OC * RP];        // OC=64: 25600 B, OC=32: 12800 B
  __shared__ int2 sSD[64];

  const int tid  = threadIdx.x;
  const int ebase = blockIdx.x * 64;

  if (tid < 64) sSD[tid] = make_int2(src[ebase + tid], dst[ebase + tid]);
  __syncthreads();

  // ---- stage weights (transposed) ----
  for (int idx = tid; idx < 192 * OC; idx += 256) {
    int k = idx / OC, n = idx % OC;
    sB[n * RP + k] = (_Float16)lW[idx];
  }

  // ---- gather A: 64 edges x 192 cols; seg-units su = edge*3+seg ----
  const int wv = tid >> 6, lane = tid & 63;
  const int part = lane & 15, u = lane >> 4;   // 16 lanes per seg-unit
  float4 v[12];
#pragma unroll
  for (int it = 0; it < 12; ++it) {
    int su = wv * 48 + it * 4 + u;       // 0..191
    int el = su / 3;                     // local edge 0..63
    int sg = su % 3;                     // 0: h[src] 1: ea[e] 2: h[dst]
    int2 sd = sSD[el];
    const float* base = (sg == 0) ? (h + (size_t)sd.x * H)
                      : (sg == 1) ? (ea + (size_t)(ebase + el) * H)
                                  : (h + (size_t)sd.y * H);
    v[it] = *(const float4*)(base + part * 4);
  }
#pragma unroll
  for (int it = 0; it < 12; ++it) {
    int su = wv * 48 + it * 4 + u;
    int el = su / 3;
    int sg = su % 3;
    f16x4 hv = { (_Float16)v[it].x, (_Float16)v[it].y, (_Float16)v[it].z, (_Float16)v[it].w };
    *(f16x4*)&sA[el * RP + sg * 64 + part * 4] = hv;
  }
  __syncthreads();

  // ---- MFMA: wave wv computes edges [wv*16, wv*16+16) x OC ----
  const int m16 = lane & 15;    // A-row / B-col / D-col
  const int kg  = lane >> 4;    // k-group
  constexpr int NF = OC / 16;
  f32x4 acc[NF];
#pragma unroll
  for (int n2 = 0; n2 < NF; ++n2) {
    float bv = lb[n2 * 16 + m16];
    acc[n2] = (f32x4){bv, bv, bv, bv};
  }
#pragma unroll
  for (int kk = 0; kk < 6; ++kk) {
    int k0 = kk * 32 + kg * 8;
    f16x8 a = *(const f16x8*)&sA[(wv * 16 + m16) * RP + k0];
#pragma unroll
    for (int n2 = 0; n2 < NF; ++n2) {
      f16x8 b = *(const f16x8*)&sB[(n2 * 16 + m16) * RP + k0];
      acc[n2] = __builtin_amdgcn_mfma_f32_16x16x32_f16(a, b, acc[n2], 0, 0, 0);
    }
  }

  // ---- store: D[row][col], col = lane&15, row = (lane>>4)*4 + r ----
#pragma unroll
  for (int n2 = 0; n2 < NF; ++n2) {
#pragma unroll
    for (int r = 0; r < 4; ++r) {
      int row = wv * 16 + kg * 4 + r;
      int col = n2 * 16 + m16;
      eout[(size_t)(ebase + row) * OC + col] = acc[n2][r];
    }
  }
}

extern "C" void kernel_launch(void* const* d_in, const int* in_sizes, int n_in,
                              void* d_out, int out_size, void* d_ws, size_t ws_size,
                              hipStream_t stream) {
  (void)in_sizes; (void)n_in; (void)out_size; (void)ws_size;
  const float* x      = (const float*)d_in[0];
  const int*   eidx   = (const int*)d_in[1];
  const float* eattr  = (const float*)d_in[2];
  const float* node_W = (const float*)d_in[3];
  const float* node_b = (const float*)d_in[4];
  const float* edge_W = (const float*)d_in[5];
  const float* edge_b = (const float*)d_in[6];
  const float* c1_W1  = (const float*)d_in[7];
  const float* c1_g   = (const float*)d_in[8];
  const float* c1_be  = (const float*)d_in[9];
  const float* c1_W2  = (const float*)d_in[10];
  const float* c2_W1  = (const float*)d_in[11];
  const float* c2_g   = (const float*)d_in[12];
  const float* c2_be  = (const float*)d_in[13];
  const float* c2_W2  = (const float*)d_in[14];
  const float* l1_W   = (const float*)d_in[15];
  const float* l1_b   = (const float*)d_in[16];
  const float* l2_W   = (const float*)d_in[17];
  const float* l2_b   = (const float*)d_in[18];

  const int* src = eidx;
  const int* dst = eidx + N_EDGES;

  float* ws = (float*)d_ws;
  size_t off = 0;
  float* ea    = ws + off; off += (size_t)N_EDGES * H;   // 81.92M floats
  float* hA    = ws + off; off += (size_t)N_NODES * H;
  float* hB    = ws + off; off += (size_t)N_NODES * H;
  float* hsum  = ws + off; off += (size_t)N_NODES * H;
  float* h3    = ws + off; off += (size_t)N_NODES * H2;
  float* sums  = ws + off; off += 256;
  float* musig = ws + off; off += 256;
  int* cnt     = (int*)(ws + off); off += N_NODES;
  int* startA  = (int*)(ws + off); off += N_NODES;
  int* cursor  = (int*)(ws + off); off += N_NODES;
  int* bsum    = (int*)(ws + off); off += 512;
  int2* eids   = (int2*)(ws + off); off += (size_t)N_EDGES * 2;

  float* h_out  = (float*)d_out;                            // [N,64]
  float* ea_out = (float*)d_out + (size_t)N_NODES * H;      // [E,32]

  constexpr int NB = (N_NODES + 255) / 256;                 // 313 scan blocks

  k_edge_enc<<<2048, 256, 0, stream>>>(eattr, edge_W, edge_b, ea);
  k_node_enc<<<1024, 256, 0, stream>>>(x, node_W, node_b, hA);

  // ---- build CSR once (shared by both conv layers) ----
  hipMemsetAsync(cnt, 0, N_NODES * 4, stream);
  k_hist<<<(N_EDGES + 255) / 256, 256, 0, stream>>>(dst, cnt);
  k_scan_blk<<<NB, 256, 0, stream>>>(cnt, bsum);
  k_scan_top<<<1, 512, 0, stream>>>(bsum, NB);
  k_scan_fin<<<NB, 256, 0, stream>>>(cnt, bsum, startA, cursor);
  k_scatter<<<(N_EDGES + 255) / 256, 256, 0, stream>>>(src, dst, cursor, eids);

  // ---- conv layer 1 ----
  hipMemsetAsync(sums, 0, 256 * 4, stream);
  k_agg_csr<<<(N_NODES * 64 + 255) / 256, 256, 0, stream>>>(hA, ea, eids, startA, cnt, hsum);
  k_mlp1<<<1024, 256, 0, stream>>>(hsum, c1_W1, h3);
  k_bnstats<<<1280, 256, 0, stream>>>(h3, sums);
  k_bnfinal<<<1, 128, 0, stream>>>(sums, musig);
  k_mlp2<<<1024, 256, 0, stream>>>(h3, musig, c1_g, c1_be, c1_W2, hB);
  k_edge_upd_mfma<64><<<N_EDGES / 64, 256, 0, stream>>>(hB, ea, src, dst, l1_W, l1_b, ea);  // in-place, row-local

  // ---- conv layer 2 ----
  hipMemsetAsync(sums, 0, 256 * 4, stream);
  k_agg_csr<<<(N_NODES * 64 + 255) / 256, 256, 0, stream>>>(hB, ea, eids, startA, cnt, hsum);
  k_mlp1<<<1024, 256, 0, stream>>>(hsum, c2_W1, h3);
  k_bnstats<<<1280, 256, 0, stream>>>(h3, sums);
  k_bnfinal<<<1, 128, 0, stream>>>(sums, musig);
  k_mlp2<<<1024, 256, 0, stream>>>(h3, musig, c2_g, c2_be, c2_W2, h_out);
  k_edge_upd_mfma<32><<<N_EDGES / 64, 256, 0, stream>>>(h_out, ea, src, dst, l2_W, l2_b, ea_out);
}

// Round 4
// 1211.954 us; speedup vs baseline: 4.6177x; 1.3773x over previous
//
#include <hip/hip_runtime.h>
#include <hip/hip_bf16.h>

#define N_NODES 80000
#define N_EDGES 1280000
constexpr int DN = 128;   // node input dim
constexpr int DE = 32;    // edge input dim
constexpr int H  = 64;    // hidden
constexpr int H2 = 128;   // 2*hidden
constexpr float EPS_GEN = 1e-7f;
constexpr float EPS_BN  = 1e-5f;

typedef _Float16 f16x8 __attribute__((ext_vector_type(8)));
typedef _Float16 f16x4 __attribute__((ext_vector_type(4)));
typedef float f32x4 __attribute__((ext_vector_type(4)));

__device__ __forceinline__ int rfl(int x) { return __builtin_amdgcn_readfirstlane(x); }

__device__ __forceinline__ void atomAddF(float* p, float v) {
  __hip_atomic_fetch_add(p, v, __ATOMIC_RELAXED, __HIP_MEMORY_SCOPE_AGENT);
}

// ---------------- edge encoder (MFMA): ea16[e,:] = f16( attr[e,:] @ W(32x64) + b ) ----------------
// 64 edges/block, 4 waves x 16 edges. K=32 = one 16x16x32 k-step.
__global__ __launch_bounds__(256) void k_edge_enc(
    const float* __restrict__ attr, const float* __restrict__ W,
    const float* __restrict__ b, _Float16* __restrict__ ea) {
  constexpr int RPA = 36;   // A pitch (halves)
  constexpr int RPB = 56;   // B pitch: 56*2=112 B, mod128=112 -> 2-way max on b128 fan
  __shared__ _Float16 sA[64 * RPA];
  __shared__ _Float16 sB[64 * RPB];
  const int tid = threadIdx.x;
  const int ebase = blockIdx.x * 64;

  for (int idx = tid; idx < DE * H; idx += 256) {   // W[k][n] -> sB[n][k]
    int k = idx >> 6, n = idx & 63;
    sB[n * RPB + k] = (_Float16)W[idx];
  }
#pragma unroll
  for (int p = 0; p < 2; ++p) {                     // 64 rows x 8 float4
    int idx = p * 256 + tid;
    int row = idx >> 3, c4 = idx & 7;
    float4 v = *(const float4*)(attr + (size_t)(ebase + row) * DE + c4 * 4);
    f16x4 hv = { (_Float16)v.x, (_Float16)v.y, (_Float16)v.z, (_Float16)v.w };
    *(f16x4*)&sA[row * RPA + c4 * 4] = hv;
  }
  __syncthreads();

  const int wv = tid >> 6, lane = tid & 63, m16 = lane & 15, kg = lane >> 4;
  f32x4 acc[4];
#pragma unroll
  for (int n2 = 0; n2 < 4; ++n2) {
    float bv = b[n2 * 16 + m16];
    acc[n2] = (f32x4){bv, bv, bv, bv};
  }
  f16x8 a = *(const f16x8*)&sA[(wv * 16 + m16) * RPA + kg * 8];
#pragma unroll
  for (int n2 = 0; n2 < 4; ++n2) {
    f16x8 bb = *(const f16x8*)&sB[(n2 * 16 + m16) * RPB + kg * 8];
    acc[n2] = __builtin_amdgcn_mfma_f32_16x16x32_f16(a, bb, acc[n2], 0, 0, 0);
  }
#pragma unroll
  for (int n2 = 0; n2 < 4; ++n2)
#pragma unroll
    for (int r = 0; r < 4; ++r)
      ea[(size_t)(ebase + wv * 16 + kg * 4 + r) * H + n2 * 16 + m16] = (_Float16)acc[n2][r];
}

// ---------------- node encoder (MFMA): h16[n,:] = f16( x[n,:] @ W(128x64) + b ) ----------------
__global__ __launch_bounds__(256) void k_node_enc(
    const float* __restrict__ x, const float* __restrict__ W,
    const float* __restrict__ b, _Float16* __restrict__ h) {
  constexpr int RPA = 136;
  constexpr int RPB = 152;  // 304 B pitch, mod128=48 -> conflict-free b128 fan
  __shared__ _Float16 sA[64 * RPA];  // 17408 B
  __shared__ _Float16 sB[64 * RPB];  // 19456 B
  const int tid = threadIdx.x;
  const int nbase = blockIdx.x * 64;

  for (int idx = tid; idx < DN * H; idx += 256) {   // W[k][n] -> sB[n][k]
    int k = idx >> 6, n = idx & 63;
    sB[n * RPB + k] = (_Float16)W[idx];
  }
#pragma unroll
  for (int p = 0; p < 8; ++p) {                     // 64 rows x 32 float4
    int idx = p * 256 + tid;
    int row = idx >> 5, c4 = idx & 31;
    float4 v = *(const float4*)(x + (size_t)(nbase + row) * DN + c4 * 4);
    f16x4 hv = { (_Float16)v.x, (_Float16)v.y, (_Float16)v.z, (_Float16)v.w };
    *(f16x4*)&sA[row * RPA + c4 * 4] = hv;
  }
  __syncthreads();

  const int wv = tid >> 6, lane = tid & 63, m16 = lane & 15, kg = lane >> 4;
  f32x4 acc[4];
#pragma unroll
  for (int n2 = 0; n2 < 4; ++n2) {
    float bv = b[n2 * 16 + m16];
    acc[n2] = (f32x4){bv, bv, bv, bv};
  }
#pragma unroll
  for (int kk = 0; kk < 4; ++kk) {
    int k0 = kk * 32 + kg * 8;
    f16x8 a = *(const f16x8*)&sA[(wv * 16 + m16) * RPA + k0];
#pragma unroll
    for (int n2 = 0; n2 < 4; ++n2) {
      f16x8 bb = *(const f16x8*)&sB[(n2 * 16 + m16) * RPB + k0];
      acc[n2] = __builtin_amdgcn_mfma_f32_16x16x32_f16(a, bb, acc[n2], 0, 0, 0);
    }
  }
#pragma unroll
  for (int n2 = 0; n2 < 4; ++n2)
#pragma unroll
    for (int r = 0; r < 4; ++r)
      h[(size_t)(nbase + wv * 16 + kg * 4 + r) * H + n2 * 16 + m16] = (_Float16)acc[n2][r];
}

// ---------------- CSR build: histogram -> scan -> scatter ----------------
__global__ void k_hist(const int* __restrict__ dst, int* cnt) {
  int e = blockIdx.x * blockDim.x + threadIdx.x;
  if (e < N_EDGES) atomicAdd(&cnt[dst[e]], 1);
}

__global__ void k_scan_blk(const int* __restrict__ cnt, int* __restrict__ bsum) {
  __shared__ int sh[256];
  int i = blockIdx.x * 256 + threadIdx.x;
  sh[threadIdx.x] = (i < N_NODES) ? cnt[i] : 0;
  __syncthreads();
  for (int s = 128; s > 0; s >>= 1) {
    if (threadIdx.x < s) sh[threadIdx.x] += sh[threadIdx.x + s];
    __syncthreads();
  }
  if (threadIdx.x == 0) bsum[blockIdx.x] = sh[0];
}

__global__ void k_scan_top(int* bsum, int nb) {  // 1 block x 512, exclusive scan
  __shared__ int sh[512];
  int t = threadIdx.x;
  int orig = (t < nb) ? bsum[t] : 0;
  sh[t] = orig;
  __syncthreads();
  for (int off = 1; off < 512; off <<= 1) {
    int v = (t >= off) ? sh[t - off] : 0;
    __syncthreads();
    sh[t] += v;
    __syncthreads();
  }
  if (t < nb) bsum[t] = sh[t] - orig;
}

__global__ void k_scan_fin(const int* __restrict__ cnt, const int* __restrict__ bsum,
                           int* __restrict__ start, int* __restrict__ cursor) {
  __shared__ int sh[256];
  int i = blockIdx.x * 256 + threadIdx.x;
  int t = threadIdx.x;
  int orig = (i < N_NODES) ? cnt[i] : 0;
  sh[t] = orig;
  __syncthreads();
  for (int off = 1; off < 256; off <<= 1) {
    int v = (t >= off) ? sh[t - off] : 0;
    __syncthreads();
    sh[t] += v;
    __syncthreads();
  }
  if (i < N_NODES) {
    int st = bsum[blockIdx.x] + sh[t] - orig;
    start[i] = st;
    cursor[i] = st;
  }
}

__global__ void k_scatter(const int* __restrict__ src, const int* __restrict__ dst,
                          int* cursor, int2* __restrict__ eids) {
  int e = blockIdx.x * blockDim.x + threadIdx.x;
  if (e < N_EDGES) {
    int pos = atomicAdd(&cursor[dst[e]], 1);
    eids[pos] = make_int2(e, src[e]);
  }
}

// ---------------- CSR softmax-aggregation: one wave per node, 2-deep pipeline ----------------
__global__ __launch_bounds__(256) void k_agg_csr(
    const _Float16* __restrict__ h, const _Float16* __restrict__ ea,
    const int2* __restrict__ eids, const int* __restrict__ start,
    const int* __restrict__ cnt, float* __restrict__ hsum) {
  int lane = threadIdx.x & 63;
  int wid  = (int)((blockIdx.x * blockDim.x + threadIdx.x) >> 6);
  if (wid >= N_NODES) return;
  int s0 = start[wid], c = cnt[wid];
  float num = 0.0f, den = 0.0f;
  int2 e1 = make_int2(0, 0);
  float hv0 = 0.0f, ev0 = 0.0f;
  if (c > 0) {
    int2 e0 = eids[s0];
    hv0 = (float)h[(size_t)e0.y * H + lane];
    ev0 = (float)ea[(size_t)e0.x * H + lane];
  }
  if (c > 1) e1 = eids[s0 + 1];
  for (int i = 0; i < c; ++i) {
    float hv = hv0, ev = ev0;
    if (i + 1 < c) {                         // issue next gathers before compute
      hv0 = (float)h[(size_t)e1.y * H + lane];
      ev0 = (float)ea[(size_t)e1.x * H + lane];
      if (i + 2 < c) e1 = eids[s0 + i + 2];
    }
    float m = fmaxf(hv + ev, 0.0f) + EPS_GEN;
    float ex = __expf(m);
    num = fmaf(m, ex, num);
    den += ex;
  }
  hsum[(size_t)wid * H + lane] = num / (den + 1e-16f) + (float)h[(size_t)wid * H + lane];
}

// ---------------- h3[n,:] = hsum[n,:] @ W1(64x128) ----------------
__global__ void k_mlp1(const float* __restrict__ hsum, const float* __restrict__ W1,
                       float* __restrict__ h3) {
  __shared__ float sW[H * H2];   // 32 KB
  for (int i = threadIdx.x; i < H * H2; i += blockDim.x) sW[i] = W1[i];
  __syncthreads();
  int lane = threadIdx.x & 63;
  int wid  = (int)((blockIdx.x * blockDim.x + threadIdx.x) >> 6);
  int nw   = (int)((gridDim.x * blockDim.x) >> 6);
  for (int n = wid; n < N_NODES; n += nw) {
    int nu = rfl(n);
    const float* hr = hsum + (size_t)nu * H;
    float a0 = 0.0f, a1 = 0.0f;
#pragma unroll 8
    for (int k = 0; k < H; ++k) {
      float h2v = hr[k];
      a0 = fmaf(h2v, sW[k * H2 + lane], a0);
      a1 = fmaf(h2v, sW[k * H2 + 64 + lane], a1);
    }
    h3[(size_t)nu * H2 + lane] = a0;
    h3[(size_t)nu * H2 + 64 + lane] = a1;
  }
}

// ---------------- BN stats ----------------
__global__ void k_bnstats(const float* __restrict__ h3, float* sums) {
  int f = threadIdx.x & (H2 - 1);
  int half = threadIdx.x >> 7;
  float s = 0.0f, q = 0.0f;
  for (int n = blockIdx.x * 2 + half; n < N_NODES; n += gridDim.x * 2) {
    float v = h3[(size_t)n * H2 + f];
    s += v;
    q = fmaf(v, v, q);
  }
  __shared__ float sh[2][2][H2];
  sh[0][half][f] = s;
  sh[1][half][f] = q;
  __syncthreads();
  if (threadIdx.x < H2) {
    atomAddF(&sums[f], sh[0][0][f] + sh[0][1][f]);
    atomAddF(&sums[H2 + f], sh[1][0][f] + sh[1][1][f]);
  }
}

__global__ void k_bnfinal(const float* __restrict__ sums, float* __restrict__ musig) {
  int f = threadIdx.x;
  if (f < H2) {
    float mu  = sums[f] / (float)N_NODES;
    float var = sums[H2 + f] / (float)N_NODES - mu * mu;
    musig[f] = mu;
    musig[H2 + f] = 1.0f / sqrtf(var + EPS_BN);
  }
}

// ---------------- h_out = relu( relu(bn(h3)) @ W2(128x64) ); f16 always, f32 when DUAL ----------------
template <bool DUAL>
__global__ void k_mlp2(const float* __restrict__ h3, const float* __restrict__ musig,
                       const float* __restrict__ g, const float* __restrict__ be,
                       const float* __restrict__ W2, _Float16* __restrict__ hout16,
                       float* __restrict__ hout32) {
  __shared__ float sW[H2 * H];   // 32 KB
  __shared__ float ssc[H2], ssh[H2];
  for (int i = threadIdx.x; i < H2 * H; i += blockDim.x) sW[i] = W2[i];
  for (int i = threadIdx.x; i < H2; i += blockDim.x) {
    float rs = musig[H2 + i];
    float sc = rs * g[i];
    ssc[i] = sc;
    ssh[i] = be[i] - musig[i] * sc;
  }
  __syncthreads();
  int lane = threadIdx.x & 63;
  int wid  = (int)((blockIdx.x * blockDim.x + threadIdx.x) >> 6);
  int nw   = (int)((gridDim.x * blockDim.x) >> 6);
  for (int n = wid; n < N_NODES; n += nw) {
    int nu = rfl(n);
    const float* r = h3 + (size_t)nu * H2;
    float acc = 0.0f;
#pragma unroll 8
    for (int m = 0; m < H2; ++m) {
      float y = fmaxf(fmaf(r[m], ssc[m], ssh[m]), 0.0f);
      acc = fmaf(y, sW[m * H + lane], acc);
    }
    float o = fmaxf(acc, 0.0f);
    hout16[(size_t)nu * H + lane] = (_Float16)o;
    if constexpr (DUAL) hout32[(size_t)nu * H + lane] = o;
  }
}

// ---------------- edge update via MFMA (f16 in, OUT_T out) ----------------
template <int OC, typename OUT_T>
__global__ __launch_bounds__(256) void k_edge_upd_mfma(
    const _Float16* __restrict__ h, const _Float16* __restrict__ ea,
    const int* __restrict__ src, const int* __restrict__ dst,
    const float* __restrict__ lW, const float* __restrict__ lb,
    OUT_T* __restrict__ eout) {
  constexpr int RPA = 200;                // A pitch (8-way fan, only 6 reads/wave)
  constexpr int RPB = 216;                // 432 B pitch, mod128=48 -> conflict-free b128 fan
  __shared__ _Float16 sA[64 * RPA];       // 25600 B
  __shared__ _Float16 sB[OC * RPB];       // OC=64: 27648 B
  __shared__ int2 sSD[64];

  const int tid  = threadIdx.x;
  const int ebase = blockIdx.x * 64;

  if (tid < 64) sSD[tid] = make_int2(src[ebase + tid], dst[ebase + tid]);
  __syncthreads();

  for (int idx = tid; idx < 192 * OC; idx += 256) {   // lW[k][n] -> sB[n][k]
    int k = idx / OC, n = idx % OC;
    sB[n * RPB + k] = (_Float16)lW[idx];
  }

  const int wv = tid >> 6, lane = tid & 63;
  const int part = lane & 15, u = lane >> 4;
  f16x4 v[12];
#pragma unroll
  for (int it = 0; it < 12; ++it) {
    int su = wv * 48 + it * 4 + u;       // 0..191
    int el = su / 3;
    int sg = su % 3;
    int2 sd = sSD[el];
    const _Float16* base = (sg == 0) ? (h + (size_t)sd.x * H)
                         : (sg == 1) ? (ea + (size_t)(ebase + el) * H)
                                     : (h + (size_t)sd.y * H);
    v[it] = *(const f16x4*)(base + part * 4);
  }
#pragma unroll
  for (int it = 0; it < 12; ++it) {
    int su = wv * 48 + it * 4 + u;
    int el = su / 3;
    int sg = su % 3;
    *(f16x4*)&sA[el * RPA + sg * 64 + part * 4] = v[it];
  }
  __syncthreads();

  const int m16 = lane & 15;
  const int kg  = lane >> 4;
  constexpr int NF = OC / 16;
  f32x4 acc[NF];
#pragma unroll
  for (int n2 = 0; n2 < NF; ++n2) {
    float bv = lb[n2 * 16 + m16];
    acc[n2] = (f32x4){bv, bv, bv, bv};
  }
#pragma unroll
  for (int kk = 0; kk < 6; ++kk) {
    int k0 = kk * 32 + kg * 8;
    f16x8 a = *(const f16x8*)&sA[(wv * 16 + m16) * RPA + k0];
#pragma unroll
    for (int n2 = 0; n2 < NF; ++n2) {
      f16x8 b = *(const f16x8*)&sB[(n2 * 16 + m16) * RPB + k0];
      acc[n2] = __builtin_amdgcn_mfma_f32_16x16x32_f16(a, b, acc[n2], 0, 0, 0);
    }
  }
#pragma unroll
  for (int n2 = 0; n2 < NF; ++n2)
#pragma unroll
    for (int r = 0; r < 4; ++r) {
      int row = wv * 16 + kg * 4 + r;
      int col = n2 * 16 + m16;
      eout[(size_t)(ebase + row) * OC + col] = (OUT_T)acc[n2][r];
    }
}

extern "C" void kernel_launch(void* const* d_in, const int* in_sizes, int n_in,
                              void* d_out, int out_size, void* d_ws, size_t ws_size,
                              hipStream_t stream) {
  (void)in_sizes; (void)n_in; (void)out_size; (void)ws_size;
  const float* x      = (const float*)d_in[0];
  const int*   eidx   = (const int*)d_in[1];
  const float* eattr  = (const float*)d_in[2];
  const float* node_W = (const float*)d_in[3];
  const float* node_b = (const float*)d_in[4];
  const float* edge_W = (const float*)d_in[5];
  const float* edge_b = (const float*)d_in[6];
  const float* c1_W1  = (const float*)d_in[7];
  const float* c1_g   = (const float*)d_in[8];
  const float* c1_be  = (const float*)d_in[9];
  const float* c1_W2  = (const float*)d_in[10];
  const float* c2_W1  = (const float*)d_in[11];
  const float* c2_g   = (const float*)d_in[12];
  const float* c2_be  = (const float*)d_in[13];
  const float* c2_W2  = (const float*)d_in[14];
  const float* l1_W   = (const float*)d_in[15];
  const float* l1_b   = (const float*)d_in[16];
  const float* l2_W   = (const float*)d_in[17];
  const float* l2_b   = (const float*)d_in[18];

  const int* src = eidx;
  const int* dst = eidx + N_EDGES;

  char* wsb = (char*)d_ws;
  size_t off = 0;
  _Float16* ea16 = (_Float16*)(wsb + off); off += (size_t)N_EDGES * H * 2;   // 163.84 MB
  _Float16* hA16 = (_Float16*)(wsb + off); off += (size_t)N_NODES * H * 2;
  _Float16* hB16 = (_Float16*)(wsb + off); off += (size_t)N_NODES * H * 2;
  _Float16* hC16 = (_Float16*)(wsb + off); off += (size_t)N_NODES * H * 2;
  float* hsum    = (float*)(wsb + off);    off += (size_t)N_NODES * H * 4;
  float* h3      = (float*)(wsb + off);    off += (size_t)N_NODES * H2 * 4;
  float* sums    = (float*)(wsb + off);    off += 256 * 4;
  float* musig   = (float*)(wsb + off);    off += 256 * 4;
  int* cnt       = (int*)(wsb + off);      off += (size_t)N_NODES * 4;
  int* startA    = (int*)(wsb + off);      off += (size_t)N_NODES * 4;
  int* cursor    = (int*)(wsb + off);      off += (size_t)N_NODES * 4;
  int* bsum      = (int*)(wsb + off);      off += 512 * 4;
  int2* eids     = (int2*)(wsb + off);     off += (size_t)N_EDGES * 8;

  float* h_out  = (float*)d_out;                            // [N,64]
  float* ea_out = (float*)d_out + (size_t)N_NODES * H;      // [E,32]

  constexpr int NB = (N_NODES + 255) / 256;                 // 313 scan blocks

  k_edge_enc<<<N_EDGES / 64, 256, 0, stream>>>(eattr, edge_W, edge_b, ea16);
  k_node_enc<<<N_NODES / 64, 256, 0, stream>>>(x, node_W, node_b, hA16);

  // ---- build CSR once (shared by both conv layers) ----
  hipMemsetAsync(cnt, 0, N_NODES * 4, stream);
  k_hist<<<(N_EDGES + 255) / 256, 256, 0, stream>>>(dst, cnt);
  k_scan_blk<<<NB, 256, 0, stream>>>(cnt, bsum);
  k_scan_top<<<1, 512, 0, stream>>>(bsum, NB);
  k_scan_fin<<<NB, 256, 0, stream>>>(cnt, bsum, startA, cursor);
  k_scatter<<<(N_EDGES + 255) / 256, 256, 0, stream>>>(src, dst, cursor, eids);

  // ---- conv layer 1 ----
  hipMemsetAsync(sums, 0, 256 * 4, stream);
  k_agg_csr<<<(N_NODES + 3) / 4, 256, 0, stream>>>(hA16, ea16, eids, startA, cnt, hsum);
  k_mlp1<<<1024, 256, 0, stream>>>(hsum, c1_W1, h3);
  k_bnstats<<<1280, 256, 0, stream>>>(h3, sums);
  k_bnfinal<<<1, 128, 0, stream>>>(sums, musig);
  k_mlp2<false><<<1024, 256, 0, stream>>>(h3, musig, c1_g, c1_be, c1_W2, hB16, nullptr);
  k_edge_upd_mfma<64, _Float16><<<N_EDGES / 64, 256, 0, stream>>>(hB16, ea16, src, dst, l1_W, l1_b, ea16);  // in-place, row-local

  // ---- conv layer 2 ----
  hipMemsetAsync(sums, 0, 256 * 4, stream);
  k_agg_csr<<<(N_NODES + 3) / 4, 256, 0, stream>>>(hB16, ea16, eids, startA, cnt, hsum);
  k_mlp1<<<1024, 256, 0, stream>>>(hsum, c2_W1, h3);
  k_bnstats<<<1280, 256, 0, stream>>>(h3, sums);
  k_bnfinal<<<1, 128, 0, stream>>>(sums, musig);
  k_mlp2<true><<<1024, 256, 0, stream>>>(h3, musig, c2_g, c2_be, c2_W2, hC16, h_out);
  k_edge_upd_mfma<32, float><<<N_EDGES / 64, 256, 0, stream>>>(hC16, ea16, src, dst, l2_W, l2_b, ea_out);
}

// Round 5
// 1019.946 us; speedup vs baseline: 5.4869x; 1.1883x over previous
//
#include <hip/hip_runtime.h>
#include <hip/hip_bf16.h>

#define N_NODES 80000
#define N_EDGES 1280000
constexpr int DN = 128;   // node input dim
constexpr int DE = 32;    // edge input dim
constexpr int H  = 64;    // hidden
constexpr int H2 = 128;   // 2*hidden
constexpr float EPS_GEN = 1e-7f;
constexpr float EPS_BN  = 1e-5f;

typedef _Float16 f16x8 __attribute__((ext_vector_type(8)));
typedef _Float16 f16x4 __attribute__((ext_vector_type(4)));
typedef float f32x4 __attribute__((ext_vector_type(4)));

__device__ __forceinline__ void atomAddF(float* p, float v) {
  __hip_atomic_fetch_add(p, v, __ATOMIC_RELAXED, __HIP_MEMORY_SCOPE_AGENT);
}

// ---------------- weight prep: f32 [K][OC] -> f16 frag-image ----------------
// image layout: slab (n2*NK+kk) of 512 halves; element ((kg*16+m16)*8+j) holds
// W[kk*32+kg*8+j][n2*16+m16].  A wave's B-fragment load = lane*16B, coalesced.
__global__ void k_prep_w(const float* __restrict__ W, int K, int OC,
                         _Float16* __restrict__ img) {
  int idx = blockIdx.x * 256 + threadIdx.x;   // < K*OC
  int nslabK = K >> 5;
  int j = idx & 7, m16 = (idx >> 3) & 15, kg = (idx >> 7) & 3;
  int slab = idx >> 9;
  int kk = slab % nslabK, n2 = slab / nslabK;
  int k = kk * 32 + kg * 8 + j, n = n2 * 16 + m16;
  img[idx] = (_Float16)W[k * OC + n];
}

// ---------------- generic dense MFMA: out[row,:] = f(A[row,:]) @ W + b ----------------
// 64 rows/block, 4 waves x 16 rows, no LDS. AFFINE: A <- relu(A*sc+sh) (BN+relu).
template <int K, int OC, bool IN16, bool AFFINE, bool BIAS, bool RELU_OUT, bool OUT16, bool OUT32>
__global__ __launch_bounds__(256) void k_dense(
    const void* __restrict__ Ain, const _Float16* __restrict__ wimg,
    const float* __restrict__ bias, const float* __restrict__ scsh,
    _Float16* __restrict__ out16, float* __restrict__ out32) {
  constexpr int NK = K / 32, NF = OC / 16;
  const int tid = threadIdx.x, wv = tid >> 6, lane = tid & 63;
  const int m16 = lane & 15, kg = lane >> 4;
  const int rowbase = blockIdx.x * 64 + wv * 16;
  f32x4 acc[NF];
#pragma unroll
  for (int n2 = 0; n2 < NF; ++n2) {
    float bv = BIAS ? bias[n2 * 16 + m16] : 0.0f;
    acc[n2] = (f32x4){bv, bv, bv, bv};
  }
  const _Float16* wp = wimg + (size_t)lane * 8;
#pragma unroll
  for (int kk = 0; kk < NK; ++kk) {
    f16x8 a;
    if constexpr (IN16) {
      const _Float16* ap = (const _Float16*)Ain + (size_t)(rowbase + m16) * K + kg * 8 + kk * 32;
      a = *(const f16x8*)ap;
    } else {
      const float* ap = (const float*)Ain + (size_t)(rowbase + m16) * K + kg * 8 + kk * 32;
      float4 v0 = *(const float4*)ap;
      float4 v1 = *(const float4*)(ap + 4);
      if constexpr (AFFINE) {
        const float* scp = scsh + kg * 8 + kk * 32;
        float4 s0 = *(const float4*)scp, s1 = *(const float4*)(scp + 4);
        float4 t0 = *(const float4*)(scp + H2), t1 = *(const float4*)(scp + H2 + 4);
        v0.x = fmaxf(fmaf(v0.x, s0.x, t0.x), 0.0f);
        v0.y = fmaxf(fmaf(v0.y, s0.y, t0.y), 0.0f);
        v0.z = fmaxf(fmaf(v0.z, s0.z, t0.z), 0.0f);
        v0.w = fmaxf(fmaf(v0.w, s0.w, t0.w), 0.0f);
        v1.x = fmaxf(fmaf(v1.x, s1.x, t1.x), 0.0f);
        v1.y = fmaxf(fmaf(v1.y, s1.y, t1.y), 0.0f);
        v1.z = fmaxf(fmaf(v1.z, s1.z, t1.z), 0.0f);
        v1.w = fmaxf(fmaf(v1.w, s1.w, t1.w), 0.0f);
      }
      a = (f16x8){(_Float16)v0.x, (_Float16)v0.y, (_Float16)v0.z, (_Float16)v0.w,
                  (_Float16)v1.x, (_Float16)v1.y, (_Float16)v1.z, (_Float16)v1.w};
    }
#pragma unroll
    for (int n2 = 0; n2 < NF; ++n2) {
      f16x8 bb = *(const f16x8*)(wp + ((size_t)(n2 * NK + kk) << 9));
      acc[n2] = __builtin_amdgcn_mfma_f32_16x16x32_f16(a, bb, acc[n2], 0, 0, 0);
    }
  }
#pragma unroll
  for (int n2 = 0; n2 < NF; ++n2)
#pragma unroll
    for (int r = 0; r < 4; ++r) {
      float o = acc[n2][r];
      if constexpr (RELU_OUT) o = fmaxf(o, 0.0f);
      size_t oi = (size_t)(rowbase + kg * 4 + r) * OC + n2 * 16 + m16;
      if constexpr (OUT16) out16[oi] = (_Float16)o;
      if constexpr (OUT32) out32[oi] = o;
    }
}

// ---------------- edge update, register-direct MFMA (no LDS, no barrier) ----------------
// out[e,:] = concat(h[src],ea,h[dst]) @ lW(192xOC) + lb
template <int OC, typename OUT_T>
__global__ __launch_bounds__(256) void k_edge_upd_reg(
    const _Float16* __restrict__ h, const _Float16* __restrict__ ea,
    const int* __restrict__ src, const int* __restrict__ dst,
    const _Float16* __restrict__ wimg, const float* __restrict__ lb,
    OUT_T* __restrict__ eout) {
  constexpr int NF = OC / 16;
  const int tid = threadIdx.x, wv = tid >> 6, lane = tid & 63;
  const int m16 = lane & 15, kg = lane >> 4;
  const int rowbase = blockIdx.x * 64 + wv * 16;
  const int row = rowbase + m16;
  const int s = src[row], d = dst[row];
  const _Float16* a0 = h + (size_t)s * H + kg * 8;
  const _Float16* a1 = ea + (size_t)row * H + kg * 8;
  const _Float16* a2 = h + (size_t)d * H + kg * 8;
  f32x4 acc[NF];
#pragma unroll
  for (int n2 = 0; n2 < NF; ++n2) {
    float bv = lb[n2 * 16 + m16];
    acc[n2] = (f32x4){bv, bv, bv, bv};
  }
  const _Float16* wp = wimg + (size_t)lane * 8;
#pragma unroll
  for (int kk = 0; kk < 6; ++kk) {
    const _Float16* ap = (kk < 2 ? a0 : (kk < 4 ? a1 : a2)) + (kk & 1) * 32;
    f16x8 a = *(const f16x8*)ap;
#pragma unroll
    for (int n2 = 0; n2 < NF; ++n2) {
      f16x8 bb = *(const f16x8*)(wp + ((size_t)(n2 * 6 + kk) << 9));
      acc[n2] = __builtin_amdgcn_mfma_f32_16x16x32_f16(a, bb, acc[n2], 0, 0, 0);
    }
  }
  // reads of ea rows [rowbase, rowbase+16) complete before these writes (same wave) -> in-place safe
#pragma unroll
  for (int n2 = 0; n2 < NF; ++n2)
#pragma unroll
    for (int r = 0; r < 4; ++r) {
      size_t oi = (size_t)(rowbase + kg * 4 + r) * OC + n2 * 16 + m16;
      eout[oi] = (OUT_T)acc[n2][r];
    }
}

// ---------------- CSR build: histogram -> scan -> scatter ----------------
__global__ void k_hist(const int* __restrict__ dst, int* cnt) {
  int e = blockIdx.x * blockDim.x + threadIdx.x;
  if (e < N_EDGES) atomicAdd(&cnt[dst[e]], 1);
}

__global__ void k_scan_blk(const int* __restrict__ cnt, int* __restrict__ bsum) {
  __shared__ int sh[256];
  int i = blockIdx.x * 256 + threadIdx.x;
  sh[threadIdx.x] = (i < N_NODES) ? cnt[i] : 0;
  __syncthreads();
  for (int s = 128; s > 0; s >>= 1) {
    if (threadIdx.x < s) sh[threadIdx.x] += sh[threadIdx.x + s];
    __syncthreads();
  }
  if (threadIdx.x == 0) bsum[blockIdx.x] = sh[0];
}

__global__ void k_scan_top(int* bsum, int nb) {  // 1 block x 512, exclusive scan
  __shared__ int sh[512];
  int t = threadIdx.x;
  int orig = (t < nb) ? bsum[t] : 0;
  sh[t] = orig;
  __syncthreads();
  for (int off = 1; off < 512; off <<= 1) {
    int v = (t >= off) ? sh[t - off] : 0;
    __syncthreads();
    sh[t] += v;
    __syncthreads();
  }
  if (t < nb) bsum[t] = sh[t] - orig;
}

__global__ void k_scan_fin(const int* __restrict__ cnt, const int* __restrict__ bsum,
                           int* __restrict__ start, int* __restrict__ cursor) {
  __shared__ int sh[256];
  int i = blockIdx.x * 256 + threadIdx.x;
  int t = threadIdx.x;
  int orig = (i < N_NODES) ? cnt[i] : 0;
  sh[t] = orig;
  __syncthreads();
  for (int off = 1; off < 256; off <<= 1) {
    int v = (t >= off) ? sh[t - off] : 0;
    __syncthreads();
    sh[t] += v;
    __syncthreads();
  }
  if (i < N_NODES) {
    int st = bsum[blockIdx.x] + sh[t] - orig;
    start[i] = st;
    cursor[i] = st;
  }
}

__global__ void k_scatter(const int* __restrict__ src, const int* __restrict__ dst,
                          int* cursor, int2* __restrict__ eids) {
  int e = blockIdx.x * blockDim.x + threadIdx.x;
  if (e < N_EDGES) {
    int pos = atomicAdd(&cursor[dst[e]], 1);
    eids[pos] = make_int2(e, src[e]);
  }
}

// ---------------- CSR softmax-aggregation: one wave per node, depth-2 pipeline ----------------
__global__ __launch_bounds__(256) void k_agg_csr(
    const _Float16* __restrict__ h, const _Float16* __restrict__ ea,
    const int2* __restrict__ eids, const int* __restrict__ start,
    const int* __restrict__ cnt, _Float16* __restrict__ hsum) {
  int lane = threadIdx.x & 63;
  int wid  = (int)((blockIdx.x * blockDim.x + threadIdx.x) >> 6);
  if (wid >= N_NODES) return;
  int s0 = start[wid], c = cnt[wid];
  float num = 0.0f, den = 0.0f;
  int2 eN = make_int2(0, 0);
  float hvA = 0.0f, evA = 0.0f, hvB = 0.0f, evB = 0.0f;
  if (c > 0) {
    int2 e0 = eids[s0];
    if (c > 1) eN = eids[s0 + 1];
    hvA = (float)h[(size_t)e0.y * H + lane];
    evA = (float)ea[(size_t)e0.x * H + lane];
  }
  if (c > 1) {
    hvB = (float)h[(size_t)eN.y * H + lane];
    evB = (float)ea[(size_t)eN.x * H + lane];
  }
  for (int i = 0; i < c; ++i) {
    float hv = hvA, ev = evA;
    hvA = hvB; evA = evB;
    if (i + 2 < c) {                       // issue gathers 2 ahead
      int2 e2 = eids[s0 + i + 2];
      hvB = (float)h[(size_t)e2.y * H + lane];
      evB = (float)ea[(size_t)e2.x * H + lane];
    }
    float m = fmaxf(hv + ev, 0.0f) + EPS_GEN;
    float ex = __expf(m);
    num = fmaf(m, ex, num);
    den += ex;
  }
  hsum[(size_t)wid * H + lane] =
      (_Float16)(num / (den + 1e-16f) + (float)h[(size_t)wid * H + lane]);
}

// ---------------- BN stats ----------------
__global__ void k_bnstats(const float* __restrict__ h3, float* sums) {
  int f = threadIdx.x & (H2 - 1);
  int half = threadIdx.x >> 7;
  float s = 0.0f, q = 0.0f;
  for (int n = blockIdx.x * 2 + half; n < N_NODES; n += gridDim.x * 2) {
    float v = h3[(size_t)n * H2 + f];
    s += v;
    q = fmaf(v, v, q);
  }
  __shared__ float sh[2][2][H2];
  sh[0][half][f] = s;
  sh[1][half][f] = q;
  __syncthreads();
  if (threadIdx.x < H2) {
    atomAddF(&sums[f], sh[0][0][f] + sh[0][1][f]);
    atomAddF(&sums[H2 + f], sh[1][0][f] + sh[1][1][f]);
  }
}

// scsh[f] = rsqrt(var+eps)*g, scsh[128+f] = be - mu*sc
__global__ void k_bnfinal(const float* __restrict__ sums, const float* __restrict__ g,
                          const float* __restrict__ be, float* __restrict__ scsh) {
  int f = threadIdx.x;
  if (f < H2) {
    float mu  = sums[f] / (float)N_NODES;
    float var = sums[H2 + f] / (float)N_NODES - mu * mu;
    float sc  = rsqrtf(var + EPS_BN) * g[f];
    scsh[f] = sc;
    scsh[H2 + f] = be[f] - mu * sc;
  }
}

extern "C" void kernel_launch(void* const* d_in, const int* in_sizes, int n_in,
                              void* d_out, int out_size, void* d_ws, size_t ws_size,
                              hipStream_t stream) {
  (void)in_sizes; (void)n_in; (void)out_size; (void)ws_size;
  const float* x      = (const float*)d_in[0];
  const int*   eidx   = (const int*)d_in[1];
  const float* eattr  = (const float*)d_in[2];
  const float* node_W = (const float*)d_in[3];
  const float* node_b = (const float*)d_in[4];
  const float* edge_W = (const float*)d_in[5];
  const float* edge_b = (const float*)d_in[6];
  const float* c1_W1  = (const float*)d_in[7];
  const float* c1_g   = (const float*)d_in[8];
  const float* c1_be  = (const float*)d_in[9];
  const float* c1_W2  = (const float*)d_in[10];
  const float* c2_W1  = (const float*)d_in[11];
  const float* c2_g   = (const float*)d_in[12];
  const float* c2_be  = (const float*)d_in[13];
  const float* c2_W2  = (const float*)d_in[14];
  const float* l1_W   = (const float*)d_in[15];
  const float* l1_b   = (const float*)d_in[16];
  const float* l2_W   = (const float*)d_in[17];
  const float* l2_b   = (const float*)d_in[18];

  const int* src = eidx;
  const int* dst = eidx + N_EDGES;

  char* wsb = (char*)d_ws;
  size_t off = 0;
  _Float16* ea16  = (_Float16*)(wsb + off); off += (size_t)N_EDGES * H * 2;
  _Float16* hA16  = (_Float16*)(wsb + off); off += (size_t)N_NODES * H * 2;
  _Float16* hB16  = (_Float16*)(wsb + off); off += (size_t)N_NODES * H * 2;
  _Float16* hC16  = (_Float16*)(wsb + off); off += (size_t)N_NODES * H * 2;
  _Float16* hsum16= (_Float16*)(wsb + off); off += (size_t)N_NODES * H * 2;
  float* h3       = (float*)(wsb + off);    off += (size_t)N_NODES * H2 * 4;
  float* sums     = (float*)(wsb + off);    off += 256 * 4;
  float* scsh     = (float*)(wsb + off);    off += 256 * 4;
  int* cnt        = (int*)(wsb + off);      off += (size_t)N_NODES * 4;
  int* startA     = (int*)(wsb + off);      off += (size_t)N_NODES * 4;
  int* cursor     = (int*)(wsb + off);      off += (size_t)N_NODES * 4;
  int* bsum       = (int*)(wsb + off);      off += 512 * 4;
  int2* eids      = (int2*)(wsb + off);     off += (size_t)N_EDGES * 8;
  _Float16* wE    = (_Float16*)(wsb + off); off += DE * H * 2;        // 32x64
  _Float16* wN    = (_Float16*)(wsb + off); off += DN * H * 2;        // 128x64
  _Float16* w1a   = (_Float16*)(wsb + off); off += H * H2 * 2;        // 64x128
  _Float16* w1b   = (_Float16*)(wsb + off); off += H * H2 * 2;
  _Float16* w2a   = (_Float16*)(wsb + off); off += H2 * H * 2;        // 128x64
  _Float16* w2b   = (_Float16*)(wsb + off); off += H2 * H * 2;
  _Float16* wL1   = (_Float16*)(wsb + off); off += 3 * H * H * 2;     // 192x64
  _Float16* wL2   = (_Float16*)(wsb + off); off += 3 * H * (H / 2) * 2; // 192x32

  float* h_out  = (float*)d_out;                            // [N,64]
  float* ea_out = (float*)d_out + (size_t)N_NODES * H;      // [E,32]

  constexpr int NB = (N_NODES + 255) / 256;                 // 313 scan blocks

  // ---- one-time weight frag-images ----
  k_prep_w<<<DE * H / 256, 256, 0, stream>>>(edge_W, DE, H, wE);
  k_prep_w<<<DN * H / 256, 256, 0, stream>>>(node_W, DN, H, wN);
  k_prep_w<<<H * H2 / 256, 256, 0, stream>>>(c1_W1, H, H2, w1a);
  k_prep_w<<<H * H2 / 256, 256, 0, stream>>>(c2_W1, H, H2, w1b);
  k_prep_w<<<H2 * H / 256, 256, 0, stream>>>(c1_W2, H2, H, w2a);
  k_prep_w<<<H2 * H / 256, 256, 0, stream>>>(c2_W2, H2, H, w2b);
  k_prep_w<<<192 * H / 256, 256, 0, stream>>>(l1_W, 192, H, wL1);
  k_prep_w<<<192 * 32 / 256, 256, 0, stream>>>(l2_W, 192, 32, wL2);

  // ---- encoders ----
  k_dense<DE, H, false, false, true, false, true, false>
      <<<N_EDGES / 64, 256, 0, stream>>>(eattr, wE, edge_b, nullptr, ea16, nullptr);
  k_dense<DN, H, false, false, true, false, true, false>
      <<<N_NODES / 64, 256, 0, stream>>>(x, wN, node_b, nullptr, hA16, nullptr);

  // ---- build CSR once (shared by both conv layers) ----
  hipMemsetAsync(cnt, 0, N_NODES * 4, stream);
  k_hist<<<(N_EDGES + 255) / 256, 256, 0, stream>>>(dst, cnt);
  k_scan_blk<<<NB, 256, 0, stream>>>(cnt, bsum);
  k_scan_top<<<1, 512, 0, stream>>>(bsum, NB);
  k_scan_fin<<<NB, 256, 0, stream>>>(cnt, bsum, startA, cursor);
  k_scatter<<<(N_EDGES + 255) / 256, 256, 0, stream>>>(src, dst, cursor, eids);

  // ---- conv layer 1 ----
  hipMemsetAsync(sums, 0, 256 * 4, stream);
  k_agg_csr<<<(N_NODES + 3) / 4, 256, 0, stream>>>(hA16, ea16, eids, startA, cnt, hsum16);
  k_dense<H, H2, true, false, false, false, false, true>
      <<<N_NODES / 64, 256, 0, stream>>>(hsum16, w1a, nullptr, nullptr, nullptr, h3);
  k_bnstats<<<1280, 256, 0, stream>>>(h3, sums);
  k_bnfinal<<<1, 128, 0, stream>>>(sums, c1_g, c1_be, scsh);
  k_dense<H2, H, false, true, false, true, true, false>
      <<<N_NODES / 64, 256, 0, stream>>>(h3, w2a, nullptr, scsh, hB16, nullptr);
  k_edge_upd_reg<64, _Float16>
      <<<N_EDGES / 64, 256, 0, stream>>>(hB16, ea16, src, dst, wL1, l1_b, ea16);  // in-place

  // ---- conv layer 2 ----
  hipMemsetAsync(sums, 0, 256 * 4, stream);
  k_agg_csr<<<(N_NODES + 3) / 4, 256, 0, stream>>>(hB16, ea16, eids, startA, cnt, hsum16);
  k_dense<H, H2, true, false, false, false, false, true>
      <<<N_NODES / 64, 256, 0, stream>>>(hsum16, w1b, nullptr, nullptr, nullptr, h3);
  k_bnstats<<<1280, 256, 0, stream>>>(h3, sums);
  k_bnfinal<<<1, 128, 0, stream>>>(sums, c2_g, c2_be, scsh);
  k_dense<H2, H, false, true, false, true, true, true>
      <<<N_NODES / 64, 256, 0, stream>>>(h3, w2b, nullptr, scsh, hC16, h_out);
  k_edge_upd_reg<32, float>
      <<<N_EDGES / 64, 256, 0, stream>>>(hC16, ea16, src, dst, wL2, l2_b, ea_out);
}

// Round 6
// 803.881 us; speedup vs baseline: 6.9617x; 1.2688x over previous
//
#include <hip/hip_runtime.h>
#include <hip/hip_bf16.h>

#define N_NODES 80000
#define N_EDGES 1280000
constexpr int DN = 128;   // node input dim
constexpr int DE = 32;    // edge input dim
constexpr int H  = 64;    // hidden
constexpr int H2 = 128;   // 2*hidden
constexpr float EPS_GEN = 1e-7f;
constexpr float EPS_BN  = 1e-5f;

typedef _Float16 f16x8 __attribute__((ext_vector_type(8)));
typedef _Float16 f16x4 __attribute__((ext_vector_type(4)));
typedef float f32x4 __attribute__((ext_vector_type(4)));

__device__ __forceinline__ void atomAddF(float* p, float v) {
  __hip_atomic_fetch_add(p, v, __ATOMIC_RELAXED, __HIP_MEMORY_SCOPE_AGENT);
}

// ---------------- weight prep: f32 [K][OC] -> f16 frag-image ----------------
// slab (n2*NK+kk) of 512 halves; element ((kg*16+m16)*8+j) = W[kk*32+kg*8+j][n2*16+m16]
__global__ void k_prep_w(const float* __restrict__ W, int K, int OC,
                         _Float16* __restrict__ img) {
  int idx = blockIdx.x * 256 + threadIdx.x;   // < K*OC
  int nslabK = K >> 5;
  int j = idx & 7, m16 = (idx >> 3) & 15, kg = (idx >> 7) & 3;
  int slab = idx >> 9;
  int kk = slab % nslabK, n2 = slab / nslabK;
  int k = kk * 32 + kg * 8 + j, n = n2 * 16 + m16;
  img[idx] = (_Float16)W[k * OC + n];
}

// ---------------- generic dense MFMA: out[row,:] = f(A[row,:]) @ W + b ----------------
// 64 rows/block, 4 waves x 16 rows, no LDS. AFFINE: A <- relu(A*sc+sh) (BN+relu).
template <int K, int OC, bool IN16, bool AFFINE, bool BIAS, bool RELU_OUT, bool OUT16, bool OUT32>
__global__ __launch_bounds__(256) void k_dense(
    const void* __restrict__ Ain, const _Float16* __restrict__ wimg,
    const float* __restrict__ bias, const float* __restrict__ scsh,
    _Float16* __restrict__ out16, float* __restrict__ out32) {
  constexpr int NK = K / 32, NF = OC / 16;
  const int tid = threadIdx.x, wv = tid >> 6, lane = tid & 63;
  const int m16 = lane & 15, kg = lane >> 4;
  const int rowbase = blockIdx.x * 64 + wv * 16;
  f32x4 acc[NF];
#pragma unroll
  for (int n2 = 0; n2 < NF; ++n2) {
    float bv = BIAS ? bias[n2 * 16 + m16] : 0.0f;
    acc[n2] = (f32x4){bv, bv, bv, bv};
  }
  const _Float16* wp = wimg + (size_t)lane * 8;
#pragma unroll
  for (int kk = 0; kk < NK; ++kk) {
    f16x8 a;
    if constexpr (IN16) {
      const _Float16* ap = (const _Float16*)Ain + (size_t)(rowbase + m16) * K + kg * 8 + kk * 32;
      a = *(const f16x8*)ap;
      if constexpr (AFFINE) {
        const float* scp = scsh + kg * 8 + kk * 32;
#pragma unroll
        for (int j = 0; j < 8; ++j) {
          float v = fmaxf(fmaf((float)a[j], scp[j], scp[H2 + j]), 0.0f);
          a[j] = (_Float16)v;
        }
      }
    } else {
      const float* ap = (const float*)Ain + (size_t)(rowbase + m16) * K + kg * 8 + kk * 32;
      float4 v0 = *(const float4*)ap;
      float4 v1 = *(const float4*)(ap + 4);
      if constexpr (AFFINE) {
        const float* scp = scsh + kg * 8 + kk * 32;
        float4 s0 = *(const float4*)scp, s1 = *(const float4*)(scp + 4);
        float4 t0 = *(const float4*)(scp + H2), t1 = *(const float4*)(scp + H2 + 4);
        v0.x = fmaxf(fmaf(v0.x, s0.x, t0.x), 0.0f);
        v0.y = fmaxf(fmaf(v0.y, s0.y, t0.y), 0.0f);
        v0.z = fmaxf(fmaf(v0.z, s0.z, t0.z), 0.0f);
        v0.w = fmaxf(fmaf(v0.w, s0.w, t0.w), 0.0f);
        v1.x = fmaxf(fmaf(v1.x, s1.x, t1.x), 0.0f);
        v1.y = fmaxf(fmaf(v1.y, s1.y, t1.y), 0.0f);
        v1.z = fmaxf(fmaf(v1.z, s1.z, t1.z), 0.0f);
        v1.w = fmaxf(fmaf(v1.w, s1.w, t1.w), 0.0f);
      }
      a = (f16x8){(_Float16)v0.x, (_Float16)v0.y, (_Float16)v0.z, (_Float16)v0.w,
                  (_Float16)v1.x, (_Float16)v1.y, (_Float16)v1.z, (_Float16)v1.w};
    }
#pragma unroll
    for (int n2 = 0; n2 < NF; ++n2) {
      f16x8 bb = *(const f16x8*)(wp + ((size_t)(n2 * NK + kk) << 9));
      acc[n2] = __builtin_amdgcn_mfma_f32_16x16x32_f16(a, bb, acc[n2], 0, 0, 0);
    }
  }
#pragma unroll
  for (int n2 = 0; n2 < NF; ++n2)
#pragma unroll
    for (int r = 0; r < 4; ++r) {
      float o = acc[n2][r];
      if constexpr (RELU_OUT) o = fmaxf(o, 0.0f);
      size_t oi = (size_t)(rowbase + kg * 4 + r) * OC + n2 * 16 + m16;
      if constexpr (OUT16) out16[oi] = (_Float16)o;
      if constexpr (OUT32) out32[oi] = o;
    }
}

// ---------------- edge update, register-direct MFMA (no LDS, no barrier) ----------------
template <int OC, typename OUT_T>
__global__ __launch_bounds__(256) void k_edge_upd_reg(
    const _Float16* __restrict__ h, const _Float16* __restrict__ ea,
    const int* __restrict__ src, const int* __restrict__ dst,
    const _Float16* __restrict__ wimg, const float* __restrict__ lb,
    OUT_T* __restrict__ eout) {
  constexpr int NF = OC / 16;
  const int tid = threadIdx.x, wv = tid >> 6, lane = tid & 63;
  const int m16 = lane & 15, kg = lane >> 4;
  const int rowbase = blockIdx.x * 64 + wv * 16;
  const int row = rowbase + m16;
  const int s = src[row], d = dst[row];
  const _Float16* a0 = h + (size_t)s * H + kg * 8;
  const _Float16* a1 = ea + (size_t)row * H + kg * 8;
  const _Float16* a2 = h + (size_t)d * H + kg * 8;
  f32x4 acc[NF];
#pragma unroll
  for (int n2 = 0; n2 < NF; ++n2) {
    float bv = lb[n2 * 16 + m16];
    acc[n2] = (f32x4){bv, bv, bv, bv};
  }
  const _Float16* wp = wimg + (size_t)lane * 8;
#pragma unroll
  for (int kk = 0; kk < 6; ++kk) {
    const _Float16* ap = (kk < 2 ? a0 : (kk < 4 ? a1 : a2)) + (kk & 1) * 32;
    f16x8 a = *(const f16x8*)ap;
#pragma unroll
    for (int n2 = 0; n2 < NF; ++n2) {
      f16x8 bb = *(const f16x8*)(wp + ((size_t)(n2 * 6 + kk) << 9));
      acc[n2] = __builtin_amdgcn_mfma_f32_16x16x32_f16(a, bb, acc[n2], 0, 0, 0);
    }
  }
#pragma unroll
  for (int n2 = 0; n2 < NF; ++n2)
#pragma unroll
    for (int r = 0; r < 4; ++r) {
      size_t oi = (size_t)(rowbase + kg * 4 + r) * OC + n2 * 16 + m16;
      eout[oi] = (OUT_T)acc[n2][r];
    }
}

// ---------------- CSR build: histogram -> scan -> scatter ----------------
__global__ void k_hist(const int* __restrict__ dst, int* cnt) {
  int e = blockIdx.x * blockDim.x + threadIdx.x;
  if (e < N_EDGES) atomicAdd(&cnt[dst[e]], 1);
}

__global__ void k_scan_blk(const int* __restrict__ cnt, int* __restrict__ bsum) {
  __shared__ int sh[256];
  int i = blockIdx.x * 256 + threadIdx.x;
  sh[threadIdx.x] = (i < N_NODES) ? cnt[i] : 0;
  __syncthreads();
  for (int s = 128; s > 0; s >>= 1) {
    if (threadIdx.x < s) sh[threadIdx.x] += sh[threadIdx.x + s];
    __syncthreads();
  }
  if (threadIdx.x == 0) bsum[blockIdx.x] = sh[0];
}

__global__ void k_scan_top(int* bsum, int nb) {  // 1 block x 512, exclusive scan
  __shared__ int sh[512];
  int t = threadIdx.x;
  int orig = (t < nb) ? bsum[t] : 0;
  sh[t] = orig;
  __syncthreads();
  for (int off = 1; off < 512; off <<= 1) {
    int v = (t >= off) ? sh[t - off] : 0;
    __syncthreads();
    sh[t] += v;
    __syncthreads();
  }
  if (t < nb) bsum[t] = sh[t] - orig;
}

__global__ void k_scan_fin(const int* __restrict__ cnt, const int* __restrict__ bsum,
                           int* __restrict__ start, int* __restrict__ cursor) {
  __shared__ int sh[256];
  int i = blockIdx.x * 256 + threadIdx.x;
  int t = threadIdx.x;
  int orig = (i < N_NODES) ? cnt[i] : 0;
  sh[t] = orig;
  __syncthreads();
  for (int off = 1; off < 256; off <<= 1) {
    int v = (t >= off) ? sh[t - off] : 0;
    __syncthreads();
    sh[t] += v;
    __syncthreads();
  }
  if (i < N_NODES) {
    int st = bsum[blockIdx.x] + sh[t] - orig;
    start[i] = st;
    cursor[i] = st;
  }
}

__global__ void k_scatter(const int* __restrict__ src, const int* __restrict__ dst,
                          int* cursor, int2* __restrict__ eids) {
  int e = blockIdx.x * blockDim.x + threadIdx.x;
  if (e < N_EDGES) {
    int pos = atomicAdd(&cursor[dst[e]], 1);
    eids[pos] = make_int2(e, src[e]);
  }
}

// ---------------- CSR softmax-aggregation: one wave per node, 4 edges in parallel ----------------
// lane = ep(2b: edge slot) x fg(4b: feature group of 4); f16x4 loads; shfl-combine.
__global__ __launch_bounds__(256) void k_agg_csr(
    const _Float16* __restrict__ h, const _Float16* __restrict__ ea,
    const int2* __restrict__ eids, const int* __restrict__ start,
    const int* __restrict__ cnt, _Float16* __restrict__ hsum) {
  const int lane = threadIdx.x & 63;
  const int wid  = (int)((blockIdx.x * blockDim.x + threadIdx.x) >> 6);
  if (wid >= N_NODES) return;
  const int ep = lane >> 4, fg = lane & 15;
  const int s0 = start[wid], c = cnt[wid];
  f32x4 num = {0.f, 0.f, 0.f, 0.f}, den = {0.f, 0.f, 0.f, 0.f};
  if (c > 0) {
    const int nit = (c + 3) >> 2;
    // prefetch iters 0 and 1
    int idx = min(ep, c - 1);
    int2 e = eids[s0 + idx];
    f16x4 hA = *(const f16x4*)(h + (size_t)e.y * H + fg * 4);
    f16x4 eA = *(const f16x4*)(ea + (size_t)e.x * H + fg * 4);
    bool vA = (ep < c);
    f16x4 hB = hA, eB = eA;
    bool vB = false;
    if (nit > 1) {
      idx = min(4 + ep, c - 1);
      e = eids[s0 + idx];
      hB = *(const f16x4*)(h + (size_t)e.y * H + fg * 4);
      eB = *(const f16x4*)(ea + (size_t)e.x * H + fg * 4);
      vB = (4 + ep < c);
    }
    for (int i = 0; i < nit; ++i) {
      f16x4 hc = hA, ec = eA;
      bool vc = vA;
      hA = hB; eA = eB; vA = vB;
      if (i + 2 < nit) {
        idx = min((i + 2) * 4 + ep, c - 1);
        e = eids[s0 + idx];
        hB = *(const f16x4*)(h + (size_t)e.y * H + fg * 4);
        eB = *(const f16x4*)(ea + (size_t)e.x * H + fg * 4);
        vB = ((i + 2) * 4 + ep < c);
      }
#pragma unroll
      for (int j = 0; j < 4; ++j) {
        float m = fmaxf((float)hc[j] + (float)ec[j], 0.0f) + EPS_GEN;
        float ex = vc ? __expf(m) : 0.0f;
        num[j] = fmaf(m, ex, num[j]);
        den[j] += ex;
      }
    }
  }
  // combine the 4 edge slots (lanes fg, fg+16, fg+32, fg+48)
#pragma unroll
  for (int j = 0; j < 4; ++j) {
    num[j] += __shfl_xor(num[j], 16);
    num[j] += __shfl_xor(num[j], 32);
    den[j] += __shfl_xor(den[j], 16);
    den[j] += __shfl_xor(den[j], 32);
  }
  if (ep == 0) {
    f16x4 hs = *(const f16x4*)(h + (size_t)wid * H + fg * 4);
    f16x4 o;
#pragma unroll
    for (int j = 0; j < 4; ++j)
      o[j] = (_Float16)(num[j] / (den[j] + 1e-16f) + (float)hs[j]);
    *(f16x4*)(hsum + (size_t)wid * H + fg * 4) = o;
  }
}

// ---------------- BN stats (f16 input) ----------------
__global__ void k_bnstats(const _Float16* __restrict__ h3, float* sums) {
  int f = threadIdx.x & (H2 - 1);
  int half = threadIdx.x >> 7;
  float s = 0.0f, q = 0.0f;
  for (int n = blockIdx.x * 2 + half; n < N_NODES; n += gridDim.x * 2) {
    float v = (float)h3[(size_t)n * H2 + f];
    s += v;
    q = fmaf(v, v, q);
  }
  __shared__ float sh[2][2][H2];
  sh[0][half][f] = s;
  sh[1][half][f] = q;
  __syncthreads();
  if (threadIdx.x < H2) {
    atomAddF(&sums[f], sh[0][0][f] + sh[0][1][f]);
    atomAddF(&sums[H2 + f], sh[1][0][f] + sh[1][1][f]);
  }
}

// scsh[f] = rsqrt(var+eps)*g, scsh[128+f] = be - mu*sc
__global__ void k_bnfinal(const float* __restrict__ sums, const float* __restrict__ g,
                          const float* __restrict__ be, float* __restrict__ scsh) {
  int f = threadIdx.x;
  if (f < H2) {
    float mu  = sums[f] / (float)N_NODES;
    float var = sums[H2 + f] / (float)N_NODES - mu * mu;
    float sc  = rsqrtf(var + EPS_BN) * g[f];
    scsh[f] = sc;
    scsh[H2 + f] = be[f] - mu * sc;
  }
}

extern "C" void kernel_launch(void* const* d_in, const int* in_sizes, int n_in,
                              void* d_out, int out_size, void* d_ws, size_t ws_size,
                              hipStream_t stream) {
  (void)in_sizes; (void)n_in; (void)out_size; (void)ws_size;
  const float* x      = (const float*)d_in[0];
  const int*   eidx   = (const int*)d_in[1];
  const float* eattr  = (const float*)d_in[2];
  const float* node_W = (const float*)d_in[3];
  const float* node_b = (const float*)d_in[4];
  const float* edge_W = (const float*)d_in[5];
  const float* edge_b = (const float*)d_in[6];
  const float* c1_W1  = (const float*)d_in[7];
  const float* c1_g   = (const float*)d_in[8];
  const float* c1_be  = (const float*)d_in[9];
  const float* c1_W2  = (const float*)d_in[10];
  const float* c2_W1  = (const float*)d_in[11];
  const float* c2_g   = (const float*)d_in[12];
  const float* c2_be  = (const float*)d_in[13];
  const float* c2_W2  = (const float*)d_in[14];
  const float* l1_W   = (const float*)d_in[15];
  const float* l1_b   = (const float*)d_in[16];
  const float* l2_W   = (const float*)d_in[17];
  const float* l2_b   = (const float*)d_in[18];

  const int* src = eidx;
  const int* dst = eidx + N_EDGES;

  char* wsb = (char*)d_ws;
  size_t off = 0;
  _Float16* ea16  = (_Float16*)(wsb + off); off += (size_t)N_EDGES * H * 2;
  _Float16* hA16  = (_Float16*)(wsb + off); off += (size_t)N_NODES * H * 2;
  _Float16* hB16  = (_Float16*)(wsb + off); off += (size_t)N_NODES * H * 2;
  _Float16* hC16  = (_Float16*)(wsb + off); off += (size_t)N_NODES * H * 2;
  _Float16* hsum16= (_Float16*)(wsb + off); off += (size_t)N_NODES * H * 2;
  _Float16* h3    = (_Float16*)(wsb + off); off += (size_t)N_NODES * H2 * 2;
  float* sums     = (float*)(wsb + off);    off += 256 * 4;
  float* scsh     = (float*)(wsb + off);    off += 256 * 4;
  int* cnt        = (int*)(wsb + off);      off += (size_t)N_NODES * 4;
  int* startA     = (int*)(wsb + off);      off += (size_t)N_NODES * 4;
  int* cursor     = (int*)(wsb + off);      off += (size_t)N_NODES * 4;
  int* bsum       = (int*)(wsb + off);      off += 512 * 4;
  int2* eids      = (int2*)(wsb + off);     off += (size_t)N_EDGES * 8;
  _Float16* wE    = (_Float16*)(wsb + off); off += DE * H * 2;
  _Float16* wN    = (_Float16*)(wsb + off); off += DN * H * 2;
  _Float16* w1a   = (_Float16*)(wsb + off); off += H * H2 * 2;
  _Float16* w1b   = (_Float16*)(wsb + off); off += H * H2 * 2;
  _Float16* w2a   = (_Float16*)(wsb + off); off += H2 * H * 2;
  _Float16* w2b   = (_Float16*)(wsb + off); off += H2 * H * 2;
  _Float16* wL1   = (_Float16*)(wsb + off); off += 3 * H * H * 2;
  _Float16* wL2   = (_Float16*)(wsb + off); off += 3 * H * (H / 2) * 2;

  float* h_out  = (float*)d_out;                            // [N,64]
  float* ea_out = (float*)d_out + (size_t)N_NODES * H;      // [E,32]

  constexpr int NB = (N_NODES + 255) / 256;                 // 313 scan blocks

  // ---- one-time weight frag-images ----
  k_prep_w<<<DE * H / 256, 256, 0, stream>>>(edge_W, DE, H, wE);
  k_prep_w<<<DN * H / 256, 256, 0, stream>>>(node_W, DN, H, wN);
  k_prep_w<<<H * H2 / 256, 256, 0, stream>>>(c1_W1, H, H2, w1a);
  k_prep_w<<<H * H2 / 256, 256, 0, stream>>>(c2_W1, H, H2, w1b);
  k_prep_w<<<H2 * H / 256, 256, 0, stream>>>(c1_W2, H2, H, w2a);
  k_prep_w<<<H2 * H / 256, 256, 0, stream>>>(c2_W2, H2, H, w2b);
  k_prep_w<<<192 * H / 256, 256, 0, stream>>>(l1_W, 192, H, wL1);
  k_prep_w<<<192 * 32 / 256, 256, 0, stream>>>(l2_W, 192, 32, wL2);

  // ---- encoders ----
  k_dense<DE, H, false, false, true, false, true, false>
      <<<N_EDGES / 64, 256, 0, stream>>>(eattr, wE, edge_b, nullptr, ea16, nullptr);
  k_dense<DN, H, false, false, true, false, true, false>
      <<<N_NODES / 64, 256, 0, stream>>>(x, wN, node_b, nullptr, hA16, nullptr);

  // ---- build CSR once (shared by both conv layers) ----
  hipMemsetAsync(cnt, 0, N_NODES * 4, stream);
  k_hist<<<(N_EDGES + 255) / 256, 256, 0, stream>>>(dst, cnt);
  k_scan_blk<<<NB, 256, 0, stream>>>(cnt, bsum);
  k_scan_top<<<1, 512, 0, stream>>>(bsum, NB);
  k_scan_fin<<<NB, 256, 0, stream>>>(cnt, bsum, startA, cursor);
  k_scatter<<<(N_EDGES + 255) / 256, 256, 0, stream>>>(src, dst, cursor, eids);

  // ---- conv layer 1 ----
  hipMemsetAsync(sums, 0, 256 * 4, stream);
  k_agg_csr<<<(N_NODES + 3) / 4, 256, 0, stream>>>(hA16, ea16, eids, startA, cnt, hsum16);
  k_dense<H, H2, true, false, false, false, true, false>
      <<<N_NODES / 64, 256, 0, stream>>>(hsum16, w1a, nullptr, nullptr, h3, nullptr);
  k_bnstats<<<1280, 256, 0, stream>>>(h3, sums);
  k_bnfinal<<<1, 128, 0, stream>>>(sums, c1_g, c1_be, scsh);
  k_dense<H2, H, true, true, false, true, true, false>
      <<<N_NODES / 64, 256, 0, stream>>>(h3, w2a, nullptr, scsh, hB16, nullptr);
  k_edge_upd_reg<64, _Float16>
      <<<N_EDGES / 64, 256, 0, stream>>>(hB16, ea16, src, dst, wL1, l1_b, ea16);  // in-place

  // ---- conv layer 2 ----
  hipMemsetAsync(sums, 0, 256 * 4, stream);
  k_agg_csr<<<(N_NODES + 3) / 4, 256, 0, stream>>>(hB16, ea16, eids, startA, cnt, hsum16);
  k_dense<H, H2, true, false, false, false, true, false>
      <<<N_NODES / 64, 256, 0, stream>>>(hsum16, w1b, nullptr, nullptr, h3, nullptr);
  k_bnstats<<<1280, 256, 0, stream>>>(h3, sums);
  k_bnfinal<<<1, 128, 0, stream>>>(sums, c2_g, c2_be, scsh);
  k_dense<H2, H, true, true, false, true, true, true>
      <<<N_NODES / 64, 256, 0, stream>>>(h3, w2b, nullptr, scsh, hC16, h_out);
  k_edge_upd_reg<32, float>
      <<<N_EDGES / 64, 256, 0, stream>>>(hC16, ea16, src, dst, wL2, l2_b, ea_out);
}

// Round 7
// 729.908 us; speedup vs baseline: 7.6672x; 1.1013x over previous
//
#include <hip/hip_runtime.h>
#include <hip/hip_bf16.h>

#define N_NODES 80000
#define N_EDGES 1280000
constexpr int DN = 128;   // node input dim
constexpr int DE = 32;    // edge input dim
constexpr int H  = 64;    // hidden
constexpr int H2 = 128;   // 2*hidden
constexpr float EPS_GEN = 1e-7f;
constexpr float EPS_BN  = 1e-5f;

typedef _Float16 f16x8 __attribute__((ext_vector_type(8)));
typedef _Float16 f16x4 __attribute__((ext_vector_type(4)));
typedef float f32x4 __attribute__((ext_vector_type(4)));

__device__ __forceinline__ void atomAddF(float* p, float v) {
  __hip_atomic_fetch_add(p, v, __ATOMIC_RELAXED, __HIP_MEMORY_SCOPE_AGENT);
}

// ---------------- weight prep: f32 [K][OC] -> f16 frag-image ----------------
// slab (n2*NK+kk) of 512 halves; element ((kg*16+m16)*8+j) = W[kk*32+kg*8+j][n2*16+m16]
__global__ void k_prep_w(const float* __restrict__ W, int K, int OC,
                         _Float16* __restrict__ img) {
  int idx = blockIdx.x * 256 + threadIdx.x;   // < K*OC
  int nslabK = K >> 5;
  int j = idx & 7, m16 = (idx >> 3) & 15, kg = (idx >> 7) & 3;
  int slab = idx >> 9;
  int kk = slab % nslabK, n2 = slab / nslabK;
  int k = kk * 32 + kg * 8 + j, n = n2 * 16 + m16;
  img[idx] = (_Float16)W[k * OC + n];
}

// ---------------- generic dense MFMA: out[row,:] = f(A[row,:]) @ W + b ----------------
template <int K, int OC, bool IN16, bool AFFINE, bool BIAS, bool RELU_OUT, bool OUT16, bool OUT32>
__global__ __launch_bounds__(256) void k_dense(
    const void* __restrict__ Ain, const _Float16* __restrict__ wimg,
    const float* __restrict__ bias, const float* __restrict__ scsh,
    _Float16* __restrict__ out16, float* __restrict__ out32) {
  constexpr int NK = K / 32, NF = OC / 16;
  const int tid = threadIdx.x, wv = tid >> 6, lane = tid & 63;
  const int m16 = lane & 15, kg = lane >> 4;
  const int rowbase = blockIdx.x * 64 + wv * 16;
  f32x4 acc[NF];
#pragma unroll
  for (int n2 = 0; n2 < NF; ++n2) {
    float bv = BIAS ? bias[n2 * 16 + m16] : 0.0f;
    acc[n2] = (f32x4){bv, bv, bv, bv};
  }
  const _Float16* wp = wimg + (size_t)lane * 8;
#pragma unroll
  for (int kk = 0; kk < NK; ++kk) {
    f16x8 a;
    if constexpr (IN16) {
      const _Float16* ap = (const _Float16*)Ain + (size_t)(rowbase + m16) * K + kg * 8 + kk * 32;
      a = *(const f16x8*)ap;
      if constexpr (AFFINE) {
        const float* scp = scsh + kg * 8 + kk * 32;
#pragma unroll
        for (int j = 0; j < 8; ++j) {
          float v = fmaxf(fmaf((float)a[j], scp[j], scp[H2 + j]), 0.0f);
          a[j] = (_Float16)v;
        }
      }
    } else {
      const float* ap = (const float*)Ain + (size_t)(rowbase + m16) * K + kg * 8 + kk * 32;
      float4 v0 = *(const float4*)ap;
      float4 v1 = *(const float4*)(ap + 4);
      a = (f16x8){(_Float16)v0.x, (_Float16)v0.y, (_Float16)v0.z, (_Float16)v0.w,
                  (_Float16)v1.x, (_Float16)v1.y, (_Float16)v1.z, (_Float16)v1.w};
    }
#pragma unroll
    for (int n2 = 0; n2 < NF; ++n2) {
      f16x8 bb = *(const f16x8*)(wp + ((size_t)(n2 * NK + kk) << 9));
      acc[n2] = __builtin_amdgcn_mfma_f32_16x16x32_f16(a, bb, acc[n2], 0, 0, 0);
    }
  }
#pragma unroll
  for (int n2 = 0; n2 < NF; ++n2)
#pragma unroll
    for (int r = 0; r < 4; ++r) {
      float o = acc[n2][r];
      if constexpr (RELU_OUT) o = fmaxf(o, 0.0f);
      size_t oi = (size_t)(rowbase + kg * 4 + r) * OC + n2 * 16 + m16;
      if constexpr (OUT16) out16[oi] = (_Float16)o;
      if constexpr (OUT32) out32[oi] = o;
    }
}

// ---------------- edge update: T tiles/block, B in LDS, A double-buffered ----------------
template <int OC, typename OUT_T, int T>
__global__ __launch_bounds__(256) void k_edge_upd_reg(
    const _Float16* __restrict__ h, const _Float16* __restrict__ ea,
    const int* __restrict__ src, const int* __restrict__ dst,
    const _Float16* __restrict__ wimg, const float* __restrict__ lb,
    OUT_T* __restrict__ eout) {
  constexpr int NF = OC / 16;
  __shared__ _Float16 sWf[NF * 6 * 512];   // frag-image copy; OC=64: 24576 B
  const int tid = threadIdx.x, wv = tid >> 6, lane = tid & 63;
  const int m16 = lane & 15, kg = lane >> 4;

  {  // stage B: linear copy (wimg already frag-ordered)
    const float4* s4 = (const float4*)wimg;
    float4* d4 = (float4*)sWf;
    constexpr int NV = NF * 6 * 512 / 8;
    for (int i = tid; i < NV; i += 256) d4[i] = s4[i];
  }
  __syncthreads();
  const _Float16* wp = sWf + (size_t)lane * 8;

  float bias_[NF];
#pragma unroll
  for (int n2 = 0; n2 < NF; ++n2) bias_[n2] = lb[n2 * 16 + m16];

  const int off = wv * 16 + m16;
  const int t0 = blockIdx.x * T;

  f16x8 FA[6], FB[6];

  auto LOADA = [&](f16x8* F, int row, int s, int d) {
    const _Float16* a0 = h + (size_t)s * H + kg * 8;
    const _Float16* a1 = ea + (size_t)row * H + kg * 8;
    const _Float16* a2 = h + (size_t)d * H + kg * 8;
    F[0] = *(const f16x8*)a0;
    F[1] = *(const f16x8*)(a0 + 32);
    F[2] = *(const f16x8*)a1;
    F[3] = *(const f16x8*)(a1 + 32);
    F[4] = *(const f16x8*)a2;
    F[5] = *(const f16x8*)(a2 + 32);
  };
  auto COMPUTE = [&](const f16x8* F, int row) {
    f32x4 acc[NF];
#pragma unroll
    for (int n2 = 0; n2 < NF; ++n2)
      acc[n2] = (f32x4){bias_[n2], bias_[n2], bias_[n2], bias_[n2]};
#pragma unroll
    for (int kk = 0; kk < 6; ++kk)
#pragma unroll
      for (int n2 = 0; n2 < NF; ++n2) {
        f16x8 bb = *(const f16x8*)(wp + ((n2 * 6 + kk) << 9));
        acc[n2] = __builtin_amdgcn_mfma_f32_16x16x32_f16(F[kk], bb, acc[n2], 0, 0, 0);
      }
    const int rowbase = row - m16;
#pragma unroll
    for (int n2 = 0; n2 < NF; ++n2)
#pragma unroll
      for (int r = 0; r < 4; ++r)
        eout[(size_t)(rowbase + kg * 4 + r) * OC + n2 * 16 + m16] = (OUT_T)acc[n2][r];
  };

  int rA = t0 * 64 + off;
  { int s = src[rA], d = dst[rA]; LOADA(FA, rA, s, d); }
  int rB = rA + 64;
  int sN = src[rB], dN = dst[rB];          // idx of tile t0+1 (T>=2)

#pragma unroll
  for (int i = 0; i < T; i += 2) {
    // phase 1: frags(tile i+1) <- FB; idx(tile i+2); compute tile i (FA)
    LOADA(FB, rB, sN, dN);
    int rC = rB + 64, sC = 0, dC = 0;
    if (i + 2 < T) { sC = src[rC]; dC = dst[rC]; }
    COMPUTE(FA, rA);
    // phase 2: frags(tile i+2) <- FA; idx(tile i+3); compute tile i+1 (FB)
    if (i + 2 < T) LOADA(FA, rC, sC, dC);
    int rD = rC + 64, sD = 0, dD = 0;
    if (i + 3 < T) { sD = src[rD]; dD = dst[rD]; }
    COMPUTE(FB, rB);
    rA = rC; rB = rD; sN = sD; dN = dD;
  }
}

// ---------------- CSR build: histogram -> scan -> scatter ----------------
__global__ void k_hist(const int* __restrict__ dst, int* cnt) {
  int e = blockIdx.x * blockDim.x + threadIdx.x;
  if (e < N_EDGES) atomicAdd(&cnt[dst[e]], 1);
}

__global__ void k_scan_blk(const int* __restrict__ cnt, int* __restrict__ bsum) {
  __shared__ int sh[256];
  int i = blockIdx.x * 256 + threadIdx.x;
  sh[threadIdx.x] = (i < N_NODES) ? cnt[i] : 0;
  __syncthreads();
  for (int s = 128; s > 0; s >>= 1) {
    if (threadIdx.x < s) sh[threadIdx.x] += sh[threadIdx.x + s];
    __syncthreads();
  }
  if (threadIdx.x == 0) bsum[blockIdx.x] = sh[0];
}

__global__ void k_scan_top(int* bsum, int nb) {  // 1 block x 512, exclusive scan
  __shared__ int sh[512];
  int t = threadIdx.x;
  int orig = (t < nb) ? bsum[t] : 0;
  sh[t] = orig;
  __syncthreads();
  for (int off = 1; off < 512; off <<= 1) {
    int v = (t >= off) ? sh[t - off] : 0;
    __syncthreads();
    sh[t] += v;
    __syncthreads();
  }
  if (t < nb) bsum[t] = sh[t] - orig;
}

__global__ void k_scan_fin(const int* __restrict__ cnt, const int* __restrict__ bsum,
                           int* __restrict__ start, int* __restrict__ cursor) {
  __shared__ int sh[256];
  int i = blockIdx.x * 256 + threadIdx.x;
  int t = threadIdx.x;
  int orig = (i < N_NODES) ? cnt[i] : 0;
  sh[t] = orig;
  __syncthreads();
  for (int off = 1; off < 256; off <<= 1) {
    int v = (t >= off) ? sh[t - off] : 0;
    __syncthreads();
    sh[t] += v;
    __syncthreads();
  }
  if (i < N_NODES) {
    int st = bsum[blockIdx.x] + sh[t] - orig;
    start[i] = st;
    cursor[i] = st;
  }
}

__global__ void k_scatter(const int* __restrict__ src, const int* __restrict__ dst,
                          int* cursor, int2* __restrict__ eids) {
  int e = blockIdx.x * blockDim.x + threadIdx.x;
  if (e < N_EDGES) {
    int pos = atomicAdd(&cursor[dst[e]], 1);
    eids[pos] = make_int2(e, src[e]);
  }
}

// ---------------- CSR softmax-aggregation: one wave per node, 8 edges in parallel ----------------
// lane = ep(3b: edge slot) x fg(3b: feature group of 8); f16x8 loads; shfl-combine.
__global__ __launch_bounds__(256) void k_agg_csr(
    const _Float16* __restrict__ h, const _Float16* __restrict__ ea,
    const int2* __restrict__ eids, const int* __restrict__ start,
    const int* __restrict__ cnt, _Float16* __restrict__ hsum) {
  const int lane = threadIdx.x & 63;
  const int wid  = (int)((blockIdx.x * blockDim.x + threadIdx.x) >> 6);
  if (wid >= N_NODES) return;
  const int ep = lane >> 3, fg = lane & 7;
  const int s0 = start[wid], c = cnt[wid];
  float num[8] = {0.f, 0.f, 0.f, 0.f, 0.f, 0.f, 0.f, 0.f};
  float den[8] = {0.f, 0.f, 0.f, 0.f, 0.f, 0.f, 0.f, 0.f};
  if (c > 0) {
    const int nit = (c + 7) >> 3;
    int idx = min(ep, c - 1);
    int2 e = eids[s0 + idx];
    f16x8 hA = *(const f16x8*)(h + (size_t)e.y * H + fg * 8);
    f16x8 eA = *(const f16x8*)(ea + (size_t)e.x * H + fg * 8);
    bool vA = (ep < c);
    f16x8 hB = hA, eB = eA;
    bool vB = false;
    if (nit > 1) {
      idx = min(8 + ep, c - 1);
      e = eids[s0 + idx];
      hB = *(const f16x8*)(h + (size_t)e.y * H + fg * 8);
      eB = *(const f16x8*)(ea + (size_t)e.x * H + fg * 8);
      vB = (8 + ep < c);
    }
    for (int i = 0; i < nit; ++i) {
      f16x8 hc = hA, ec = eA;
      bool vc = vA;
      hA = hB; eA = eB; vA = vB;
      if (i + 2 < nit) {
        idx = min((i + 2) * 8 + ep, c - 1);
        e = eids[s0 + idx];
        hB = *(const f16x8*)(h + (size_t)e.y * H + fg * 8);
        eB = *(const f16x8*)(ea + (size_t)e.x * H + fg * 8);
        vB = ((i + 2) * 8 + ep < c);
      }
#pragma unroll
      for (int j = 0; j < 8; ++j) {
        float m = fmaxf((float)hc[j] + (float)ec[j], 0.0f) + EPS_GEN;
        float ex = vc ? __expf(m) : 0.0f;
        num[j] = fmaf(m, ex, num[j]);
        den[j] += ex;
      }
    }
  }
#pragma unroll
  for (int j = 0; j < 8; ++j) {
    num[j] += __shfl_xor(num[j], 8);
    num[j] += __shfl_xor(num[j], 16);
    num[j] += __shfl_xor(num[j], 32);
    den[j] += __shfl_xor(den[j], 8);
    den[j] += __shfl_xor(den[j], 16);
    den[j] += __shfl_xor(den[j], 32);
  }
  if (ep == 0) {
    f16x8 hs = *(const f16x8*)(h + (size_t)wid * H + fg * 8);
    f16x8 o;
#pragma unroll
    for (int j = 0; j < 8; ++j)
      o[j] = (_Float16)(num[j] / (den[j] + 1e-16f) + (float)hs[j]);
    *(f16x8*)(hsum + (size_t)wid * H + fg * 8) = o;
  }
}

// ---------------- BN stats (f16 input) ----------------
__global__ void k_bnstats(const _Float16* __restrict__ h3, float* sums) {
  int f = threadIdx.x & (H2 - 1);
  int half = threadIdx.x >> 7;
  float s = 0.0f, q = 0.0f;
  for (int n = blockIdx.x * 2 + half; n < N_NODES; n += gridDim.x * 2) {
    float v = (float)h3[(size_t)n * H2 + f];
    s += v;
    q = fmaf(v, v, q);
  }
  __shared__ float sh[2][2][H2];
  sh[0][half][f] = s;
  sh[1][half][f] = q;
  __syncthreads();
  if (threadIdx.x < H2) {
    atomAddF(&sums[f], sh[0][0][f] + sh[0][1][f]);
    atomAddF(&sums[H2 + f], sh[1][0][f] + sh[1][1][f]);
  }
}

// scsh[f] = rsqrt(var+eps)*g, scsh[128+f] = be - mu*sc
__global__ void k_bnfinal(const float* __restrict__ sums, const float* __restrict__ g,
                          const float* __restrict__ be, float* __restrict__ scsh) {
  int f = threadIdx.x;
  if (f < H2) {
    float mu  = sums[f] / (float)N_NODES;
    float var = sums[H2 + f] / (float)N_NODES - mu * mu;
    float sc  = rsqrtf(var + EPS_BN) * g[f];
    scsh[f] = sc;
    scsh[H2 + f] = be[f] - mu * sc;
  }
}

extern "C" void kernel_launch(void* const* d_in, const int* in_sizes, int n_in,
                              void* d_out, int out_size, void* d_ws, size_t ws_size,
                              hipStream_t stream) {
  (void)in_sizes; (void)n_in; (void)out_size; (void)ws_size;
  const float* x      = (const float*)d_in[0];
  const int*   eidx   = (const int*)d_in[1];
  const float* eattr  = (const float*)d_in[2];
  const float* node_W = (const float*)d_in[3];
  const float* node_b = (const float*)d_in[4];
  const float* edge_W = (const float*)d_in[5];
  const float* edge_b = (const float*)d_in[6];
  const float* c1_W1  = (const float*)d_in[7];
  const float* c1_g   = (const float*)d_in[8];
  const float* c1_be  = (const float*)d_in[9];
  const float* c1_W2  = (const float*)d_in[10];
  const float* c2_W1  = (const float*)d_in[11];
  const float* c2_g   = (const float*)d_in[12];
  const float* c2_be  = (const float*)d_in[13];
  const float* c2_W2  = (const float*)d_in[14];
  const float* l1_W   = (const float*)d_in[15];
  const float* l1_b   = (const float*)d_in[16];
  const float* l2_W   = (const float*)d_in[17];
  const float* l2_b   = (const float*)d_in[18];

  const int* src = eidx;
  const int* dst = eidx + N_EDGES;

  char* wsb = (char*)d_ws;
  size_t off = 0;
  _Float16* ea16  = (_Float16*)(wsb + off); off += (size_t)N_EDGES * H * 2;
  _Float16* hA16  = (_Float16*)(wsb + off); off += (size_t)N_NODES * H * 2;
  _Float16* hB16  = (_Float16*)(wsb + off); off += (size_t)N_NODES * H * 2;
  _Float16* hC16  = (_Float16*)(wsb + off); off += (size_t)N_NODES * H * 2;
  _Float16* hsum16= (_Float16*)(wsb + off); off += (size_t)N_NODES * H * 2;
  _Float16* h3    = (_Float16*)(wsb + off); off += (size_t)N_NODES * H2 * 2;
  float* sums     = (float*)(wsb + off);    off += 256 * 4;
  float* scsh     = (float*)(wsb + off);    off += 256 * 4;
  int* cnt        = (int*)(wsb + off);      off += (size_t)N_NODES * 4;
  int* startA     = (int*)(wsb + off);      off += (size_t)N_NODES * 4;
  int* cursor     = (int*)(wsb + off);      off += (size_t)N_NODES * 4;
  int* bsum       = (int*)(wsb + off);      off += 512 * 4;
  int2* eids      = (int2*)(wsb + off);     off += (size_t)N_EDGES * 8;
  _Float16* wE    = (_Float16*)(wsb + off); off += DE * H * 2;
  _Float16* wN    = (_Float16*)(wsb + off); off += DN * H * 2;
  _Float16* w1a   = (_Float16*)(wsb + off); off += H * H2 * 2;
  _Float16* w1b   = (_Float16*)(wsb + off); off += H * H2 * 2;
  _Float16* w2a   = (_Float16*)(wsb + off); off += H2 * H * 2;
  _Float16* w2b   = (_Float16*)(wsb + off); off += H2 * H * 2;
  _Float16* wL1   = (_Float16*)(wsb + off); off += 3 * H * H * 2;
  _Float16* wL2   = (_Float16*)(wsb + off); off += 3 * H * (H / 2) * 2;

  float* h_out  = (float*)d_out;                            // [N,64]
  float* ea_out = (float*)d_out + (size_t)N_NODES * H;      // [E,32]

  constexpr int NB = (N_NODES + 255) / 256;                 // 313 scan blocks

  // ---- one-time weight frag-images ----
  k_prep_w<<<DE * H / 256, 256, 0, stream>>>(edge_W, DE, H, wE);
  k_prep_w<<<DN * H / 256, 256, 0, stream>>>(node_W, DN, H, wN);
  k_prep_w<<<H * H2 / 256, 256, 0, stream>>>(c1_W1, H, H2, w1a);
  k_prep_w<<<H * H2 / 256, 256, 0, stream>>>(c2_W1, H, H2, w1b);
  k_prep_w<<<H2 * H / 256, 256, 0, stream>>>(c1_W2, H2, H, w2a);
  k_prep_w<<<H2 * H / 256, 256, 0, stream>>>(c2_W2, H2, H, w2b);
  k_prep_w<<<192 * H / 256, 256, 0, stream>>>(l1_W, 192, H, wL1);
  k_prep_w<<<192 * 32 / 256, 256, 0, stream>>>(l2_W, 192, 32, wL2);

  // ---- encoders ----
  k_dense<DE, H, false, false, true, false, true, false>
      <<<N_EDGES / 64, 256, 0, stream>>>(eattr, wE, edge_b, nullptr, ea16, nullptr);
  k_dense<DN, H, false, false, true, false, true, false>
      <<<N_NODES / 64, 256, 0, stream>>>(x, wN, node_b, nullptr, hA16, nullptr);

  // ---- build CSR once (shared by both conv layers) ----
  hipMemsetAsync(cnt, 0, N_NODES * 4, stream);
  k_hist<<<(N_EDGES + 255) / 256, 256, 0, stream>>>(dst, cnt);
  k_scan_blk<<<NB, 256, 0, stream>>>(cnt, bsum);
  k_scan_top<<<1, 512, 0, stream>>>(bsum, NB);
  k_scan_fin<<<NB, 256, 0, stream>>>(cnt, bsum, startA, cursor);
  k_scatter<<<(N_EDGES + 255) / 256, 256, 0, stream>>>(src, dst, cursor, eids);

  // ---- conv layer 1 ----
  hipMemsetAsync(sums, 0, 256 * 4, stream);
  k_agg_csr<<<(N_NODES + 3) / 4, 256, 0, stream>>>(hA16, ea16, eids, startA, cnt, hsum16);
  k_dense<H, H2, true, false, false, false, true, false>
      <<<N_NODES / 64, 256, 0, stream>>>(hsum16, w1a, nullptr, nullptr, h3, nullptr);
  k_bnstats<<<1280, 256, 0, stream>>>(h3, sums);
  k_bnfinal<<<1, 128, 0, stream>>>(sums, c1_g, c1_be, scsh);
  k_dense<H2, H, true, true, false, true, true, false>
      <<<N_NODES / 64, 256, 0, stream>>>(h3, w2a, nullptr, scsh, hB16, nullptr);
  k_edge_upd_reg<64, _Float16, 8>
      <<<N_EDGES / 64 / 8, 256, 0, stream>>>(hB16, ea16, src, dst, wL1, l1_b, ea16);  // in-place

  // ---- conv layer 2 ----
  hipMemsetAsync(sums, 0, 256 * 4, stream);
  k_agg_csr<<<(N_NODES + 3) / 4, 256, 0, stream>>>(hB16, ea16, eids, startA, cnt, hsum16);
  k_dense<H, H2, true, false, false, false, true, false>
      <<<N_NODES / 64, 256, 0, stream>>>(hsum16, w1b, nullptr, nullptr, h3, nullptr);
  k_bnstats<<<1280, 256, 0, stream>>>(h3, sums);
  k_bnfinal<<<1, 128, 0, stream>>>(sums, c2_g, c2_be, scsh);
  k_dense<H2, H, true, true, false, true, true, true>
      <<<N_NODES / 64, 256, 0, stream>>>(h3, w2b, nullptr, scsh, hC16, h_out);
  k_edge_upd_reg<32, float, 8>
      <<<N_EDGES / 64 / 8, 256, 0, stream>>>(hC16, ea16, src, dst, wL2, l2_b, ea_out);
}

// Round 8
// 686.316 us; speedup vs baseline: 8.1542x; 1.0635x over previous
//
#include <hip/hip_runtime.h>
#include <hip/hip_bf16.h>

#define N_NODES 80000
#define N_EDGES 1280000
constexpr int DN = 128;   // node input dim
constexpr int DE = 32;    // edge input dim
constexpr int H  = 64;    // hidden
constexpr int H2 = 128;   // 2*hidden
constexpr float EPS_GEN = 1e-7f;
constexpr float EPS_BN  = 1e-5f;

typedef _Float16 f16x8 __attribute__((ext_vector_type(8)));
typedef _Float16 f16x4 __attribute__((ext_vector_type(4)));
typedef float f32x4 __attribute__((ext_vector_type(4)));

__device__ __forceinline__ void atomAddF(float* p, float v) {
  __hip_atomic_fetch_add(p, v, __ATOMIC_RELAXED, __HIP_MEMORY_SCOPE_AGENT);
}

// ---------------- weight prep (all matrices, one dispatch) ----------------
// frag-image: slab (n2*NK+kk) of 512 halves; elem ((kg*16+m16)*8+j) = W[kk*32+kg*8+j][n2*16+m16]
struct PrepDesc { const float* W; _Float16* img; int K; int OC; int blkStart; };
struct PrepAll { PrepDesc d[8]; };

__global__ void k_prep_all(PrepAll P) {
  int b = blockIdx.x;
  int i = 0;
#pragma unroll
  for (int t = 1; t < 8; ++t)
    if (P.d[t].blkStart <= b) i = t;
  const PrepDesc D = P.d[i];
  int idx = (b - D.blkStart) * 256 + threadIdx.x;
  if (idx >= D.K * D.OC) return;
  int nslabK = D.K >> 5;
  int j = idx & 7, m16 = (idx >> 3) & 15, kg = (idx >> 7) & 3;
  int slab = idx >> 9;
  int kk = slab % nslabK, n2 = slab / nslabK;
  int k = kk * 32 + kg * 8 + j, n = n2 * 16 + m16;
  D.img[idx] = (_Float16)D.W[k * D.OC + n];
}

// ---------------- generic dense MFMA: out[row,:] = f(A[arow,:]) @ W + b ----------------
// GATHER: arow = eids[row].x (sorted-position processing). AFFINE: BN affine from sums (in-block).
template <int K, int OC, bool GATHER, bool IN16, bool AFFINE, bool BIAS,
          bool RELU_OUT, bool OUT16, bool OUT32, bool CLRS>
__global__ __launch_bounds__(256) void k_dense(
    const void* __restrict__ Ain, const _Float16* __restrict__ wimg,
    const float* __restrict__ bias, const float* __restrict__ sums,
    const float* __restrict__ g, const float* __restrict__ be,
    const int2* __restrict__ eids,
    _Float16* __restrict__ out16, float* __restrict__ out32,
    float* __restrict__ sums_clr) {
  constexpr int NK = K / 32, NF = OC / 16;
  __shared__ float sSC[H2], sSH[H2];
  const int tid = threadIdx.x, wv = tid >> 6, lane = tid & 63;
  const int m16 = lane & 15, kg = lane >> 4;
  const int rowbase = blockIdx.x * 64 + wv * 16;
  if constexpr (CLRS) {
    if (blockIdx.x == 0) sums_clr[tid] = 0.0f;   // 256 floats, grid>=1 block
  }
  if constexpr (AFFINE) {
    for (int i = tid; i < H2; i += 256) {
      float mu  = sums[i] * (1.0f / N_NODES);
      float var = sums[H2 + i] * (1.0f / N_NODES) - mu * mu;
      float sc  = rsqrtf(var + EPS_BN) * g[i];
      sSC[i] = sc;
      sSH[i] = be[i] - mu * sc;
    }
    __syncthreads();
  }
  int arow = rowbase + m16;
  if constexpr (GATHER) arow = eids[arow].x;
  f32x4 acc[NF];
#pragma unroll
  for (int n2 = 0; n2 < NF; ++n2) {
    float bv = BIAS ? bias[n2 * 16 + m16] : 0.0f;
    acc[n2] = (f32x4){bv, bv, bv, bv};
  }
  const _Float16* wp = wimg + (size_t)lane * 8;
#pragma unroll
  for (int kk = 0; kk < NK; ++kk) {
    f16x8 a;
    if constexpr (IN16) {
      const _Float16* ap = (const _Float16*)Ain + (size_t)arow * K + kg * 8 + kk * 32;
      a = *(const f16x8*)ap;
      if constexpr (AFFINE) {
#pragma unroll
        for (int j = 0; j < 8; ++j) {
          int f = kg * 8 + kk * 32 + j;
          float v = fmaxf(fmaf((float)a[j], sSC[f], sSH[f]), 0.0f);
          a[j] = (_Float16)v;
        }
      }
    } else {
      const float* ap = (const float*)Ain + (size_t)arow * K + kg * 8 + kk * 32;
      float4 v0 = *(const float4*)ap;
      float4 v1 = *(const float4*)(ap + 4);
      a = (f16x8){(_Float16)v0.x, (_Float16)v0.y, (_Float16)v0.z, (_Float16)v0.w,
                  (_Float16)v1.x, (_Float16)v1.y, (_Float16)v1.z, (_Float16)v1.w};
    }
#pragma unroll
    for (int n2 = 0; n2 < NF; ++n2) {
      f16x8 bb = *(const f16x8*)(wp + ((size_t)(n2 * NK + kk) << 9));
      acc[n2] = __builtin_amdgcn_mfma_f32_16x16x32_f16(a, bb, acc[n2], 0, 0, 0);
    }
  }
#pragma unroll
  for (int n2 = 0; n2 < NF; ++n2)
#pragma unroll
    for (int r = 0; r < 4; ++r) {
      float o = acc[n2][r];
      if constexpr (RELU_OUT) o = fmaxf(o, 0.0f);
      size_t oi = (size_t)(rowbase + kg * 4 + r) * OC + n2 * 16 + m16;
      if constexpr (OUT16) out16[oi] = (_Float16)o;
      if constexpr (OUT32) out32[oi] = o;
    }
}

// ---------------- edge update on sorted positions: T tiles/block ----------------
// pos-range [p0, p0+T*64); ea_s streamed (in-place for OC=64); SCAT: write out[e] scattered.
template <int OC, typename OUT_T, int T, bool SCAT>
__global__ __launch_bounds__(256) void k_edge_upd_srt(
    const _Float16* __restrict__ h, const _Float16* __restrict__ ea,
    const int2* __restrict__ eids, const int* __restrict__ dstS,
    const _Float16* __restrict__ wimg, const float* __restrict__ lb,
    OUT_T* __restrict__ eout) {
  constexpr int NF = OC / 16;
  __shared__ _Float16 sWf[NF * 6 * 512];
  __shared__ int sS[T * 64], sD[T * 64];
  __shared__ int sE[SCAT ? T * 64 : 1];
  const int tid = threadIdx.x, wv = tid >> 6, lane = tid & 63;
  const int m16 = lane & 15, kg = lane >> 4;
  const int p0 = blockIdx.x * (T * 64);

  for (int i = tid; i < T * 64; i += 256) {
    int2 t = eids[p0 + i];
    sS[i] = t.y;
    sD[i] = dstS[p0 + i];
    if constexpr (SCAT) sE[i] = t.x;
  }
  {  // stage weights: linear copy (frag-ordered)
    const float4* s4 = (const float4*)wimg;
    float4* d4 = (float4*)sWf;
    constexpr int NV = NF * 6 * 512 / 8;
    for (int i = tid; i < NV; i += 256) d4[i] = s4[i];
  }
  __syncthreads();
  const _Float16* wp = sWf + (size_t)lane * 8;

  float bias_[NF];
#pragma unroll
  for (int n2 = 0; n2 < NF; ++n2) bias_[n2] = lb[n2 * 16 + m16];

  f16x8 FA[6], FB[6];
  auto LOADA = [&](f16x8* F, int l) {        // l = local row (pos - p0)
    const _Float16* a0 = h + (size_t)sS[l] * H + kg * 8;
    const _Float16* a1 = ea + (size_t)(p0 + l) * H + kg * 8;
    const _Float16* a2 = h + (size_t)sD[l] * H + kg * 8;
    F[0] = *(const f16x8*)a0;
    F[1] = *(const f16x8*)(a0 + 32);
    F[2] = *(const f16x8*)a1;
    F[3] = *(const f16x8*)(a1 + 32);
    F[4] = *(const f16x8*)a2;
    F[5] = *(const f16x8*)(a2 + 32);
  };
  auto COMPUTE = [&](const f16x8* F, int l) {
    f32x4 acc[NF];
#pragma unroll
    for (int n2 = 0; n2 < NF; ++n2)
      acc[n2] = (f32x4){bias_[n2], bias_[n2], bias_[n2], bias_[n2]};
#pragma unroll
    for (int kk = 0; kk < 6; ++kk)
#pragma unroll
      for (int n2 = 0; n2 < NF; ++n2) {
        f16x8 bb = *(const f16x8*)(wp + ((n2 * 6 + kk) << 9));
        acc[n2] = __builtin_amdgcn_mfma_f32_16x16x32_f16(F[kk], bb, acc[n2], 0, 0, 0);
      }
    const int lbase = l - m16;
#pragma unroll
    for (int n2 = 0; n2 < NF; ++n2)
#pragma unroll
      for (int r = 0; r < 4; ++r) {
        int lr = lbase + kg * 4 + r;
        int col = n2 * 16 + m16;
        if constexpr (SCAT)
          eout[(size_t)sE[lr] * OC + col] = (OUT_T)acc[n2][r];
        else
          eout[(size_t)(p0 + lr) * OC + col] = (OUT_T)acc[n2][r];
      }
  };

  const int l0 = wv * 16 + m16;
  LOADA(FA, l0);
  if (T > 1) LOADA(FB, l0 + 64);
#pragma unroll
  for (int t = 0; t < T; ++t) {
    if (t & 1) {
      COMPUTE(FB, l0 + t * 64);
      if (t + 2 < T) LOADA(FB, l0 + (t + 2) * 64);
    } else {
      COMPUTE(FA, l0 + t * 64);
      if (t + 2 < T) LOADA(FA, l0 + (t + 2) * 64);
    }
  }
}

// ---------------- CSR build: histogram -> scan -> scatter ----------------
__global__ void k_hist(const int* __restrict__ dst, int* cnt) {
  int e = blockIdx.x * blockDim.x + threadIdx.x;
  if (e < N_EDGES) atomicAdd(&cnt[dst[e]], 1);
}

__global__ void k_scan_blk(const int* __restrict__ cnt, int* __restrict__ bsum) {
  __shared__ int sh[256];
  int i = blockIdx.x * 256 + threadIdx.x;
  sh[threadIdx.x] = (i < N_NODES) ? cnt[i] : 0;
  __syncthreads();
  for (int s = 128; s > 0; s >>= 1) {
    if (threadIdx.x < s) sh[threadIdx.x] += sh[threadIdx.x + s];
    __syncthreads();
  }
  if (threadIdx.x == 0) bsum[blockIdx.x] = sh[0];
}

__global__ void k_scan_top(int* bsum, int nb) {  // 1 block x 512, exclusive scan
  __shared__ int sh[512];
  int t = threadIdx.x;
  int orig = (t < nb) ? bsum[t] : 0;
  sh[t] = orig;
  __syncthreads();
  for (int off = 1; off < 512; off <<= 1) {
    int v = (t >= off) ? sh[t - off] : 0;
    __syncthreads();
    sh[t] += v;
    __syncthreads();
  }
  if (t < nb) bsum[t] = sh[t] - orig;
}

__global__ void k_scan_fin(const int* __restrict__ cnt, const int* __restrict__ bsum,
                           int* __restrict__ start, int* __restrict__ cursor) {
  __shared__ int sh[256];
  int i = blockIdx.x * 256 + threadIdx.x;
  int t = threadIdx.x;
  int orig = (i < N_NODES) ? cnt[i] : 0;
  sh[t] = orig;
  __syncthreads();
  for (int off = 1; off < 256; off <<= 1) {
    int v = (t >= off) ? sh[t - off] : 0;
    __syncthreads();
    sh[t] += v;
    __syncthreads();
  }
  if (i < N_NODES) {
    int st = bsum[blockIdx.x] + sh[t] - orig;
    start[i] = st;
    cursor[i] = st;
  }
}

__global__ void k_scatter(const int* __restrict__ src, const int* __restrict__ dst,
                          int* cursor, int2* __restrict__ eids, int* __restrict__ dstS) {
  int e = blockIdx.x * blockDim.x + threadIdx.x;
  if (e < N_EDGES) {
    int d = dst[e];
    int pos = atomicAdd(&cursor[d], 1);
    eids[pos] = make_int2(e, src[e]);
    dstS[pos] = d;
  }
}

// ---------------- CSR softmax-aggregation: wave/node, 8 edges parallel, CONTIGUOUS ea ----------------
__global__ __launch_bounds__(256) void k_agg_csr(
    const _Float16* __restrict__ h, const _Float16* __restrict__ ea_s,
    const int2* __restrict__ eids, const int* __restrict__ start,
    const int* __restrict__ cnt, _Float16* __restrict__ hsum) {
  const int lane = threadIdx.x & 63;
  const int wid  = (int)((blockIdx.x * blockDim.x + threadIdx.x) >> 6);
  if (wid >= N_NODES) return;
  const int ep = lane >> 3, fg = lane & 7;
  const int s0 = start[wid], c = cnt[wid];
  float num[8] = {0.f, 0.f, 0.f, 0.f, 0.f, 0.f, 0.f, 0.f};
  float den[8] = {0.f, 0.f, 0.f, 0.f, 0.f, 0.f, 0.f, 0.f};
  if (c > 0) {
    const int nit = (c + 7) >> 3;
    int idx = min(ep, c - 1);
    f16x8 hA = *(const f16x8*)(h + (size_t)eids[s0 + idx].y * H + fg * 8);
    f16x8 eA = *(const f16x8*)(ea_s + (size_t)(s0 + idx) * H + fg * 8);
    bool vA = (ep < c);
    f16x8 hB = hA, eB = eA;
    bool vB = false;
    if (nit > 1) {
      idx = min(8 + ep, c - 1);
      hB = *(const f16x8*)(h + (size_t)eids[s0 + idx].y * H + fg * 8);
      eB = *(const f16x8*)(ea_s + (size_t)(s0 + idx) * H + fg * 8);
      vB = (8 + ep < c);
    }
    for (int i = 0; i < nit; ++i) {
      f16x8 hc = hA, ec = eA;
      bool vc = vA;
      hA = hB; eA = eB; vA = vB;
      if (i + 2 < nit) {
        idx = min((i + 2) * 8 + ep, c - 1);
        hB = *(const f16x8*)(h + (size_t)eids[s0 + idx].y * H + fg * 8);
        eB = *(const f16x8*)(ea_s + (size_t)(s0 + idx) * H + fg * 8);
        vB = ((i + 2) * 8 + ep < c);
      }
#pragma unroll
      for (int j = 0; j < 8; ++j) {
        float m = fmaxf((float)hc[j] + (float)ec[j], 0.0f) + EPS_GEN;
        float ex = vc ? __expf(m) : 0.0f;
        num[j] = fmaf(m, ex, num[j]);
        den[j] += ex;
      }
    }
  }
#pragma unroll
  for (int j = 0; j < 8; ++j) {
    num[j] += __shfl_xor(num[j], 8);
    num[j] += __shfl_xor(num[j], 16);
    num[j] += __shfl_xor(num[j], 32);
    den[j] += __shfl_xor(den[j], 8);
    den[j] += __shfl_xor(den[j], 16);
    den[j] += __shfl_xor(den[j], 32);
  }
  if (ep == 0) {
    f16x8 hs = *(const f16x8*)(h + (size_t)wid * H + fg * 8);
    f16x8 o;
#pragma unroll
    for (int j = 0; j < 8; ++j)
      o[j] = (_Float16)(num[j] / (den[j] + 1e-16f) + (float)hs[j]);
    *(f16x8*)(hsum + (size_t)wid * H + fg * 8) = o;
  }
}

// ---------------- BN stats (f16 input) ----------------
__global__ void k_bnstats(const _Float16* __restrict__ h3, float* sums) {
  int f = threadIdx.x & (H2 - 1);
  int half = threadIdx.x >> 7;
  float s = 0.0f, q = 0.0f;
  for (int n = blockIdx.x * 2 + half; n < N_NODES; n += gridDim.x * 2) {
    float v = (float)h3[(size_t)n * H2 + f];
    s += v;
    q = fmaf(v, v, q);
  }
  __shared__ float sh[2][2][H2];
  sh[0][half][f] = s;
  sh[1][half][f] = q;
  __syncthreads();
  if (threadIdx.x < H2) {
    atomAddF(&sums[f], sh[0][0][f] + sh[0][1][f]);
    atomAddF(&sums[H2 + f], sh[1][0][f] + sh[1][1][f]);
  }
}

extern "C" void kernel_launch(void* const* d_in, const int* in_sizes, int n_in,
                              void* d_out, int out_size, void* d_ws, size_t ws_size,
                              hipStream_t stream) {
  (void)in_sizes; (void)n_in; (void)out_size; (void)ws_size;
  const float* x      = (const float*)d_in[0];
  const int*   eidx   = (const int*)d_in[1];
  const float* eattr  = (const float*)d_in[2];
  const float* node_W = (const float*)d_in[3];
  const float* node_b = (const float*)d_in[4];
  const float* edge_W = (const float*)d_in[5];
  const float* edge_b = (const float*)d_in[6];
  const float* c1_W1  = (const float*)d_in[7];
  const float* c1_g   = (const float*)d_in[8];
  const float* c1_be  = (const float*)d_in[9];
  const float* c1_W2  = (const float*)d_in[10];
  const float* c2_W1  = (const float*)d_in[11];
  const float* c2_g   = (const float*)d_in[12];
  const float* c2_be  = (const float*)d_in[13];
  const float* c2_W2  = (const float*)d_in[14];
  const float* l1_W   = (const float*)d_in[15];
  const float* l1_b   = (const float*)d_in[16];
  const float* l2_W   = (const float*)d_in[17];
  const float* l2_b   = (const float*)d_in[18];

  const int* src = eidx;
  const int* dst = eidx + N_EDGES;

  char* wsb = (char*)d_ws;
  size_t off = 0;
  _Float16* ea_s  = (_Float16*)(wsb + off); off += (size_t)N_EDGES * H * 2;   // sorted-order ea
  _Float16* hA16  = (_Float16*)(wsb + off); off += (size_t)N_NODES * H * 2;
  _Float16* hB16  = (_Float16*)(wsb + off); off += (size_t)N_NODES * H * 2;
  _Float16* hC16  = (_Float16*)(wsb + off); off += (size_t)N_NODES * H * 2;
  _Float16* hsum16= (_Float16*)(wsb + off); off += (size_t)N_NODES * H * 2;
  _Float16* h3    = (_Float16*)(wsb + off); off += (size_t)N_NODES * H2 * 2;
  float* sums     = (float*)(wsb + off);    off += 256 * 4;
  int* cnt        = (int*)(wsb + off);      off += (size_t)N_NODES * 4;
  int* startA     = (int*)(wsb + off);      off += (size_t)N_NODES * 4;
  int* cursor     = (int*)(wsb + off);      off += (size_t)N_NODES * 4;
  int* bsum       = (int*)(wsb + off);      off += 512 * 4;
  int2* eids      = (int2*)(wsb + off);     off += (size_t)N_EDGES * 8;
  int* dstS       = (int*)(wsb + off);      off += (size_t)N_EDGES * 4;
  _Float16* wE    = (_Float16*)(wsb + off); off += DE * H * 2;
  _Float16* wN    = (_Float16*)(wsb + off); off += DN * H * 2;
  _Float16* w1a   = (_Float16*)(wsb + off); off += H * H2 * 2;
  _Float16* w1b   = (_Float16*)(wsb + off); off += H * H2 * 2;
  _Float16* w2a   = (_Float16*)(wsb + off); off += H2 * H * 2;
  _Float16* w2b   = (_Float16*)(wsb + off); off += H2 * H * 2;
  _Float16* wL1   = (_Float16*)(wsb + off); off += 3 * H * H * 2;
  _Float16* wL2   = (_Float16*)(wsb + off); off += 3 * H * 32 * 2;

  float* h_out  = (float*)d_out;                            // [N,64]
  float* ea_out = (float*)d_out + (size_t)N_NODES * H;      // [E,32]

  constexpr int NB = (N_NODES + 255) / 256;                 // 313 scan blocks

  // ---- one-time weight frag-images (single dispatch) ----
  PrepAll P;
  P.d[0] = {edge_W, wE, DE, H, 0};       // 8 blocks
  P.d[1] = {node_W, wN, DN, H, 8};       // 32
  P.d[2] = {c1_W1, w1a, H, H2, 40};      // 32
  P.d[3] = {c2_W1, w1b, H, H2, 72};      // 32
  P.d[4] = {c1_W2, w2a, H2, H, 104};     // 32
  P.d[5] = {c2_W2, w2b, H2, H, 136};     // 32
  P.d[6] = {l1_W, wL1, 192, H, 168};     // 48
  P.d[7] = {l2_W, wL2, 192, 32, 216};    // 24 -> total 240
  k_prep_all<<<240, 256, 0, stream>>>(P);

  // ---- build CSR (shared by both layers; needed by encoder's gather) ----
  hipMemsetAsync(cnt, 0, N_NODES * 4, stream);
  k_hist<<<(N_EDGES + 255) / 256, 256, 0, stream>>>(dst, cnt);
  k_scan_blk<<<NB, 256, 0, stream>>>(cnt, bsum);
  k_scan_top<<<1, 512, 0, stream>>>(bsum, NB);
  k_scan_fin<<<NB, 256, 0, stream>>>(cnt, bsum, startA, cursor);
  k_scatter<<<(N_EDGES + 255) / 256, 256, 0, stream>>>(src, dst, cursor, eids, dstS);

  // ---- encoders (edge encoder writes dst-sorted ea_s via gather-read) ----
  k_dense<DE, H, true, false, false, true, false, true, false, false>
      <<<N_EDGES / 64, 256, 0, stream>>>(eattr, wE, edge_b, nullptr, nullptr, nullptr,
                                         eids, ea_s, nullptr, nullptr);
  k_dense<DN, H, false, false, false, true, false, true, false, false>
      <<<N_NODES / 64, 256, 0, stream>>>(x, wN, node_b, nullptr, nullptr, nullptr,
                                         nullptr, hA16, nullptr, nullptr);

  // ---- conv layer 1 ----
  k_agg_csr<<<(N_NODES + 3) / 4, 256, 0, stream>>>(hA16, ea_s, eids, startA, cnt, hsum16);
  k_dense<H, H2, false, true, false, false, false, true, false, true>
      <<<N_NODES / 64, 256, 0, stream>>>(hsum16, w1a, nullptr, nullptr, nullptr, nullptr,
                                         nullptr, h3, nullptr, sums);
  k_bnstats<<<1280, 256, 0, stream>>>(h3, sums);
  k_dense<H2, H, false, true, true, false, true, true, false, false>
      <<<N_NODES / 64, 256, 0, stream>>>(h3, w2a, nullptr, sums, c1_g, c1_be,
                                         nullptr, hB16, nullptr, nullptr);
  k_edge_upd_srt<64, _Float16, 4, false>
      <<<N_EDGES / 256, 256, 0, stream>>>(hB16, ea_s, eids, dstS, wL1, l1_b, ea_s);  // in-place

  // ---- conv layer 2 ----
  k_agg_csr<<<(N_NODES + 3) / 4, 256, 0, stream>>>(hB16, ea_s, eids, startA, cnt, hsum16);
  k_dense<H, H2, false, true, false, false, false, true, false, true>
      <<<N_NODES / 64, 256, 0, stream>>>(hsum16, w1b, nullptr, nullptr, nullptr, nullptr,
                                         nullptr, h3, nullptr, sums);
  k_bnstats<<<1280, 256, 0, stream>>>(h3, sums);
  k_dense<H2, H, false, true, true, false, true, true, true, false>
      <<<N_NODES / 64, 256, 0, stream>>>(h3, w2b, nullptr, sums, c2_g, c2_be,
                                         nullptr, hC16, h_out, nullptr);
  k_edge_upd_srt<32, float, 4, true>
      <<<N_EDGES / 256, 256, 0, stream>>>(hC16, ea_s, eids, dstS, wL2, l2_b, ea_out);
}

// Round 9
// 685.366 us; speedup vs baseline: 8.1655x; 1.0014x over previous
//
#include <hip/hip_runtime.h>
#include <hip/hip_bf16.h>

#define N_NODES 80000
#define N_EDGES 1280000
constexpr int DN = 128;   // node input dim
constexpr int DE = 32;    // edge input dim
constexpr int H  = 64;    // hidden
constexpr int H2 = 128;   // 2*hidden
constexpr float EPS_GEN = 1e-7f;
constexpr float EPS_BN  = 1e-5f;

typedef _Float16 f16x8 __attribute__((ext_vector_type(8)));
typedef _Float16 f16x4 __attribute__((ext_vector_type(4)));
typedef float f32x4 __attribute__((ext_vector_type(4)));

__device__ __forceinline__ void atomAddF(float* p, float v) {
  __hip_atomic_fetch_add(p, v, __ATOMIC_RELAXED, __HIP_MEMORY_SCOPE_AGENT);
}

// ---------------- weight prep (all matrices, one dispatch) ----------------
// frag-image: slab (n2*NK+kk) of 512 halves; elem ((kg*16+m16)*8+j) = W[kk*32+kg*8+j][n2*16+m16]
struct PrepDesc { const float* W; _Float16* img; int K; int OC; int blkStart; };
struct PrepAll { PrepDesc d[8]; };

__global__ void k_prep_all(PrepAll P) {
  int b = blockIdx.x;
  int i = 0;
#pragma unroll
  for (int t = 1; t < 8; ++t)
    if (P.d[t].blkStart <= b) i = t;
  const PrepDesc D = P.d[i];
  int idx = (b - D.blkStart) * 256 + threadIdx.x;
  if (idx >= D.K * D.OC) return;
  int nslabK = D.K >> 5;
  int j = idx & 7, m16 = (idx >> 3) & 15, kg = (idx >> 7) & 3;
  int slab = idx >> 9;
  int kk = slab % nslabK, n2 = slab / nslabK;
  int k = kk * 32 + kg * 8 + j, n = n2 * 16 + m16;
  D.img[idx] = (_Float16)D.W[k * D.OC + n];
}

// ---------------- generic dense MFMA: out[orow,:] = f(A[row,:]) @ W + b ----------------
// SCATOUT: orow = posmap[row] (scatter-write). AFFINE: BN affine from sums (in-block).
template <int K, int OC, bool IN16, bool AFFINE, bool BIAS,
          bool RELU_OUT, bool OUT16, bool OUT32, bool CLRS, bool SCATOUT>
__global__ __launch_bounds__(256) void k_dense(
    const void* __restrict__ Ain, const _Float16* __restrict__ wimg,
    const float* __restrict__ bias, const float* __restrict__ sums,
    const float* __restrict__ g, const float* __restrict__ be,
    const int* __restrict__ posmap,
    _Float16* __restrict__ out16, float* __restrict__ out32,
    float* __restrict__ sums_clr) {
  constexpr int NK = K / 32, NF = OC / 16;
  __shared__ float sSC[H2], sSH[H2];
  const int tid = threadIdx.x, wv = tid >> 6, lane = tid & 63;
  const int m16 = lane & 15, kg = lane >> 4;
  const int rowbase = blockIdx.x * 64 + wv * 16;
  if constexpr (CLRS) {
    if (blockIdx.x == 0) sums_clr[tid] = 0.0f;   // 256 floats
  }
  if constexpr (AFFINE) {
    for (int i = tid; i < H2; i += 256) {
      float mu  = sums[i] * (1.0f / N_NODES);
      float var = sums[H2 + i] * (1.0f / N_NODES) - mu * mu;
      float sc  = rsqrtf(var + EPS_BN) * g[i];
      sSC[i] = sc;
      sSH[i] = be[i] - mu * sc;
    }
    __syncthreads();
  }
  const int arow = rowbase + m16;
  f32x4 acc[NF];
#pragma unroll
  for (int n2 = 0; n2 < NF; ++n2) {
    float bv = BIAS ? bias[n2 * 16 + m16] : 0.0f;
    acc[n2] = (f32x4){bv, bv, bv, bv};
  }
  const _Float16* wp = wimg + (size_t)lane * 8;
#pragma unroll
  for (int kk = 0; kk < NK; ++kk) {
    f16x8 a;
    if constexpr (IN16) {
      const _Float16* ap = (const _Float16*)Ain + (size_t)arow * K + kg * 8 + kk * 32;
      a = *(const f16x8*)ap;
      if constexpr (AFFINE) {
#pragma unroll
        for (int j = 0; j < 8; ++j) {
          int f = kg * 8 + kk * 32 + j;
          float v = fmaxf(fmaf((float)a[j], sSC[f], sSH[f]), 0.0f);
          a[j] = (_Float16)v;
        }
      }
    } else {
      const float* ap = (const float*)Ain + (size_t)arow * K + kg * 8 + kk * 32;
      float4 v0 = *(const float4*)ap;
      float4 v1 = *(const float4*)(ap + 4);
      a = (f16x8){(_Float16)v0.x, (_Float16)v0.y, (_Float16)v0.z, (_Float16)v0.w,
                  (_Float16)v1.x, (_Float16)v1.y, (_Float16)v1.z, (_Float16)v1.w};
    }
#pragma unroll
    for (int n2 = 0; n2 < NF; ++n2) {
      f16x8 bb = *(const f16x8*)(wp + ((size_t)(n2 * NK + kk) << 9));
      acc[n2] = __builtin_amdgcn_mfma_f32_16x16x32_f16(a, bb, acc[n2], 0, 0, 0);
    }
  }
#pragma unroll
  for (int n2 = 0; n2 < NF; ++n2)
#pragma unroll
    for (int r = 0; r < 4; ++r) {
      float o = acc[n2][r];
      if constexpr (RELU_OUT) o = fmaxf(o, 0.0f);
      int orow = rowbase + kg * 4 + r;
      if constexpr (SCATOUT) orow = posmap[orow];
      size_t oi = (size_t)orow * OC + n2 * 16 + m16;
      if constexpr (OUT16) out16[oi] = (_Float16)o;
      if constexpr (OUT32) out32[oi] = o;
    }
}

// ---------------- edge update on sorted positions: T tiles/block ----------------
template <int OC, typename OUT_T, int T, bool SCAT>
__global__ __launch_bounds__(256) void k_edge_upd_srt(
    const _Float16* __restrict__ h, const _Float16* __restrict__ ea,
    const int2* __restrict__ eids, const int* __restrict__ dstS,
    const _Float16* __restrict__ wimg, const float* __restrict__ lb,
    OUT_T* __restrict__ eout) {
  constexpr int NF = OC / 16;
  __shared__ _Float16 sWf[NF * 6 * 512];
  __shared__ int sS[T * 64], sD[T * 64];
  __shared__ int sE[SCAT ? T * 64 : 1];
  const int tid = threadIdx.x, wv = tid >> 6, lane = tid & 63;
  const int m16 = lane & 15, kg = lane >> 4;
  const int p0 = blockIdx.x * (T * 64);

  for (int i = tid; i < T * 64; i += 256) {
    int2 t = eids[p0 + i];
    sS[i] = t.y;
    sD[i] = dstS[p0 + i];
    if constexpr (SCAT) sE[i] = t.x;
  }
  {  // stage weights: linear copy (frag-ordered)
    const float4* s4 = (const float4*)wimg;
    float4* d4 = (float4*)sWf;
    constexpr int NV = NF * 6 * 512 / 8;
    for (int i = tid; i < NV; i += 256) d4[i] = s4[i];
  }
  __syncthreads();
  const _Float16* wp = sWf + (size_t)lane * 8;

  float bias_[NF];
#pragma unroll
  for (int n2 = 0; n2 < NF; ++n2) bias_[n2] = lb[n2 * 16 + m16];

  f16x8 FA[6], FB[6];
  auto LOADA = [&](f16x8* F, int l) {        // l = local row (pos - p0)
    const _Float16* a0 = h + (size_t)sS[l] * H + kg * 8;
    const _Float16* a1 = ea + (size_t)(p0 + l) * H + kg * 8;
    const _Float16* a2 = h + (size_t)sD[l] * H + kg * 8;
    F[0] = *(const f16x8*)a0;
    F[1] = *(const f16x8*)(a0 + 32);
    F[2] = *(const f16x8*)a1;
    F[3] = *(const f16x8*)(a1 + 32);
    F[4] = *(const f16x8*)a2;
    F[5] = *(const f16x8*)(a2 + 32);
  };
  auto COMPUTE = [&](const f16x8* F, int l) {
    f32x4 acc[NF];
#pragma unroll
    for (int n2 = 0; n2 < NF; ++n2)
      acc[n2] = (f32x4){bias_[n2], bias_[n2], bias_[n2], bias_[n2]};
#pragma unroll
    for (int kk = 0; kk < 6; ++kk)
#pragma unroll
      for (int n2 = 0; n2 < NF; ++n2) {
        f16x8 bb = *(const f16x8*)(wp + ((n2 * 6 + kk) << 9));
        acc[n2] = __builtin_amdgcn_mfma_f32_16x16x32_f16(F[kk], bb, acc[n2], 0, 0, 0);
      }
    const int lbase = l - m16;
#pragma unroll
    for (int n2 = 0; n2 < NF; ++n2)
#pragma unroll
      for (int r = 0; r < 4; ++r) {
        int lr = lbase + kg * 4 + r;
        int col = n2 * 16 + m16;
        if constexpr (SCAT)
          eout[(size_t)sE[lr] * OC + col] = (OUT_T)acc[n2][r];
        else
          eout[(size_t)(p0 + lr) * OC + col] = (OUT_T)acc[n2][r];
      }
  };

  const int l0 = wv * 16 + m16;
  LOADA(FA, l0);
  if (T > 1) LOADA(FB, l0 + 64);
#pragma unroll
  for (int t = 0; t < T; ++t) {
    if (t & 1) {
      COMPUTE(FB, l0 + t * 64);
      if (t + 2 < T) LOADA(FB, l0 + (t + 2) * 64);
    } else {
      COMPUTE(FA, l0 + t * 64);
      if (t + 2 < T) LOADA(FA, l0 + (t + 2) * 64);
    }
  }
}

// ---------------- CSR build: histogram -> scan -> scatter ----------------
__global__ void k_hist(const int* __restrict__ dst, int* cnt) {
  int e = blockIdx.x * blockDim.x + threadIdx.x;
  if (e < N_EDGES) atomicAdd(&cnt[dst[e]], 1);
}

__global__ void k_scan_blk(const int* __restrict__ cnt, int* __restrict__ bsum) {
  __shared__ int sh[256];
  int i = blockIdx.x * 256 + threadIdx.x;
  sh[threadIdx.x] = (i < N_NODES) ? cnt[i] : 0;
  __syncthreads();
  for (int s = 128; s > 0; s >>= 1) {
    if (threadIdx.x < s) sh[threadIdx.x] += sh[threadIdx.x + s];
    __syncthreads();
  }
  if (threadIdx.x == 0) bsum[blockIdx.x] = sh[0];
}

__global__ void k_scan_top(int* bsum, int nb) {  // 1 block x 512, exclusive scan
  __shared__ int sh[512];
  int t = threadIdx.x;
  int orig = (t < nb) ? bsum[t] : 0;
  sh[t] = orig;
  __syncthreads();
  for (int off = 1; off < 512; off <<= 1) {
    int v = (t >= off) ? sh[t - off] : 0;
    __syncthreads();
    sh[t] += v;
    __syncthreads();
  }
  if (t < nb) bsum[t] = sh[t] - orig;
}

__global__ void k_scan_fin(const int* __restrict__ cnt, const int* __restrict__ bsum,
                           int* __restrict__ start, int* __restrict__ cursor) {
  __shared__ int sh[256];
  int i = blockIdx.x * 256 + threadIdx.x;
  int t = threadIdx.x;
  int orig = (i < N_NODES) ? cnt[i] : 0;
  sh[t] = orig;
  __syncthreads();
  for (int off = 1; off < 256; off <<= 1) {
    int v = (t >= off) ? sh[t - off] : 0;
    __syncthreads();
    sh[t] += v;
    __syncthreads();
  }
  if (i < N_NODES) {
    int st = bsum[blockIdx.x] + sh[t] - orig;
    start[i] = st;
    cursor[i] = st;
  }
}

__global__ void k_scatter(const int* __restrict__ src, const int* __restrict__ dst,
                          int* cursor, int2* __restrict__ eids, int* __restrict__ dstS,
                          int* __restrict__ posOf) {
  int e = blockIdx.x * blockDim.x + threadIdx.x;
  if (e < N_EDGES) {
    int d = dst[e];
    int pos = atomicAdd(&cursor[d], 1);
    eids[pos] = make_int2(e, src[e]);
    dstS[pos] = d;
    posOf[e] = pos;
  }
}

// ---------------- CSR softmax-aggregation: wave/node, 8 edges parallel, CONTIGUOUS ea ----------------
__global__ __launch_bounds__(256) void k_agg_csr(
    const _Float16* __restrict__ h, const _Float16* __restrict__ ea_s,
    const int2* __restrict__ eids, const int* __restrict__ start,
    const int* __restrict__ cnt, _Float16* __restrict__ hsum) {
  const int lane = threadIdx.x & 63;
  const int wid  = (int)((blockIdx.x * blockDim.x + threadIdx.x) >> 6);
  if (wid >= N_NODES) return;
  const int ep = lane >> 3, fg = lane & 7;
  const int s0 = start[wid], c = cnt[wid];
  float num[8] = {0.f, 0.f, 0.f, 0.f, 0.f, 0.f, 0.f, 0.f};
  float den[8] = {0.f, 0.f, 0.f, 0.f, 0.f, 0.f, 0.f, 0.f};
  if (c > 0) {
    const int nit = (c + 7) >> 3;
    int idx = min(ep, c - 1);
    f16x8 hA = *(const f16x8*)(h + (size_t)eids[s0 + idx].y * H + fg * 8);
    f16x8 eA = *(const f16x8*)(ea_s + (size_t)(s0 + idx) * H + fg * 8);
    bool vA = (ep < c);
    f16x8 hB = hA, eB = eA;
    bool vB = false;
    if (nit > 1) {
      idx = min(8 + ep, c - 1);
      hB = *(const f16x8*)(h + (size_t)eids[s0 + idx].y * H + fg * 8);
      eB = *(const f16x8*)(ea_s + (size_t)(s0 + idx) * H + fg * 8);
      vB = (8 + ep < c);
    }
    for (int i = 0; i < nit; ++i) {
      f16x8 hc = hA, ec = eA;
      bool vc = vA;
      hA = hB; eA = eB; vA = vB;
      if (i + 2 < nit) {
        idx = min((i + 2) * 8 + ep, c - 1);
        hB = *(const f16x8*)(h + (size_t)eids[s0 + idx].y * H + fg * 8);
        eB = *(const f16x8*)(ea_s + (size_t)(s0 + idx) * H + fg * 8);
        vB = ((i + 2) * 8 + ep < c);
      }
#pragma unroll
      for (int j = 0; j < 8; ++j) {
        float m = fmaxf((float)hc[j] + (float)ec[j], 0.0f) + EPS_GEN;
        float ex = vc ? __expf(m) : 0.0f;
        num[j] = fmaf(m, ex, num[j]);
        den[j] += ex;
      }
    }
  }
#pragma unroll
  for (int j = 0; j < 8; ++j) {
    num[j] += __shfl_xor(num[j], 8);
    num[j] += __shfl_xor(num[j], 16);
    num[j] += __shfl_xor(num[j], 32);
    den[j] += __shfl_xor(den[j], 8);
    den[j] += __shfl_xor(den[j], 16);
    den[j] += __shfl_xor(den[j], 32);
  }
  if (ep == 0) {
    f16x8 hs = *(const f16x8*)(h + (size_t)wid * H + fg * 8);
    f16x8 o;
#pragma unroll
    for (int j = 0; j < 8; ++j)
      o[j] = (_Float16)(num[j] / (den[j] + 1e-16f) + (float)hs[j]);
    *(f16x8*)(hsum + (size_t)wid * H + fg * 8) = o;
  }
}

// ---------------- BN stats (f16 input) ----------------
__global__ void k_bnstats(const _Float16* __restrict__ h3, float* sums) {
  int f = threadIdx.x & (H2 - 1);
  int half = threadIdx.x >> 7;
  float s = 0.0f, q = 0.0f;
  for (int n = blockIdx.x * 2 + half; n < N_NODES; n += gridDim.x * 2) {
    float v = (float)h3[(size_t)n * H2 + f];
    s += v;
    q = fmaf(v, v, q);
  }
  __shared__ float sh[2][2][H2];
  sh[0][half][f] = s;
  sh[1][half][f] = q;
  __syncthreads();
  if (threadIdx.x < H2) {
    atomAddF(&sums[f], sh[0][0][f] + sh[0][1][f]);
    atomAddF(&sums[H2 + f], sh[1][0][f] + sh[1][1][f]);
  }
}

extern "C" void kernel_launch(void* const* d_in, const int* in_sizes, int n_in,
                              void* d_out, int out_size, void* d_ws, size_t ws_size,
                              hipStream_t stream) {
  (void)in_sizes; (void)n_in; (void)out_size; (void)ws_size;
  const float* x      = (const float*)d_in[0];
  const int*   eidx   = (const int*)d_in[1];
  const float* eattr  = (const float*)d_in[2];
  const float* node_W = (const float*)d_in[3];
  const float* node_b = (const float*)d_in[4];
  const float* edge_W = (const float*)d_in[5];
  const float* edge_b = (const float*)d_in[6];
  const float* c1_W1  = (const float*)d_in[7];
  const float* c1_g   = (const float*)d_in[8];
  const float* c1_be  = (const float*)d_in[9];
  const float* c1_W2  = (const float*)d_in[10];
  const float* c2_W1  = (const float*)d_in[11];
  const float* c2_g   = (const float*)d_in[12];
  const float* c2_be  = (const float*)d_in[13];
  const float* c2_W2  = (const float*)d_in[14];
  const float* l1_W   = (const float*)d_in[15];
  const float* l1_b   = (const float*)d_in[16];
  const float* l2_W   = (const float*)d_in[17];
  const float* l2_b   = (const float*)d_in[18];

  const int* src = eidx;
  const int* dst = eidx + N_EDGES;

  char* wsb = (char*)d_ws;
  size_t off = 0;
  _Float16* ea_s  = (_Float16*)(wsb + off); off += (size_t)N_EDGES * H * 2;   // sorted-order ea
  _Float16* hA16  = (_Float16*)(wsb + off); off += (size_t)N_NODES * H * 2;
  _Float16* hB16  = (_Float16*)(wsb + off); off += (size_t)N_NODES * H * 2;
  _Float16* hC16  = (_Float16*)(wsb + off); off += (size_t)N_NODES * H * 2;
  _Float16* hsum16= (_Float16*)(wsb + off); off += (size_t)N_NODES * H * 2;
  _Float16* h3    = (_Float16*)(wsb + off); off += (size_t)N_NODES * H2 * 2;
  float* sums     = (float*)(wsb + off);    off += 256 * 4;
  int* cnt        = (int*)(wsb + off);      off += (size_t)N_NODES * 4;
  int* startA     = (int*)(wsb + off);      off += (size_t)N_NODES * 4;
  int* cursor     = (int*)(wsb + off);      off += (size_t)N_NODES * 4;
  int* bsum       = (int*)(wsb + off);      off += 512 * 4;
  int2* eids      = (int2*)(wsb + off);     off += (size_t)N_EDGES * 8;
  int* dstS       = (int*)(wsb + off);      off += (size_t)N_EDGES * 4;
  int* posOf      = (int*)(wsb + off);      off += (size_t)N_EDGES * 4;
  _Float16* wE    = (_Float16*)(wsb + off); off += DE * H * 2;
  _Float16* wN    = (_Float16*)(wsb + off); off += DN * H * 2;
  _Float16* w1a   = (_Float16*)(wsb + off); off += H * H2 * 2;
  _Float16* w1b   = (_Float16*)(wsb + off); off += H * H2 * 2;
  _Float16* w2a   = (_Float16*)(wsb + off); off += H2 * H * 2;
  _Float16* w2b   = (_Float16*)(wsb + off); off += H2 * H * 2;
  _Float16* wL1   = (_Float16*)(wsb + off); off += 3 * H * H * 2;
  _Float16* wL2   = (_Float16*)(wsb + off); off += 3 * H * 32 * 2;

  float* h_out  = (float*)d_out;                            // [N,64]
  float* ea_out = (float*)d_out + (size_t)N_NODES * H;      // [E,32]

  constexpr int NB = (N_NODES + 255) / 256;                 // 313 scan blocks

  // ---- one-time weight frag-images (single dispatch) ----
  PrepAll P;
  P.d[0] = {edge_W, wE, DE, H, 0};       // 8 blocks
  P.d[1] = {node_W, wN, DN, H, 8};       // 32
  P.d[2] = {c1_W1, w1a, H, H2, 40};      // 32
  P.d[3] = {c2_W1, w1b, H, H2, 72};      // 32
  P.d[4] = {c1_W2, w2a, H2, H, 104};     // 32
  P.d[5] = {c2_W2, w2b, H2, H, 136};     // 32
  P.d[6] = {l1_W, wL1, 192, H, 168};     // 48
  P.d[7] = {l2_W, wL2, 192, 32, 216};    // 24 -> total 240
  k_prep_all<<<240, 256, 0, stream>>>(P);

  // ---- build CSR (shared by both layers) ----
  hipMemsetAsync(cnt, 0, N_NODES * 4, stream);
  k_hist<<<(N_EDGES + 255) / 256, 256, 0, stream>>>(dst, cnt);
  k_scan_blk<<<NB, 256, 0, stream>>>(cnt, bsum);
  k_scan_top<<<1, 512, 0, stream>>>(bsum, NB);
  k_scan_fin<<<NB, 256, 0, stream>>>(cnt, bsum, startA, cursor);
  k_scatter<<<(N_EDGES + 255) / 256, 256, 0, stream>>>(src, dst, cursor, eids, dstS, posOf);

  // ---- encoders (edge encoder: streaming read, scatter-write to sorted ea_s) ----
  k_dense<DE, H, false, false, true, false, true, false, false, true>
      <<<N_EDGES / 64, 256, 0, stream>>>(eattr, wE, edge_b, nullptr, nullptr, nullptr,
                                         posOf, ea_s, nullptr, nullptr);
  k_dense<DN, H, false, false, true, false, true, false, false, false>
      <<<N_NODES / 64, 256, 0, stream>>>(x, wN, node_b, nullptr, nullptr, nullptr,
                                         nullptr, hA16, nullptr, nullptr);

  // ---- conv layer 1 ----
  k_agg_csr<<<(N_NODES + 3) / 4, 256, 0, stream>>>(hA16, ea_s, eids, startA, cnt, hsum16);
  k_dense<H, H2, true, false, false, false, true, false, true, false>
      <<<N_NODES / 64, 256, 0, stream>>>(hsum16, w1a, nullptr, nullptr, nullptr, nullptr,
                                         nullptr, h3, nullptr, sums);
  k_bnstats<<<1280, 256, 0, stream>>>(h3, sums);
  k_dense<H2, H, true, true, false, true, true, false, false, false>
      <<<N_NODES / 64, 256, 0, stream>>>(h3, w2a, nullptr, sums, c1_g, c1_be,
                                         nullptr, hB16, nullptr, nullptr);
  k_edge_upd_srt<64, _Float16, 8, false>
      <<<N_EDGES / 512, 256, 0, stream>>>(hB16, ea_s, eids, dstS, wL1, l1_b, ea_s);  // in-place

  // ---- conv layer 2 ----
  k_agg_csr<<<(N_NODES + 3) / 4, 256, 0, stream>>>(hB16, ea_s, eids, startA, cnt, hsum16);
  k_dense<H, H2, true, false, false, false, true, false, true, false>
      <<<N_NODES / 64, 256, 0, stream>>>(hsum16, w1b, nullptr, nullptr, nullptr, nullptr,
                                         nullptr, h3, nullptr, sums);
  k_bnstats<<<1280, 256, 0, stream>>>(h3, sums);
  k_dense<H2, H, true, true, false, true, true, true, false, false>
      <<<N_NODES / 64, 256, 0, stream>>>(h3, w2b, nullptr, sums, c2_g, c2_be,
                                         nullptr, hC16, h_out, nullptr);
  k_edge_upd_srt<32, float, 8, true>
      <<<N_EDGES / 512, 256, 0, stream>>>(hC16, ea_s, eids, dstS, wL2, l2_b, ea_out);
}

// Round 10
// 663.885 us; speedup vs baseline: 8.4298x; 1.0324x over previous
//
#include <hip/hip_runtime.h>
#include <hip/hip_bf16.h>

#define N_NODES 80000
#define N_EDGES 1280000
constexpr int DN = 128;   // node input dim
constexpr int DE = 32;    // edge input dim
constexpr int H  = 64;    // hidden
constexpr int H2 = 128;   // 2*hidden
constexpr float EPS_GEN = 1e-7f;
constexpr float EPS_BN  = 1e-5f;

typedef _Float16 f16x8 __attribute__((ext_vector_type(8)));
typedef _Float16 f16x4 __attribute__((ext_vector_type(4)));
typedef float f32x4 __attribute__((ext_vector_type(4)));

__device__ __forceinline__ void atomAddF(float* p, float v) {
  __hip_atomic_fetch_add(p, v, __ATOMIC_RELAXED, __HIP_MEMORY_SCOPE_AGENT);
}

// ---------------- weight prep (all matrices, one dispatch) ----------------
// frag-image: slab (n2*NK+kk) of 512 halves; elem ((kg*16+m16)*8+j) = W[kk*32+kg*8+j][n2*16+m16]
struct PrepDesc { const float* W; _Float16* img; int K; int OC; int blkStart; };
struct PrepAll { PrepDesc d[8]; };

__global__ void k_prep_all(PrepAll P) {
  int b = blockIdx.x;
  int i = 0;
#pragma unroll
  for (int t = 1; t < 8; ++t)
    if (P.d[t].blkStart <= b) i = t;
  const PrepDesc D = P.d[i];
  int idx = (b - D.blkStart) * 256 + threadIdx.x;
  if (idx >= D.K * D.OC) return;
  int nslabK = D.K >> 5;
  int j = idx & 7, m16 = (idx >> 3) & 15, kg = (idx >> 7) & 3;
  int slab = idx >> 9;
  int kk = slab % nslabK, n2 = slab / nslabK;
  int k = kk * 32 + kg * 8 + j, n = n2 * 16 + m16;
  D.img[idx] = (_Float16)D.W[k * D.OC + n];
}

// ---------------- generic dense MFMA: out[orow,:] = f(A[row,:]) @ W + b ----------------
// SCATOUT: orow = posmap[row]. AFFINE: BN affine from sums. STATS: accumulate col sums/sumsq.
template <int K, int OC, bool IN16, bool AFFINE, bool BIAS,
          bool RELU_OUT, bool OUT16, bool OUT32, bool SCATOUT, bool STATS>
__global__ __launch_bounds__(256) void k_dense(
    const void* __restrict__ Ain, const _Float16* __restrict__ wimg,
    const float* __restrict__ bias, const float* __restrict__ sums,
    const float* __restrict__ g, const float* __restrict__ be,
    const int* __restrict__ posmap,
    _Float16* __restrict__ out16, float* __restrict__ out32,
    float* __restrict__ sums_out) {
  constexpr int NK = K / 32, NF = OC / 16;
  __shared__ float sSC[AFFINE ? H2 : 1], sSH[AFFINE ? H2 : 1];
  __shared__ float sStat[STATS ? 1024 : 1];   // [2][4 waves][128]
  const int tid = threadIdx.x, wv = tid >> 6, lane = tid & 63;
  const int m16 = lane & 15, kg = lane >> 4;
  const int rowbase = blockIdx.x * 64 + wv * 16;
  if constexpr (AFFINE) {
    for (int i = tid; i < H2; i += 256) {
      float mu  = sums[i] * (1.0f / N_NODES);
      float var = sums[H2 + i] * (1.0f / N_NODES) - mu * mu;
      float sc  = rsqrtf(var + EPS_BN) * g[i];
      sSC[i] = sc;
      sSH[i] = be[i] - mu * sc;
    }
    __syncthreads();
  }
  const int arow = rowbase + m16;
  f32x4 acc[NF];
#pragma unroll
  for (int n2 = 0; n2 < NF; ++n2) {
    float bv = BIAS ? bias[n2 * 16 + m16] : 0.0f;
    acc[n2] = (f32x4){bv, bv, bv, bv};
  }
  const _Float16* wp = wimg + (size_t)lane * 8;
#pragma unroll
  for (int kk = 0; kk < NK; ++kk) {
    f16x8 a;
    if constexpr (IN16) {
      const _Float16* ap = (const _Float16*)Ain + (size_t)arow * K + kg * 8 + kk * 32;
      a = *(const f16x8*)ap;
      if constexpr (AFFINE) {
#pragma unroll
        for (int j = 0; j < 8; ++j) {
          int f = kg * 8 + kk * 32 + j;
          float v = fmaxf(fmaf((float)a[j], sSC[f], sSH[f]), 0.0f);
          a[j] = (_Float16)v;
        }
      }
    } else {
      const float* ap = (const float*)Ain + (size_t)arow * K + kg * 8 + kk * 32;
      float4 v0 = *(const float4*)ap;
      float4 v1 = *(const float4*)(ap + 4);
      a = (f16x8){(_Float16)v0.x, (_Float16)v0.y, (_Float16)v0.z, (_Float16)v0.w,
                  (_Float16)v1.x, (_Float16)v1.y, (_Float16)v1.z, (_Float16)v1.w};
    }
#pragma unroll
    for (int n2 = 0; n2 < NF; ++n2) {
      f16x8 bb = *(const f16x8*)(wp + ((size_t)(n2 * NK + kk) << 9));
      acc[n2] = __builtin_amdgcn_mfma_f32_16x16x32_f16(a, bb, acc[n2], 0, 0, 0);
    }
  }
#pragma unroll
  for (int n2 = 0; n2 < NF; ++n2)
#pragma unroll
    for (int r = 0; r < 4; ++r) {
      float o = acc[n2][r];
      if constexpr (RELU_OUT) o = fmaxf(o, 0.0f);
      int orow = rowbase + kg * 4 + r;
      if constexpr (SCATOUT) orow = posmap[orow];
      size_t oi = (size_t)orow * OC + n2 * 16 + m16;
      if constexpr (OUT16) out16[oi] = (_Float16)o;
      if constexpr (OUT32) out32[oi] = o;
    }
  if constexpr (STATS) {
    static_assert(!STATS || NF == 8, "STATS assumes OC==128");
#pragma unroll
    for (int n2 = 0; n2 < NF; ++n2) {
      float s = acc[n2][0] + acc[n2][1] + acc[n2][2] + acc[n2][3];
      float q = acc[n2][0] * acc[n2][0] + acc[n2][1] * acc[n2][1] +
                acc[n2][2] * acc[n2][2] + acc[n2][3] * acc[n2][3];
      s += __shfl_xor(s, 16); s += __shfl_xor(s, 32);
      q += __shfl_xor(q, 16); q += __shfl_xor(q, 32);
      if (kg == 0) {
        sStat[wv * 128 + n2 * 16 + m16] = s;
        sStat[512 + wv * 128 + n2 * 16 + m16] = q;
      }
    }
    __syncthreads();
    {
      int which = tid >> 7, f = tid & 127;
      const float* b0 = sStat + which * 512;
      float v = b0[f] + b0[128 + f] + b0[256 + f] + b0[384 + f];
      atomAddF(&sums_out[which * H2 + f], v);
    }
  }
}

// ---------------- edge update on sorted positions: T tiles/block ----------------
// eidsQ[pos] = (e, src, dst, 0). ea_s streamed (in-place for OC=64); SCAT -> write eout[e].
template <int OC, typename OUT_T, int T, bool SCAT>
__global__ __launch_bounds__(256) void k_edge_upd_srt(
    const _Float16* __restrict__ h, const _Float16* __restrict__ ea,
    const int4* __restrict__ eidsQ,
    const _Float16* __restrict__ wimg, const float* __restrict__ lb,
    OUT_T* __restrict__ eout) {
  constexpr int NF = OC / 16;
  __shared__ _Float16 sWf[NF * 6 * 512];
  __shared__ int sS[T * 64], sD[T * 64];
  __shared__ int sE[SCAT ? T * 64 : 1];
  const int tid = threadIdx.x, wv = tid >> 6, lane = tid & 63;
  const int m16 = lane & 15, kg = lane >> 4;
  const int p0 = blockIdx.x * (T * 64);

  for (int i = tid; i < T * 64; i += 256) {
    int4 t = eidsQ[p0 + i];
    sS[i] = t.y;
    sD[i] = t.z;
    if constexpr (SCAT) sE[i] = t.x;
  }
  {  // stage weights: linear copy (frag-ordered)
    const float4* s4 = (const float4*)wimg;
    float4* d4 = (float4*)sWf;
    constexpr int NV = NF * 6 * 512 / 8;
    for (int i = tid; i < NV; i += 256) d4[i] = s4[i];
  }
  __syncthreads();
  const _Float16* wp = sWf + (size_t)lane * 8;

  float bias_[NF];
#pragma unroll
  for (int n2 = 0; n2 < NF; ++n2) bias_[n2] = lb[n2 * 16 + m16];

  f16x8 FA[6], FB[6];
  auto LOADA = [&](f16x8* F, int l) {        // l = local row (pos - p0)
    const _Float16* a0 = h + (size_t)sS[l] * H + kg * 8;
    const _Float16* a1 = ea + (size_t)(p0 + l) * H + kg * 8;
    const _Float16* a2 = h + (size_t)sD[l] * H + kg * 8;
    F[0] = *(const f16x8*)a0;
    F[1] = *(const f16x8*)(a0 + 32);
    F[2] = *(const f16x8*)a1;
    F[3] = *(const f16x8*)(a1 + 32);
    F[4] = *(const f16x8*)a2;
    F[5] = *(const f16x8*)(a2 + 32);
  };
  auto COMPUTE = [&](const f16x8* F, int l) {
    f32x4 acc[NF];
#pragma unroll
    for (int n2 = 0; n2 < NF; ++n2)
      acc[n2] = (f32x4){bias_[n2], bias_[n2], bias_[n2], bias_[n2]};
#pragma unroll
    for (int kk = 0; kk < 6; ++kk)
#pragma unroll
      for (int n2 = 0; n2 < NF; ++n2) {
        f16x8 bb = *(const f16x8*)(wp + ((n2 * 6 + kk) << 9));
        acc[n2] = __builtin_amdgcn_mfma_f32_16x16x32_f16(F[kk], bb, acc[n2], 0, 0, 0);
      }
    const int lbase = l - m16;
#pragma unroll
    for (int n2 = 0; n2 < NF; ++n2)
#pragma unroll
      for (int r = 0; r < 4; ++r) {
        int lr = lbase + kg * 4 + r;
        int col = n2 * 16 + m16;
        if constexpr (SCAT)
          eout[(size_t)sE[lr] * OC + col] = (OUT_T)acc[n2][r];
        else
          eout[(size_t)(p0 + lr) * OC + col] = (OUT_T)acc[n2][r];
      }
  };

  const int l0 = wv * 16 + m16;
  LOADA(FA, l0);
  if (T > 1) LOADA(FB, l0 + 64);
#pragma unroll
  for (int t = 0; t < T; ++t) {
    if (t & 1) {
      COMPUTE(FB, l0 + t * 64);
      if (t + 2 < T) LOADA(FB, l0 + (t + 2) * 64);
    } else {
      COMPUTE(FA, l0 + t * 64);
      if (t + 2 < T) LOADA(FA, l0 + (t + 2) * 64);
    }
  }
}

// ---------------- CSR build: histogram -> scan -> scatter ----------------
__global__ void k_hist(const int* __restrict__ dst, int* cnt) {
  int e = blockIdx.x * blockDim.x + threadIdx.x;
  if (e < N_EDGES) atomicAdd(&cnt[dst[e]], 1);
}

__global__ void k_scan_blk(const int* __restrict__ cnt, int* __restrict__ bsum) {
  __shared__ int sh[256];
  int i = blockIdx.x * 256 + threadIdx.x;
  sh[threadIdx.x] = (i < N_NODES) ? cnt[i] : 0;
  __syncthreads();
  for (int s = 128; s > 0; s >>= 1) {
    if (threadIdx.x < s) sh[threadIdx.x] += sh[threadIdx.x + s];
    __syncthreads();
  }
  if (threadIdx.x == 0) bsum[blockIdx.x] = sh[0];
}

__global__ void k_scan_top(int* bsum, int nb) {  // 1 block x 512, exclusive scan
  __shared__ int sh[512];
  int t = threadIdx.x;
  int orig = (t < nb) ? bsum[t] : 0;
  sh[t] = orig;
  __syncthreads();
  for (int off = 1; off < 512; off <<= 1) {
    int v = (t >= off) ? sh[t - off] : 0;
    __syncthreads();
    sh[t] += v;
    __syncthreads();
  }
  if (t < nb) bsum[t] = sh[t] - orig;
}

__global__ void k_scan_fin(const int* __restrict__ cnt, const int* __restrict__ bsum,
                           int* __restrict__ start, int* __restrict__ cursor) {
  __shared__ int sh[256];
  int i = blockIdx.x * 256 + threadIdx.x;
  int t = threadIdx.x;
  int orig = (i < N_NODES) ? cnt[i] : 0;
  sh[t] = orig;
  __syncthreads();
  for (int off = 1; off < 256; off <<= 1) {
    int v = (t >= off) ? sh[t - off] : 0;
    __syncthreads();
    sh[t] += v;
    __syncthreads();
  }
  if (i < N_NODES) {
    int st = bsum[blockIdx.x] + sh[t] - orig;
    start[i] = st;
    cursor[i] = st;
  }
}

__global__ void k_scatter(const int* __restrict__ src, const int* __restrict__ dst,
                          int* cursor, int4* __restrict__ eidsQ, int* __restrict__ posOf) {
  int e = blockIdx.x * blockDim.x + threadIdx.x;
  if (e < N_EDGES) {
    int d = dst[e];
    int s = src[e];
    int pos = atomicAdd(&cursor[d], 1);
    eidsQ[pos] = make_int4(e, s, d, 0);   // single 16B scattered store
    posOf[e] = pos;                        // coalesced
  }
}

// ---------------- CSR softmax-aggregation: wave/node, 8 edges parallel, CONTIGUOUS ea ----------------
// block 0 also zeroes sums[256] for the following mlp1's STATS accumulation.
__global__ __launch_bounds__(256) void k_agg_csr(
    const _Float16* __restrict__ h, const _Float16* __restrict__ ea_s,
    const int4* __restrict__ eidsQ, const int* __restrict__ start,
    const int* __restrict__ cnt, _Float16* __restrict__ hsum,
    float* __restrict__ sums_clr) {
  if (blockIdx.x == 0) sums_clr[threadIdx.x] = 0.0f;
  const int lane = threadIdx.x & 63;
  const int wid  = (int)((blockIdx.x * blockDim.x + threadIdx.x) >> 6);
  if (wid >= N_NODES) return;
  const int ep = lane >> 3, fg = lane & 7;
  const int s0 = start[wid], c = cnt[wid];
  float num[8] = {0.f, 0.f, 0.f, 0.f, 0.f, 0.f, 0.f, 0.f};
  float den[8] = {0.f, 0.f, 0.f, 0.f, 0.f, 0.f, 0.f, 0.f};
  if (c > 0) {
    const int nit = (c + 7) >> 3;
    int idx = min(ep, c - 1);
    int2 pe = *(const int2*)(eidsQ + s0 + idx);   // (e, src) 8B prefix
    f16x8 hA = *(const f16x8*)(h + (size_t)pe.y * H + fg * 8);
    f16x8 eA = *(const f16x8*)(ea_s + (size_t)(s0 + idx) * H + fg * 8);
    bool vA = (ep < c);
    f16x8 hB = hA, eB = eA;
    bool vB = false;
    if (nit > 1) {
      idx = min(8 + ep, c - 1);
      pe = *(const int2*)(eidsQ + s0 + idx);
      hB = *(const f16x8*)(h + (size_t)pe.y * H + fg * 8);
      eB = *(const f16x8*)(ea_s + (size_t)(s0 + idx) * H + fg * 8);
      vB = (8 + ep < c);
    }
    for (int i = 0; i < nit; ++i) {
      f16x8 hc = hA, ec = eA;
      bool vc = vA;
      hA = hB; eA = eB; vA = vB;
      if (i + 2 < nit) {
        idx = min((i + 2) * 8 + ep, c - 1);
        pe = *(const int2*)(eidsQ + s0 + idx);
        hB = *(const f16x8*)(h + (size_t)pe.y * H + fg * 8);
        eB = *(const f16x8*)(ea_s + (size_t)(s0 + idx) * H + fg * 8);
        vB = ((i + 2) * 8 + ep < c);
      }
#pragma unroll
      for (int j = 0; j < 8; ++j) {
        float m = fmaxf((float)hc[j] + (float)ec[j], 0.0f) + EPS_GEN;
        float ex = vc ? __expf(m) : 0.0f;
        num[j] = fmaf(m, ex, num[j]);
        den[j] += ex;
      }
    }
  }
#pragma unroll
  for (int j = 0; j < 8; ++j) {
    num[j] += __shfl_xor(num[j], 8);
    num[j] += __shfl_xor(num[j], 16);
    num[j] += __shfl_xor(num[j], 32);
    den[j] += __shfl_xor(den[j], 8);
    den[j] += __shfl_xor(den[j], 16);
    den[j] += __shfl_xor(den[j], 32);
  }
  if (ep == 0) {
    f16x8 hs = *(const f16x8*)(h + (size_t)wid * H + fg * 8);
    f16x8 o;
#pragma unroll
    for (int j = 0; j < 8; ++j)
      o[j] = (_Float16)(num[j] / (den[j] + 1e-16f) + (float)hs[j]);
    *(f16x8*)(hsum + (size_t)wid * H + fg * 8) = o;
  }
}

extern "C" void kernel_launch(void* const* d_in, const int* in_sizes, int n_in,
                              void* d_out, int out_size, void* d_ws, size_t ws_size,
                              hipStream_t stream) {
  (void)in_sizes; (void)n_in; (void)out_size; (void)ws_size;
  const float* x      = (const float*)d_in[0];
  const int*   eidx   = (const int*)d_in[1];
  const float* eattr  = (const float*)d_in[2];
  const float* node_W = (const float*)d_in[3];
  const float* node_b = (const float*)d_in[4];
  const float* edge_W = (const float*)d_in[5];
  const float* edge_b = (const float*)d_in[6];
  const float* c1_W1  = (const float*)d_in[7];
  const float* c1_g   = (const float*)d_in[8];
  const float* c1_be  = (const float*)d_in[9];
  const float* c1_W2  = (const float*)d_in[10];
  const float* c2_W1  = (const float*)d_in[11];
  const float* c2_g   = (const float*)d_in[12];
  const float* c2_be  = (const float*)d_in[13];
  const float* c2_W2  = (const float*)d_in[14];
  const float* l1_W   = (const float*)d_in[15];
  const float* l1_b   = (const float*)d_in[16];
  const float* l2_W   = (const float*)d_in[17];
  const float* l2_b   = (const float*)d_in[18];

  const int* src = eidx;
  const int* dst = eidx + N_EDGES;

  char* wsb = (char*)d_ws;
  size_t off = 0;
  _Float16* ea_s  = (_Float16*)(wsb + off); off += (size_t)N_EDGES * H * 2;   // sorted-order ea
  _Float16* hA16  = (_Float16*)(wsb + off); off += (size_t)N_NODES * H * 2;
  _Float16* hB16  = (_Float16*)(wsb + off); off += (size_t)N_NODES * H * 2;
  _Float16* hC16  = (_Float16*)(wsb + off); off += (size_t)N_NODES * H * 2;
  _Float16* hsum16= (_Float16*)(wsb + off); off += (size_t)N_NODES * H * 2;
  _Float16* h3    = (_Float16*)(wsb + off); off += (size_t)N_NODES * H2 * 2;
  float* sums     = (float*)(wsb + off);    off += 256 * 4;
  int* cnt        = (int*)(wsb + off);      off += (size_t)N_NODES * 4;
  int* startA     = (int*)(wsb + off);      off += (size_t)N_NODES * 4;
  int* cursor     = (int*)(wsb + off);      off += (size_t)N_NODES * 4;
  int* bsum       = (int*)(wsb + off);      off += 512 * 4;
  int4* eidsQ     = (int4*)(wsb + off);     off += (size_t)N_EDGES * 16;
  int* posOf      = (int*)(wsb + off);      off += (size_t)N_EDGES * 4;
  _Float16* wE    = (_Float16*)(wsb + off); off += DE * H * 2;
  _Float16* wN    = (_Float16*)(wsb + off); off += DN * H * 2;
  _Float16* w1a   = (_Float16*)(wsb + off); off += H * H2 * 2;
  _Float16* w1b   = (_Float16*)(wsb + off); off += H * H2 * 2;
  _Float16* w2a   = (_Float16*)(wsb + off); off += H2 * H * 2;
  _Float16* w2b   = (_Float16*)(wsb + off); off += H2 * H * 2;
  _Float16* wL1   = (_Float16*)(wsb + off); off += 3 * H * H * 2;
  _Float16* wL2   = (_Float16*)(wsb + off); off += 3 * H * 32 * 2;

  float* h_out  = (float*)d_out;                            // [N,64]
  float* ea_out = (float*)d_out + (size_t)N_NODES * H;      // [E,32]

  constexpr int NB = (N_NODES + 255) / 256;                 // 313 scan blocks

  // ---- one-time weight frag-images (single dispatch) ----
  PrepAll P;
  P.d[0] = {edge_W, wE, DE, H, 0};       // 8 blocks
  P.d[1] = {node_W, wN, DN, H, 8};       // 32
  P.d[2] = {c1_W1, w1a, H, H2, 40};      // 32
  P.d[3] = {c2_W1, w1b, H, H2, 72};      // 32
  P.d[4] = {c1_W2, w2a, H2, H, 104};     // 32
  P.d[5] = {c2_W2, w2b, H2, H, 136};     // 32
  P.d[6] = {l1_W, wL1, 192, H, 168};     // 48
  P.d[7] = {l2_W, wL2, 192, 32, 216};    // 24 -> total 240
  k_prep_all<<<240, 256, 0, stream>>>(P);

  // ---- build CSR (shared by both layers) ----
  hipMemsetAsync(cnt, 0, N_NODES * 4, stream);
  k_hist<<<(N_EDGES + 255) / 256, 256, 0, stream>>>(dst, cnt);
  k_scan_blk<<<NB, 256, 0, stream>>>(cnt, bsum);
  k_scan_top<<<1, 512, 0, stream>>>(bsum, NB);
  k_scan_fin<<<NB, 256, 0, stream>>>(cnt, bsum, startA, cursor);
  k_scatter<<<(N_EDGES + 255) / 256, 256, 0, stream>>>(src, dst, cursor, eidsQ, posOf);

  // ---- encoders (edge encoder: streaming read, scatter-write to sorted ea_s) ----
  k_dense<DE, H, false, false, true, false, true, false, true, false>
      <<<N_EDGES / 64, 256, 0, stream>>>(eattr, wE, edge_b, nullptr, nullptr, nullptr,
                                         posOf, ea_s, nullptr, nullptr);
  k_dense<DN, H, false, false, true, false, true, false, false, false>
      <<<N_NODES / 64, 256, 0, stream>>>(x, wN, node_b, nullptr, nullptr, nullptr,
                                         nullptr, hA16, nullptr, nullptr);

  // ---- conv layer 1 ----
  k_agg_csr<<<(N_NODES + 3) / 4, 256, 0, stream>>>(hA16, ea_s, eidsQ, startA, cnt, hsum16, sums);
  k_dense<H, H2, true, false, false, false, true, false, false, true>
      <<<N_NODES / 64, 256, 0, stream>>>(hsum16, w1a, nullptr, nullptr, nullptr, nullptr,
                                         nullptr, h3, nullptr, sums);
  k_dense<H2, H, true, true, false, true, true, false, false, false>
      <<<N_NODES / 64, 256, 0, stream>>>(h3, w2a, nullptr, sums, c1_g, c1_be,
                                         nullptr, hB16, nullptr, nullptr);
  k_edge_upd_srt<64, _Float16, 8, false>
      <<<N_EDGES / 512, 256, 0, stream>>>(hB16, ea_s, eidsQ, wL1, l1_b, ea_s);  // in-place

  // ---- conv layer 2 ----
  k_agg_csr<<<(N_NODES + 3) / 4, 256, 0, stream>>>(hB16, ea_s, eidsQ, startA, cnt, hsum16, sums);
  k_dense<H, H2, true, false, false, false, true, false, false, true>
      <<<N_NODES / 64, 256, 0, stream>>>(hsum16, w1b, nullptr, nullptr, nullptr, nullptr,
                                         nullptr, h3, nullptr, sums);
  k_dense<H2, H, true, true, false, true, true, true, false, false>
      <<<N_NODES / 64, 256, 0, stream>>>(h3, w2b, nullptr, sums, c2_g, c2_be,
                                         nullptr, hC16, h_out, nullptr);
  k_edge_upd_srt<32, float, 8, true>
      <<<N_EDGES / 512, 256, 0, stream>>>(hC16, ea_s, eidsQ, wL2, l2_b, ea_out);
}

// Round 11
// 602.264 us; speedup vs baseline: 9.2922x; 1.1023x over previous
//
#include <hip/hip_runtime.h>
#include <hip/hip_bf16.h>

#define N_NODES 80000
#define N_EDGES 1280000
constexpr int DN = 128;   // node input dim
constexpr int DE = 32;    // edge input dim
constexpr int H  = 64;    // hidden
constexpr int H2 = 128;   // 2*hidden
constexpr int CSTRIDE = 32;  // padded counter stride (128 B/line) to kill same-line atomic serialization
constexpr float EPS_GEN = 1e-7f;
constexpr float EPS_BN  = 1e-5f;

typedef _Float16 f16x8 __attribute__((ext_vector_type(8)));
typedef _Float16 f16x4 __attribute__((ext_vector_type(4)));
typedef float f32x4 __attribute__((ext_vector_type(4)));

__device__ __forceinline__ void atomAddF(float* p, float v) {
  __hip_atomic_fetch_add(p, v, __ATOMIC_RELAXED, __HIP_MEMORY_SCOPE_AGENT);
}

// ---------------- weight prep (all matrices, one dispatch) ----------------
// frag-image: slab (n2*NK+kk) of 512 halves; elem ((kg*16+m16)*8+j) = W[kk*32+kg*8+j][n2*16+m16]
struct PrepDesc { const float* W; _Float16* img; int K; int OC; int blkStart; };
struct PrepAll { PrepDesc d[8]; };

__global__ void k_prep_all(PrepAll P) {
  int b = blockIdx.x;
  int i = 0;
#pragma unroll
  for (int t = 1; t < 8; ++t)
    if (P.d[t].blkStart <= b) i = t;
  const PrepDesc D = P.d[i];
  int idx = (b - D.blkStart) * 256 + threadIdx.x;
  if (idx >= D.K * D.OC) return;
  int nslabK = D.K >> 5;
  int j = idx & 7, m16 = (idx >> 3) & 15, kg = (idx >> 7) & 3;
  int slab = idx >> 9;
  int kk = slab % nslabK, n2 = slab / nslabK;
  int k = kk * 32 + kg * 8 + j, n = n2 * 16 + m16;
  D.img[idx] = (_Float16)D.W[k * D.OC + n];
}

// ---------------- generic dense MFMA: out[orow,:] = f(A[row,:]) @ W + b ----------------
// SCATOUT: orow = posmap[row]. AFFINE: BN affine from sums. STATS: accumulate col sums/sumsq.
template <int K, int OC, bool IN16, bool AFFINE, bool BIAS,
          bool RELU_OUT, bool OUT16, bool OUT32, bool SCATOUT, bool STATS>
__global__ __launch_bounds__(256) void k_dense(
    const void* __restrict__ Ain, const _Float16* __restrict__ wimg,
    const float* __restrict__ bias, const float* __restrict__ sums,
    const float* __restrict__ g, const float* __restrict__ be,
    const int* __restrict__ posmap,
    _Float16* __restrict__ out16, float* __restrict__ out32,
    float* __restrict__ sums_out) {
  constexpr int NK = K / 32, NF = OC / 16;
  __shared__ float sSC[AFFINE ? H2 : 1], sSH[AFFINE ? H2 : 1];
  __shared__ float sStat[STATS ? 1024 : 1];   // [2][4 waves][128]
  const int tid = threadIdx.x, wv = tid >> 6, lane = tid & 63;
  const int m16 = lane & 15, kg = lane >> 4;
  const int rowbase = blockIdx.x * 64 + wv * 16;
  if constexpr (AFFINE) {
    for (int i = tid; i < H2; i += 256) {
      float mu  = sums[i] * (1.0f / N_NODES);
      float var = sums[H2 + i] * (1.0f / N_NODES) - mu * mu;
      float sc  = rsqrtf(var + EPS_BN) * g[i];
      sSC[i] = sc;
      sSH[i] = be[i] - mu * sc;
    }
    __syncthreads();
  }
  const int arow = rowbase + m16;
  f32x4 acc[NF];
#pragma unroll
  for (int n2 = 0; n2 < NF; ++n2) {
    float bv = BIAS ? bias[n2 * 16 + m16] : 0.0f;
    acc[n2] = (f32x4){bv, bv, bv, bv};
  }
  const _Float16* wp = wimg + (size_t)lane * 8;
#pragma unroll
  for (int kk = 0; kk < NK; ++kk) {
    f16x8 a;
    if constexpr (IN16) {
      const _Float16* ap = (const _Float16*)Ain + (size_t)arow * K + kg * 8 + kk * 32;
      a = *(const f16x8*)ap;
      if constexpr (AFFINE) {
#pragma unroll
        for (int j = 0; j < 8; ++j) {
          int f = kg * 8 + kk * 32 + j;
          float v = fmaxf(fmaf((float)a[j], sSC[f], sSH[f]), 0.0f);
          a[j] = (_Float16)v;
        }
      }
    } else {
      const float* ap = (const float*)Ain + (size_t)arow * K + kg * 8 + kk * 32;
      float4 v0 = *(const float4*)ap;
      float4 v1 = *(const float4*)(ap + 4);
      a = (f16x8){(_Float16)v0.x, (_Float16)v0.y, (_Float16)v0.z, (_Float16)v0.w,
                  (_Float16)v1.x, (_Float16)v1.y, (_Float16)v1.z, (_Float16)v1.w};
    }
#pragma unroll
    for (int n2 = 0; n2 < NF; ++n2) {
      f16x8 bb = *(const f16x8*)(wp + ((size_t)(n2 * NK + kk) << 9));
      acc[n2] = __builtin_amdgcn_mfma_f32_16x16x32_f16(a, bb, acc[n2], 0, 0, 0);
    }
  }
#pragma unroll
  for (int n2 = 0; n2 < NF; ++n2)
#pragma unroll
    for (int r = 0; r < 4; ++r) {
      float o = acc[n2][r];
      if constexpr (RELU_OUT) o = fmaxf(o, 0.0f);
      int orow = rowbase + kg * 4 + r;
      if constexpr (SCATOUT) orow = posmap[orow];
      size_t oi = (size_t)orow * OC + n2 * 16 + m16;
      if constexpr (OUT16) out16[oi] = (_Float16)o;
      if constexpr (OUT32) out32[oi] = o;
    }
  if constexpr (STATS) {
    static_assert(!STATS || NF == 8, "STATS assumes OC==128");
#pragma unroll
    for (int n2 = 0; n2 < NF; ++n2) {
      float s = acc[n2][0] + acc[n2][1] + acc[n2][2] + acc[n2][3];
      float q = acc[n2][0] * acc[n2][0] + acc[n2][1] * acc[n2][1] +
                acc[n2][2] * acc[n2][2] + acc[n2][3] * acc[n2][3];
      s += __shfl_xor(s, 16); s += __shfl_xor(s, 32);
      q += __shfl_xor(q, 16); q += __shfl_xor(q, 32);
      if (kg == 0) {
        sStat[wv * 128 + n2 * 16 + m16] = s;
        sStat[512 + wv * 128 + n2 * 16 + m16] = q;
      }
    }
    __syncthreads();
    {
      int which = tid >> 7, f = tid & 127;
      const float* b0 = sStat + which * 512;
      float v = b0[f] + b0[128 + f] + b0[256 + f] + b0[384 + f];
      atomAddF(&sums_out[which * H2 + f], v);
    }
  }
}

// ---------------- edge update on sorted positions: T tiles/block ----------------
// eidsQ[pos] = (e, src, dst, 0). ea_s streamed (in-place for OC=64); SCAT -> write eout[e].
template <int OC, typename OUT_T, int T, bool SCAT>
__global__ __launch_bounds__(256) void k_edge_upd_srt(
    const _Float16* __restrict__ h, const _Float16* __restrict__ ea,
    const int4* __restrict__ eidsQ,
    const _Float16* __restrict__ wimg, const float* __restrict__ lb,
    OUT_T* __restrict__ eout) {
  constexpr int NF = OC / 16;
  __shared__ _Float16 sWf[NF * 6 * 512];
  __shared__ int sS[T * 64], sD[T * 64];
  __shared__ int sE[SCAT ? T * 64 : 1];
  const int tid = threadIdx.x, wv = tid >> 6, lane = tid & 63;
  const int m16 = lane & 15, kg = lane >> 4;
  const int p0 = blockIdx.x * (T * 64);

  for (int i = tid; i < T * 64; i += 256) {
    int4 t = eidsQ[p0 + i];
    sS[i] = t.y;
    sD[i] = t.z;
    if constexpr (SCAT) sE[i] = t.x;
  }
  {  // stage weights: linear copy (frag-ordered)
    const float4* s4 = (const float4*)wimg;
    float4* d4 = (float4*)sWf;
    constexpr int NV = NF * 6 * 512 / 8;
    for (int i = tid; i < NV; i += 256) d4[i] = s4[i];
  }
  __syncthreads();
  const _Float16* wp = sWf + (size_t)lane * 8;

  float bias_[NF];
#pragma unroll
  for (int n2 = 0; n2 < NF; ++n2) bias_[n2] = lb[n2 * 16 + m16];

  f16x8 FA[6], FB[6];
  auto LOADA = [&](f16x8* F, int l) {        // l = local row (pos - p0)
    const _Float16* a0 = h + (size_t)sS[l] * H + kg * 8;
    const _Float16* a1 = ea + (size_t)(p0 + l) * H + kg * 8;
    const _Float16* a2 = h + (size_t)sD[l] * H + kg * 8;
    F[0] = *(const f16x8*)a0;
    F[1] = *(const f16x8*)(a0 + 32);
    F[2] = *(const f16x8*)a1;
    F[3] = *(const f16x8*)(a1 + 32);
    F[4] = *(const f16x8*)a2;
    F[5] = *(const f16x8*)(a2 + 32);
  };
  auto COMPUTE = [&](const f16x8* F, int l) {
    f32x4 acc[NF];
#pragma unroll
    for (int n2 = 0; n2 < NF; ++n2)
      acc[n2] = (f32x4){bias_[n2], bias_[n2], bias_[n2], bias_[n2]};
#pragma unroll
    for (int kk = 0; kk < 6; ++kk)
#pragma unroll
      for (int n2 = 0; n2 < NF; ++n2) {
        f16x8 bb = *(const f16x8*)(wp + ((n2 * 6 + kk) << 9));
        acc[n2] = __builtin_amdgcn_mfma_f32_16x16x32_f16(F[kk], bb, acc[n2], 0, 0, 0);
      }
    const int lbase = l - m16;
#pragma unroll
    for (int n2 = 0; n2 < NF; ++n2)
#pragma unroll
      for (int r = 0; r < 4; ++r) {
        int lr = lbase + kg * 4 + r;
        int col = n2 * 16 + m16;
        if constexpr (SCAT)
          eout[(size_t)sE[lr] * OC + col] = (OUT_T)acc[n2][r];
        else
          eout[(size_t)(p0 + lr) * OC + col] = (OUT_T)acc[n2][r];
      }
  };

  const int l0 = wv * 16 + m16;
  LOADA(FA, l0);
  if (T > 1) LOADA(FB, l0 + 64);
#pragma unroll
  for (int t = 0; t < T; ++t) {
    if (t & 1) {
      COMPUTE(FB, l0 + t * 64);
      if (t + 2 < T) LOADA(FB, l0 + (t + 2) * 64);
    } else {
      COMPUTE(FA, l0 + t * 64);
      if (t + 2 < T) LOADA(FA, l0 + (t + 2) * 64);
    }
  }
}

// ---------------- CSR build: rank (padded atomics) -> scan -> pure scatter ----------------
__global__ void k_rank(const int* __restrict__ dst, int* cntPad, int* __restrict__ rank) {
  int e = blockIdx.x * blockDim.x + threadIdx.x;
  if (e < N_EDGES)
    rank[e] = atomicAdd(&cntPad[(size_t)dst[e] * CSTRIDE], 1);
}

__global__ void k_scan_blk(const int* __restrict__ cntPad, int* __restrict__ bsum) {
  __shared__ int sh[256];
  int i = blockIdx.x * 256 + threadIdx.x;
  sh[threadIdx.x] = (i < N_NODES) ? cntPad[(size_t)i * CSTRIDE] : 0;
  __syncthreads();
  for (int s = 128; s > 0; s >>= 1) {
    if (threadIdx.x < s) sh[threadIdx.x] += sh[threadIdx.x + s];
    __syncthreads();
  }
  if (threadIdx.x == 0) bsum[blockIdx.x] = sh[0];
}

__global__ void k_scan_top(int* bsum, int nb) {  // 1 block x 512, exclusive scan
  __shared__ int sh[512];
  int t = threadIdx.x;
  int orig = (t < nb) ? bsum[t] : 0;
  sh[t] = orig;
  __syncthreads();
  for (int off = 1; off < 512; off <<= 1) {
    int v = (t >= off) ? sh[t - off] : 0;
    __syncthreads();
    sh[t] += v;
    __syncthreads();
  }
  if (t < nb) bsum[t] = sh[t] - orig;
}

__global__ void k_scan_fin(const int* __restrict__ cntPad, const int* __restrict__ bsum,
                           int* __restrict__ start, int* __restrict__ cntC) {
  __shared__ int sh[256];
  int i = blockIdx.x * 256 + threadIdx.x;
  int t = threadIdx.x;
  int orig = (i < N_NODES) ? cntPad[(size_t)i * CSTRIDE] : 0;
  sh[t] = orig;
  __syncthreads();
  for (int off = 1; off < 256; off <<= 1) {
    int v = (t >= off) ? sh[t - off] : 0;
    __syncthreads();
    sh[t] += v;
    __syncthreads();
  }
  if (i < N_NODES) {
    start[i] = bsum[blockIdx.x] + sh[t] - orig;
    cntC[i] = orig;
  }
}

__global__ void k_scatter(const int* __restrict__ src, const int* __restrict__ dst,
                          const int* __restrict__ rank, const int* __restrict__ start,
                          int4* __restrict__ eidsQ, int* __restrict__ posOf) {
  int e = blockIdx.x * blockDim.x + threadIdx.x;
  if (e < N_EDGES) {
    int d = dst[e];
    int pos = start[d] + rank[e];
    eidsQ[pos] = make_int4(e, src[e], d, 0);   // single 16B scattered store, no atomics
    posOf[e] = pos;                             // coalesced
  }
}

// ---------------- CSR softmax-aggregation: wave/node, 8 edges parallel, CONTIGUOUS ea ----------------
// block 0 also zeroes sums[256] for the following mlp1's STATS accumulation.
__global__ __launch_bounds__(256) void k_agg_csr(
    const _Float16* __restrict__ h, const _Float16* __restrict__ ea_s,
    const int4* __restrict__ eidsQ, const int* __restrict__ start,
    const int* __restrict__ cnt, _Float16* __restrict__ hsum,
    float* __restrict__ sums_clr) {
  if (blockIdx.x == 0) sums_clr[threadIdx.x] = 0.0f;
  const int lane = threadIdx.x & 63;
  const int wid  = (int)((blockIdx.x * blockDim.x + threadIdx.x) >> 6);
  if (wid >= N_NODES) return;
  const int ep = lane >> 3, fg = lane & 7;
  const int s0 = start[wid], c = cnt[wid];
  float num[8] = {0.f, 0.f, 0.f, 0.f, 0.f, 0.f, 0.f, 0.f};
  float den[8] = {0.f, 0.f, 0.f, 0.f, 0.f, 0.f, 0.f, 0.f};
  if (c > 0) {
    const int nit = (c + 7) >> 3;
    int idx = min(ep, c - 1);
    int2 pe = *(const int2*)(eidsQ + s0 + idx);   // (e, src) 8B prefix
    f16x8 hA = *(const f16x8*)(h + (size_t)pe.y * H + fg * 8);
    f16x8 eA = *(const f16x8*)(ea_s + (size_t)(s0 + idx) * H + fg * 8);
    bool vA = (ep < c);
    f16x8 hB = hA, eB = eA;
    bool vB = false;
    if (nit > 1) {
      idx = min(8 + ep, c - 1);
      pe = *(const int2*)(eidsQ + s0 + idx);
      hB = *(const f16x8*)(h + (size_t)pe.y * H + fg * 8);
      eB = *(const f16x8*)(ea_s + (size_t)(s0 + idx) * H + fg * 8);
      vB = (8 + ep < c);
    }
    for (int i = 0; i < nit; ++i) {
      f16x8 hc = hA, ec = eA;
      bool vc = vA;
      hA = hB; eA = eB; vA = vB;
      if (i + 2 < nit) {
        idx = min((i + 2) * 8 + ep, c - 1);
        pe = *(const int2*)(eidsQ + s0 + idx);
        hB = *(const f16x8*)(h + (size_t)pe.y * H + fg * 8);
        eB = *(const f16x8*)(ea_s + (size_t)(s0 + idx) * H + fg * 8);
        vB = ((i + 2) * 8 + ep < c);
      }
#pragma unroll
      for (int j = 0; j < 8; ++j) {
        float m = fmaxf((float)hc[j] + (float)ec[j], 0.0f) + EPS_GEN;
        float ex = vc ? __expf(m) : 0.0f;
        num[j] = fmaf(m, ex, num[j]);
        den[j] += ex;
      }
    }
  }
#pragma unroll
  for (int j = 0; j < 8; ++j) {
    num[j] += __shfl_xor(num[j], 8);
    num[j] += __shfl_xor(num[j], 16);
    num[j] += __shfl_xor(num[j], 32);
    den[j] += __shfl_xor(den[j], 8);
    den[j] += __shfl_xor(den[j], 16);
    den[j] += __shfl_xor(den[j], 32);
  }
  if (ep == 0) {
    f16x8 hs = *(const f16x8*)(h + (size_t)wid * H + fg * 8);
    f16x8 o;
#pragma unroll
    for (int j = 0; j < 8; ++j)
      o[j] = (_Float16)(num[j] / (den[j] + 1e-16f) + (float)hs[j]);
    *(f16x8*)(hsum + (size_t)wid * H + fg * 8) = o;
  }
}

extern "C" void kernel_launch(void* const* d_in, const int* in_sizes, int n_in,
                              void* d_out, int out_size, void* d_ws, size_t ws_size,
                              hipStream_t stream) {
  (void)in_sizes; (void)n_in; (void)out_size; (void)ws_size;
  const float* x      = (const float*)d_in[0];
  const int*   eidx   = (const int*)d_in[1];
  const float* eattr  = (const float*)d_in[2];
  const float* node_W = (const float*)d_in[3];
  const float* node_b = (const float*)d_in[4];
  const float* edge_W = (const float*)d_in[5];
  const float* edge_b = (const float*)d_in[6];
  const float* c1_W1  = (const float*)d_in[7];
  const float* c1_g   = (const float*)d_in[8];
  const float* c1_be  = (const float*)d_in[9];
  const float* c1_W2  = (const float*)d_in[10];
  const float* c2_W1  = (const float*)d_in[11];
  const float* c2_g   = (const float*)d_in[12];
  const float* c2_be  = (const float*)d_in[13];
  const float* c2_W2  = (const float*)d_in[14];
  const float* l1_W   = (const float*)d_in[15];
  const float* l1_b   = (const float*)d_in[16];
  const float* l2_W   = (const float*)d_in[17];
  const float* l2_b   = (const float*)d_in[18];

  const int* src = eidx;
  const int* dst = eidx + N_EDGES;

  char* wsb = (char*)d_ws;
  size_t off = 0;
  _Float16* ea_s  = (_Float16*)(wsb + off); off += (size_t)N_EDGES * H * 2;   // sorted-order ea
  _Float16* hA16  = (_Float16*)(wsb + off); off += (size_t)N_NODES * H * 2;
  _Float16* hB16  = (_Float16*)(wsb + off); off += (size_t)N_NODES * H * 2;
  _Float16* hC16  = (_Float16*)(wsb + off); off += (size_t)N_NODES * H * 2;
  _Float16* hsum16= (_Float16*)(wsb + off); off += (size_t)N_NODES * H * 2;
  _Float16* h3    = (_Float16*)(wsb + off); off += (size_t)N_NODES * H2 * 2;
  float* sums     = (float*)(wsb + off);    off += 256 * 4;
  int* cntPad     = (int*)(wsb + off);      off += (size_t)N_NODES * CSTRIDE * 4;  // 10.24 MB
  int* startA     = (int*)(wsb + off);      off += (size_t)N_NODES * 4;
  int* cntC       = (int*)(wsb + off);      off += (size_t)N_NODES * 4;
  int* bsum       = (int*)(wsb + off);      off += 512 * 4;
  int* rankE      = (int*)(wsb + off);      off += (size_t)N_EDGES * 4;
  int4* eidsQ     = (int4*)(wsb + off);     off += (size_t)N_EDGES * 16;
  int* posOf      = (int*)(wsb + off);      off += (size_t)N_EDGES * 4;
  _Float16* wE    = (_Float16*)(wsb + off); off += DE * H * 2;
  _Float16* wN    = (_Float16*)(wsb + off); off += DN * H * 2;
  _Float16* w1a   = (_Float16*)(wsb + off); off += H * H2 * 2;
  _Float16* w1b   = (_Float16*)(wsb + off); off += H * H2 * 2;
  _Float16* w2a   = (_Float16*)(wsb + off); off += H2 * H * 2;
  _Float16* w2b   = (_Float16*)(wsb + off); off += H2 * H * 2;
  _Float16* wL1   = (_Float16*)(wsb + off); off += 3 * H * H * 2;
  _Float16* wL2   = (_Float16*)(wsb + off); off += 3 * H * 32 * 2;

  float* h_out  = (float*)d_out;                            // [N,64]
  float* ea_out = (float*)d_out + (size_t)N_NODES * H;      // [E,32]

  constexpr int NB = (N_NODES + 255) / 256;                 // 313 scan blocks

  // ---- one-time weight frag-images (single dispatch) ----
  PrepAll P;
  P.d[0] = {edge_W, wE, DE, H, 0};       // 8 blocks
  P.d[1] = {node_W, wN, DN, H, 8};       // 32
  P.d[2] = {c1_W1, w1a, H, H2, 40};      // 32
  P.d[3] = {c2_W1, w1b, H, H2, 72};      // 32
  P.d[4] = {c1_W2, w2a, H2, H, 104};     // 32
  P.d[5] = {c2_W2, w2b, H2, H, 136};     // 32
  P.d[6] = {l1_W, wL1, 192, H, 168};     // 48
  P.d[7] = {l2_W, wL2, 192, 32, 216};    // 24 -> total 240
  k_prep_all<<<240, 256, 0, stream>>>(P);

  // ---- build CSR (padded-counter rank, atomic-free scatter) ----
  hipMemsetAsync(cntPad, 0, (size_t)N_NODES * CSTRIDE * 4, stream);
  k_rank<<<(N_EDGES + 255) / 256, 256, 0, stream>>>(dst, cntPad, rankE);
  k_scan_blk<<<NB, 256, 0, stream>>>(cntPad, bsum);
  k_scan_top<<<1, 512, 0, stream>>>(bsum, NB);
  k_scan_fin<<<NB, 256, 0, stream>>>(cntPad, bsum, startA, cntC);
  k_scatter<<<(N_EDGES + 255) / 256, 256, 0, stream>>>(src, dst, rankE, startA, eidsQ, posOf);

  // ---- encoders (edge encoder: streaming read, scatter-write to sorted ea_s) ----
  k_dense<DE, H, false, false, true, false, true, false, true, false>
      <<<N_EDGES / 64, 256, 0, stream>>>(eattr, wE, edge_b, nullptr, nullptr, nullptr,
                                         posOf, ea_s, nullptr, nullptr);
  k_dense<DN, H, false, false, true, false, true, false, false, false>
      <<<N_NODES / 64, 256, 0, stream>>>(x, wN, node_b, nullptr, nullptr, nullptr,
                                         nullptr, hA16, nullptr, nullptr);

  // ---- conv layer 1 ----
  k_agg_csr<<<(N_NODES + 3) / 4, 256, 0, stream>>>(hA16, ea_s, eidsQ, startA, cntC, hsum16, sums);
  k_dense<H, H2, true, false, false, false, true, false, false, true>
      <<<N_NODES / 64, 256, 0, stream>>>(hsum16, w1a, nullptr, nullptr, nullptr, nullptr,
                                         nullptr, h3, nullptr, sums);
  k_dense<H2, H, true, true, false, true, true, false, false, false>
      <<<N_NODES / 64, 256, 0, stream>>>(h3, w2a, nullptr, sums, c1_g, c1_be,
                                         nullptr, hB16, nullptr, nullptr);
  k_edge_upd_srt<64, _Float16, 16, false>
      <<<N_EDGES / 1024, 256, 0, stream>>>(hB16, ea_s, eidsQ, wL1, l1_b, ea_s);  // in-place

  // ---- conv layer 2 ----
  k_agg_csr<<<(N_NODES + 3) / 4, 256, 0, stream>>>(hB16, ea_s, eidsQ, startA, cntC, hsum16, sums);
  k_dense<H, H2, true, false, false, false, true, false, false, true>
      <<<N_NODES / 64, 256, 0, stream>>>(hsum16, w1b, nullptr, nullptr, nullptr, nullptr,
                                         nullptr, h3, nullptr, sums);
  k_dense<H2, H, true, true, false, true, true, true, false, false>
      <<<N_NODES / 64, 256, 0, stream>>>(h3, w2b, nullptr, sums, c2_g, c2_be,
                                         nullptr, hC16, h_out, nullptr);
  k_edge_upd_srt<32, float, 16, true>
      <<<N_EDGES / 1024, 256, 0, stream>>>(hC16, ea_s, eidsQ, wL2, l2_b, ea_out);
}

// Round 12
// 594.102 us; speedup vs baseline: 9.4199x; 1.0137x over previous
//
#include <hip/hip_runtime.h>
#include <hip/hip_bf16.h>

#define N_NODES 80000
#define N_EDGES 1280000
constexpr int DN = 128;   // node input dim
constexpr int DE = 32;    // edge input dim
constexpr int H  = 64;    // hidden
constexpr int H2 = 128;   // 2*hidden
constexpr int CSTRIDE = 32;  // padded counter stride (128 B/line) to kill same-line atomic serialization
constexpr float EPS_GEN = 1e-7f;
constexpr float EPS_BN  = 1e-5f;

typedef _Float16 f16x8 __attribute__((ext_vector_type(8)));
typedef _Float16 f16x4 __attribute__((ext_vector_type(4)));
typedef float f32x4 __attribute__((ext_vector_type(4)));

__device__ __forceinline__ void atomAddF(float* p, float v) {
  __hip_atomic_fetch_add(p, v, __ATOMIC_RELAXED, __HIP_MEMORY_SCOPE_AGENT);
}

// ---------------- weight prep (all matrices, one dispatch) ----------------
// frag-image: slab (n2*NK+kk) of 512 halves; elem ((kg*16+m16)*8+j) = W[kk*32+kg*8+j][n2*16+m16]
struct PrepDesc { const float* W; _Float16* img; int K; int OC; int blkStart; };
struct PrepAll { PrepDesc d[8]; };

__global__ void k_prep_all(PrepAll P) {
  int b = blockIdx.x;
  int i = 0;
#pragma unroll
  for (int t = 1; t < 8; ++t)
    if (P.d[t].blkStart <= b) i = t;
  const PrepDesc D = P.d[i];
  int idx = (b - D.blkStart) * 256 + threadIdx.x;
  if (idx >= D.K * D.OC) return;
  int nslabK = D.K >> 5;
  int j = idx & 7, m16 = (idx >> 3) & 15, kg = (idx >> 7) & 3;
  int slab = idx >> 9;
  int kk = slab % nslabK, n2 = slab / nslabK;
  int k = kk * 32 + kg * 8 + j, n = n2 * 16 + m16;
  D.img[idx] = (_Float16)D.W[k * D.OC + n];
}

// ---------------- generic dense MFMA: out[orow,:] = f(A[row,:]) @ W + b ----------------
// SCATOUT: orow = posmap[row]. STATS: accumulate col sums/sumsq (use with no OUT -> stats-only).
template <int K, int OC, bool IN16, bool BIAS,
          bool RELU_OUT, bool OUT16, bool OUT32, bool SCATOUT, bool STATS>
__global__ __launch_bounds__(256) void k_dense(
    const void* __restrict__ Ain, const _Float16* __restrict__ wimg,
    const float* __restrict__ bias,
    const int* __restrict__ posmap,
    _Float16* __restrict__ out16, float* __restrict__ out32,
    float* __restrict__ sums_out) {
  constexpr int NK = K / 32, NF = OC / 16;
  __shared__ float sStat[STATS ? 1024 : 1];   // [2][4 waves][128]
  const int tid = threadIdx.x, wv = tid >> 6, lane = tid & 63;
  const int m16 = lane & 15, kg = lane >> 4;
  const int rowbase = blockIdx.x * 64 + wv * 16;
  const int arow = rowbase + m16;
  f32x4 acc[NF];
#pragma unroll
  for (int n2 = 0; n2 < NF; ++n2) {
    float bv = BIAS ? bias[n2 * 16 + m16] : 0.0f;
    acc[n2] = (f32x4){bv, bv, bv, bv};
  }
  const _Float16* wp = wimg + (size_t)lane * 8;
#pragma unroll
  for (int kk = 0; kk < NK; ++kk) {
    f16x8 a;
    if constexpr (IN16) {
      const _Float16* ap = (const _Float16*)Ain + (size_t)arow * K + kg * 8 + kk * 32;
      a = *(const f16x8*)ap;
    } else {
      const float* ap = (const float*)Ain + (size_t)arow * K + kg * 8 + kk * 32;
      float4 v0 = *(const float4*)ap;
      float4 v1 = *(const float4*)(ap + 4);
      a = (f16x8){(_Float16)v0.x, (_Float16)v0.y, (_Float16)v0.z, (_Float16)v0.w,
                  (_Float16)v1.x, (_Float16)v1.y, (_Float16)v1.z, (_Float16)v1.w};
    }
#pragma unroll
    for (int n2 = 0; n2 < NF; ++n2) {
      f16x8 bb = *(const f16x8*)(wp + ((size_t)(n2 * NK + kk) << 9));
      acc[n2] = __builtin_amdgcn_mfma_f32_16x16x32_f16(a, bb, acc[n2], 0, 0, 0);
    }
  }
  if constexpr (OUT16 || OUT32) {
#pragma unroll
    for (int n2 = 0; n2 < NF; ++n2)
#pragma unroll
      for (int r = 0; r < 4; ++r) {
        float o = acc[n2][r];
        if constexpr (RELU_OUT) o = fmaxf(o, 0.0f);
        int orow = rowbase + kg * 4 + r;
        if constexpr (SCATOUT) orow = posmap[orow];
        size_t oi = (size_t)orow * OC + n2 * 16 + m16;
        if constexpr (OUT16) out16[oi] = (_Float16)o;
        if constexpr (OUT32) out32[oi] = o;
      }
  }
  if constexpr (STATS) {
    static_assert(!STATS || NF == 8, "STATS assumes OC==128");
#pragma unroll
    for (int n2 = 0; n2 < NF; ++n2) {
      float s = acc[n2][0] + acc[n2][1] + acc[n2][2] + acc[n2][3];
      float q = acc[n2][0] * acc[n2][0] + acc[n2][1] * acc[n2][1] +
                acc[n2][2] * acc[n2][2] + acc[n2][3] * acc[n2][3];
      s += __shfl_xor(s, 16); s += __shfl_xor(s, 32);
      q += __shfl_xor(q, 16); q += __shfl_xor(q, 32);
      if (kg == 0) {
        sStat[wv * 128 + n2 * 16 + m16] = s;
        sStat[512 + wv * 128 + n2 * 16 + m16] = q;
      }
    }
    __syncthreads();
    {
      int which = tid >> 7, f = tid & 127;
      const float* b0 = sStat + which * 512;
      float v = b0[f] + b0[128 + f] + b0[256 + f] + b0[384 + f];
      atomAddF(&sums_out[which * H2 + f], v);
    }
  }
}

// ---------------- fused BN-MLP: out = relu( relu(bn(hsum@W1)) @ W2 ) ----------------
// Recomputes h3 in registers (no h3 buffer), per-col BN affine on D-layout,
// LDS transpose (pitch 136 halves), then W2 GEMM. OUT16 always; OUT32 optional.
template <bool OUT32>
__global__ __launch_bounds__(256) void k_mlp2f(
    const _Float16* __restrict__ hsum, const _Float16* __restrict__ w1img,
    const _Float16* __restrict__ w2img, const float* __restrict__ sums,
    const float* __restrict__ g, const float* __restrict__ be,
    _Float16* __restrict__ out16, float* __restrict__ out32) {
  constexpr int TP = 136;                 // LDS tile pitch (halves)
  __shared__ float sSC[H2], sSH[H2];
  __shared__ _Float16 sT[64 * TP];        // 17408 B
  const int tid = threadIdx.x, wv = tid >> 6, lane = tid & 63;
  const int m16 = lane & 15, kg = lane >> 4;
  const int rowbase = blockIdx.x * 64 + wv * 16;

  for (int i = tid; i < H2; i += 256) {
    float mu  = sums[i] * (1.0f / N_NODES);
    float var = sums[H2 + i] * (1.0f / N_NODES) - mu * mu;
    float sc  = rsqrtf(var + EPS_BN) * g[i];
    sSC[i] = sc;
    sSH[i] = be[i] - mu * sc;
  }

  // phase 1: h3 = hsum @ W1 (K=64 -> NK=2, OC=128 -> NF=8)
  f32x4 acc1[8];
#pragma unroll
  for (int n2 = 0; n2 < 8; ++n2) acc1[n2] = (f32x4){0.f, 0.f, 0.f, 0.f};
  const _Float16* wp1 = w1img + (size_t)lane * 8;
#pragma unroll
  for (int kk = 0; kk < 2; ++kk) {
    f16x8 a = *(const f16x8*)(hsum + (size_t)(rowbase + m16) * H + kg * 8 + kk * 32);
#pragma unroll
    for (int n2 = 0; n2 < 8; ++n2) {
      f16x8 bb = *(const f16x8*)(wp1 + ((size_t)(n2 * 2 + kk) << 9));
      acc1[n2] = __builtin_amdgcn_mfma_f32_16x16x32_f16(a, bb, acc1[n2], 0, 0, 0);
    }
  }
  __syncthreads();   // sSC/sSH ready
  // phase 2: BN affine + relu on D-layout (col = n2*16+m16 is per-lane constant), write LDS
#pragma unroll
  for (int n2 = 0; n2 < 8; ++n2) {
    int col = n2 * 16 + m16;
    float sc = sSC[col], sh = sSH[col];
#pragma unroll
    for (int r = 0; r < 4; ++r) {
      float v = fmaxf(fmaf(acc1[n2][r], sc, sh), 0.0f);
      sT[(wv * 16 + kg * 4 + r) * TP + col] = (_Float16)v;
    }
  }
  __syncthreads();
  // phase 3: out = sT @ W2 (K=128 -> NK=4, OC=64 -> NF=4)
  f32x4 acc2[4];
#pragma unroll
  for (int n2 = 0; n2 < 4; ++n2) acc2[n2] = (f32x4){0.f, 0.f, 0.f, 0.f};
  const _Float16* wp2 = w2img + (size_t)lane * 8;
#pragma unroll
  for (int kk = 0; kk < 4; ++kk) {
    f16x8 a2 = *(const f16x8*)&sT[(wv * 16 + m16) * TP + kg * 8 + kk * 32];
#pragma unroll
    for (int n2 = 0; n2 < 4; ++n2) {
      f16x8 bb = *(const f16x8*)(wp2 + ((size_t)(n2 * 4 + kk) << 9));
      acc2[n2] = __builtin_amdgcn_mfma_f32_16x16x32_f16(a2, bb, acc2[n2], 0, 0, 0);
    }
  }
#pragma unroll
  for (int n2 = 0; n2 < 4; ++n2)
#pragma unroll
    for (int r = 0; r < 4; ++r) {
      float o = fmaxf(acc2[n2][r], 0.0f);
      size_t oi = (size_t)(rowbase + kg * 4 + r) * H + n2 * 16 + m16;
      out16[oi] = (_Float16)o;
      if constexpr (OUT32) out32[oi] = o;
    }
}

// ---------------- edge update on sorted positions: T tiles/block ----------------
// eidsQ[pos] = (e, src, dst, 0). ea_s streamed (in-place for OC=64); SCAT -> write eout[e].
template <int OC, typename OUT_T, int T, bool SCAT>
__global__ __launch_bounds__(256) void k_edge_upd_srt(
    const _Float16* __restrict__ h, const _Float16* __restrict__ ea,
    const int4* __restrict__ eidsQ,
    const _Float16* __restrict__ wimg, const float* __restrict__ lb,
    OUT_T* __restrict__ eout) {
  constexpr int NF = OC / 16;
  __shared__ _Float16 sWf[NF * 6 * 512];
  __shared__ int sS[T * 64], sD[T * 64];
  __shared__ int sE[SCAT ? T * 64 : 1];
  const int tid = threadIdx.x, wv = tid >> 6, lane = tid & 63;
  const int m16 = lane & 15, kg = lane >> 4;
  const int p0 = blockIdx.x * (T * 64);

  for (int i = tid; i < T * 64; i += 256) {
    int4 t = eidsQ[p0 + i];
    sS[i] = t.y;
    sD[i] = t.z;
    if constexpr (SCAT) sE[i] = t.x;
  }
  {  // stage weights: linear copy (frag-ordered)
    const float4* s4 = (const float4*)wimg;
    float4* d4 = (float4*)sWf;
    constexpr int NV = NF * 6 * 512 / 8;
    for (int i = tid; i < NV; i += 256) d4[i] = s4[i];
  }
  __syncthreads();
  const _Float16* wp = sWf + (size_t)lane * 8;

  float bias_[NF];
#pragma unroll
  for (int n2 = 0; n2 < NF; ++n2) bias_[n2] = lb[n2 * 16 + m16];

  f16x8 FA[6], FB[6];
  auto LOADA = [&](f16x8* F, int l) {        // l = local row (pos - p0)
    const _Float16* a0 = h + (size_t)sS[l] * H + kg * 8;
    const _Float16* a1 = ea + (size_t)(p0 + l) * H + kg * 8;
    const _Float16* a2 = h + (size_t)sD[l] * H + kg * 8;
    F[0] = *(const f16x8*)a0;
    F[1] = *(const f16x8*)(a0 + 32);
    F[2] = *(const f16x8*)a1;
    F[3] = *(const f16x8*)(a1 + 32);
    F[4] = *(const f16x8*)a2;
    F[5] = *(const f16x8*)(a2 + 32);
  };
  auto COMPUTE = [&](const f16x8* F, int l) {
    f32x4 acc[NF];
#pragma unroll
    for (int n2 = 0; n2 < NF; ++n2)
      acc[n2] = (f32x4){bias_[n2], bias_[n2], bias_[n2], bias_[n2]};
#pragma unroll
    for (int kk = 0; kk < 6; ++kk)
#pragma unroll
      for (int n2 = 0; n2 < NF; ++n2) {
        f16x8 bb = *(const f16x8*)(wp + ((n2 * 6 + kk) << 9));
        acc[n2] = __builtin_amdgcn_mfma_f32_16x16x32_f16(F[kk], bb, acc[n2], 0, 0, 0);
      }
    const int lbase = l - m16;
#pragma unroll
    for (int n2 = 0; n2 < NF; ++n2)
#pragma unroll
      for (int r = 0; r < 4; ++r) {
        int lr = lbase + kg * 4 + r;
        int col = n2 * 16 + m16;
        if constexpr (SCAT)
          eout[(size_t)sE[lr] * OC + col] = (OUT_T)acc[n2][r];
        else
          eout[(size_t)(p0 + lr) * OC + col] = (OUT_T)acc[n2][r];
      }
  };

  const int l0 = wv * 16 + m16;
  LOADA(FA, l0);
  if (T > 1) LOADA(FB, l0 + 64);
#pragma unroll
  for (int t = 0; t < T; ++t) {
    if (t & 1) {
      COMPUTE(FB, l0 + t * 64);
      if (t + 2 < T) LOADA(FB, l0 + (t + 2) * 64);
    } else {
      COMPUTE(FA, l0 + t * 64);
      if (t + 2 < T) LOADA(FA, l0 + (t + 2) * 64);
    }
  }
}

// ---------------- CSR build: rank (padded atomics) -> scan -> pure scatter ----------------
__global__ void k_rank(const int* __restrict__ dst, int* cntPad, int* __restrict__ rank) {
  int e = blockIdx.x * blockDim.x + threadIdx.x;
  if (e < N_EDGES)
    rank[e] = atomicAdd(&cntPad[(size_t)dst[e] * CSTRIDE], 1);
}

__global__ void k_scan_blk(const int* __restrict__ cntPad, int* __restrict__ bsum) {
  __shared__ int sh[256];
  int i = blockIdx.x * 256 + threadIdx.x;
  sh[threadIdx.x] = (i < N_NODES) ? cntPad[(size_t)i * CSTRIDE] : 0;
  __syncthreads();
  for (int s = 128; s > 0; s >>= 1) {
    if (threadIdx.x < s) sh[threadIdx.x] += sh[threadIdx.x + s];
    __syncthreads();
  }
  if (threadIdx.x == 0) bsum[blockIdx.x] = sh[0];
}

__global__ void k_scan_top(int* bsum, int nb) {  // 1 block x 512, exclusive scan
  __shared__ int sh[512];
  int t = threadIdx.x;
  int orig = (t < nb) ? bsum[t] : 0;
  sh[t] = orig;
  __syncthreads();
  for (int off = 1; off < 512; off <<= 1) {
    int v = (t >= off) ? sh[t - off] : 0;
    __syncthreads();
    sh[t] += v;
    __syncthreads();
  }
  if (t < nb) bsum[t] = sh[t] - orig;
}

__global__ void k_scan_fin(const int* __restrict__ cntPad, const int* __restrict__ bsum,
                           int* __restrict__ start, int* __restrict__ cntC) {
  __shared__ int sh[256];
  int i = blockIdx.x * 256 + threadIdx.x;
  int t = threadIdx.x;
  int orig = (i < N_NODES) ? cntPad[(size_t)i * CSTRIDE] : 0;
  sh[t] = orig;
  __syncthreads();
  for (int off = 1; off < 256; off <<= 1) {
    int v = (t >= off) ? sh[t - off] : 0;
    __syncthreads();
    sh[t] += v;
    __syncthreads();
  }
  if (i < N_NODES) {
    start[i] = bsum[blockIdx.x] + sh[t] - orig;
    cntC[i] = orig;
  }
}

__global__ void k_scatter(const int* __restrict__ src, const int* __restrict__ dst,
                          const int* __restrict__ rank, const int* __restrict__ start,
                          int4* __restrict__ eidsQ, int* __restrict__ posOf) {
  int e = blockIdx.x * blockDim.x + threadIdx.x;
  if (e < N_EDGES) {
    int d = dst[e];
    int pos = start[d] + rank[e];
    eidsQ[pos] = make_int4(e, src[e], d, 0);   // single 16B scattered store, no atomics
    posOf[e] = pos;                             // coalesced
  }
}

// ---------------- CSR softmax-aggregation: wave/node, 8 edges parallel, CONTIGUOUS ea ----------------
// block 0 also zeroes sums[256] for the following stats pass.
__global__ __launch_bounds__(256) void k_agg_csr(
    const _Float16* __restrict__ h, const _Float16* __restrict__ ea_s,
    const int4* __restrict__ eidsQ, const int* __restrict__ start,
    const int* __restrict__ cnt, _Float16* __restrict__ hsum,
    float* __restrict__ sums_clr) {
  if (blockIdx.x == 0) sums_clr[threadIdx.x] = 0.0f;
  const int lane = threadIdx.x & 63;
  const int wid  = (int)((blockIdx.x * blockDim.x + threadIdx.x) >> 6);
  if (wid >= N_NODES) return;
  const int ep = lane >> 3, fg = lane & 7;
  const int s0 = start[wid], c = cnt[wid];
  float num[8] = {0.f, 0.f, 0.f, 0.f, 0.f, 0.f, 0.f, 0.f};
  float den[8] = {0.f, 0.f, 0.f, 0.f, 0.f, 0.f, 0.f, 0.f};
  if (c > 0) {
    const int nit = (c + 7) >> 3;
    int idx = min(ep, c - 1);
    int2 pe = *(const int2*)(eidsQ + s0 + idx);   // (e, src) 8B prefix
    f16x8 hA = *(const f16x8*)(h + (size_t)pe.y * H + fg * 8);
    f16x8 eA = *(const f16x8*)(ea_s + (size_t)(s0 + idx) * H + fg * 8);
    bool vA = (ep < c);
    f16x8 hB = hA, eB = eA;
    bool vB = false;
    if (nit > 1) {
      idx = min(8 + ep, c - 1);
      pe = *(const int2*)(eidsQ + s0 + idx);
      hB = *(const f16x8*)(h + (size_t)pe.y * H + fg * 8);
      eB = *(const f16x8*)(ea_s + (size_t)(s0 + idx) * H + fg * 8);
      vB = (8 + ep < c);
    }
    for (int i = 0; i < nit; ++i) {
      f16x8 hc = hA, ec = eA;
      bool vc = vA;
      hA = hB; eA = eB; vA = vB;
      if (i + 2 < nit) {
        idx = min((i + 2) * 8 + ep, c - 1);
        pe = *(const int2*)(eidsQ + s0 + idx);
        hB = *(const f16x8*)(h + (size_t)pe.y * H + fg * 8);
        eB = *(const f16x8*)(ea_s + (size_t)(s0 + idx) * H + fg * 8);
        vB = ((i + 2) * 8 + ep < c);
      }
#pragma unroll
      for (int j = 0; j < 8; ++j) {
        float m = fmaxf((float)hc[j] + (float)ec[j], 0.0f) + EPS_GEN;
        float ex = vc ? __expf(m) : 0.0f;
        num[j] = fmaf(m, ex, num[j]);
        den[j] += ex;
      }
    }
  }
#pragma unroll
  for (int j = 0; j < 8; ++j) {
    num[j] += __shfl_xor(num[j], 8);
    num[j] += __shfl_xor(num[j], 16);
    num[j] += __shfl_xor(num[j], 32);
    den[j] += __shfl_xor(den[j], 8);
    den[j] += __shfl_xor(den[j], 16);
    den[j] += __shfl_xor(den[j], 32);
  }
  if (ep == 0) {
    f16x8 hs = *(const f16x8*)(h + (size_t)wid * H + fg * 8);
    f16x8 o;
#pragma unroll
    for (int j = 0; j < 8; ++j)
      o[j] = (_Float16)(num[j] / (den[j] + 1e-16f) + (float)hs[j]);
    *(f16x8*)(hsum + (size_t)wid * H + fg * 8) = o;
  }
}

extern "C" void kernel_launch(void* const* d_in, const int* in_sizes, int n_in,
                              void* d_out, int out_size, void* d_ws, size_t ws_size,
                              hipStream_t stream) {
  (void)in_sizes; (void)n_in; (void)out_size; (void)ws_size;
  const float* x      = (const float*)d_in[0];
  const int*   eidx   = (const int*)d_in[1];
  const float* eattr  = (const float*)d_in[2];
  const float* node_W = (const float*)d_in[3];
  const float* node_b = (const float*)d_in[4];
  const float* edge_W = (const float*)d_in[5];
  const float* edge_b = (const float*)d_in[6];
  const float* c1_W1  = (const float*)d_in[7];
  const float* c1_g   = (const float*)d_in[8];
  const float* c1_be  = (const float*)d_in[9];
  const float* c1_W2  = (const float*)d_in[10];
  const float* c2_W1  = (const float*)d_in[11];
  const float* c2_g   = (const float*)d_in[12];
  const float* c2_be  = (const float*)d_in[13];
  const float* c2_W2  = (const float*)d_in[14];
  const float* l1_W   = (const float*)d_in[15];
  const float* l1_b   = (const float*)d_in[16];
  const float* l2_W   = (const float*)d_in[17];
  const float* l2_b   = (const float*)d_in[18];

  const int* src = eidx;
  const int* dst = eidx + N_EDGES;

  char* wsb = (char*)d_ws;
  size_t off = 0;
  _Float16* ea_s  = (_Float16*)(wsb + off); off += (size_t)N_EDGES * H * 2;   // sorted-order ea
  _Float16* hA16  = (_Float16*)(wsb + off); off += (size_t)N_NODES * H * 2;
  _Float16* hB16  = (_Float16*)(wsb + off); off += (size_t)N_NODES * H * 2;
  _Float16* hC16  = (_Float16*)(wsb + off); off += (size_t)N_NODES * H * 2;
  _Float16* hsum16= (_Float16*)(wsb + off); off += (size_t)N_NODES * H * 2;
  float* sums     = (float*)(wsb + off);    off += 256 * 4;
  int* cntPad     = (int*)(wsb + off);      off += (size_t)N_NODES * CSTRIDE * 4;  // 10.24 MB
  int* startA     = (int*)(wsb + off);      off += (size_t)N_NODES * 4;
  int* cntC       = (int*)(wsb + off);      off += (size_t)N_NODES * 4;
  int* bsum       = (int*)(wsb + off);      off += 512 * 4;
  int* rankE      = (int*)(wsb + off);      off += (size_t)N_EDGES * 4;
  int4* eidsQ     = (int4*)(wsb + off);     off += (size_t)N_EDGES * 16;
  int* posOf      = (int*)(wsb + off);      off += (size_t)N_EDGES * 4;
  _Float16* wE    = (_Float16*)(wsb + off); off += DE * H * 2;
  _Float16* wN    = (_Float16*)(wsb + off); off += DN * H * 2;
  _Float16* w1a   = (_Float16*)(wsb + off); off += H * H2 * 2;
  _Float16* w1b   = (_Float16*)(wsb + off); off += H * H2 * 2;
  _Float16* w2a   = (_Float16*)(wsb + off); off += H2 * H * 2;
  _Float16* w2b   = (_Float16*)(wsb + off); off += H2 * H * 2;
  _Float16* wL1   = (_Float16*)(wsb + off); off += 3 * H * H * 2;
  _Float16* wL2   = (_Float16*)(wsb + off); off += 3 * H * 32 * 2;

  float* h_out  = (float*)d_out;                            // [N,64]
  float* ea_out = (float*)d_out + (size_t)N_NODES * H;      // [E,32]

  constexpr int NB = (N_NODES + 255) / 256;                 // 313 scan blocks

  // ---- one-time weight frag-images (single dispatch) ----
  PrepAll P;
  P.d[0] = {edge_W, wE, DE, H, 0};       // 8 blocks
  P.d[1] = {node_W, wN, DN, H, 8};       // 32
  P.d[2] = {c1_W1, w1a, H, H2, 40};      // 32
  P.d[3] = {c2_W1, w1b, H, H2, 72};      // 32
  P.d[4] = {c1_W2, w2a, H2, H, 104};     // 32
  P.d[5] = {c2_W2, w2b, H2, H, 136};     // 32
  P.d[6] = {l1_W, wL1, 192, H, 168};     // 48
  P.d[7] = {l2_W, wL2, 192, 32, 216};    // 24 -> total 240
  k_prep_all<<<240, 256, 0, stream>>>(P);

  // ---- build CSR (padded-counter rank, atomic-free scatter) ----
  hipMemsetAsync(cntPad, 0, (size_t)N_NODES * CSTRIDE * 4, stream);
  k_rank<<<(N_EDGES + 255) / 256, 256, 0, stream>>>(dst, cntPad, rankE);
  k_scan_blk<<<NB, 256, 0, stream>>>(cntPad, bsum);
  k_scan_top<<<1, 512, 0, stream>>>(bsum, NB);
  k_scan_fin<<<NB, 256, 0, stream>>>(cntPad, bsum, startA, cntC);
  k_scatter<<<(N_EDGES + 255) / 256, 256, 0, stream>>>(src, dst, rankE, startA, eidsQ, posOf);

  // ---- encoders (edge encoder: streaming read, scatter-write to sorted ea_s) ----
  k_dense<DE, H, false, true, false, true, false, true, false>
      <<<N_EDGES / 64, 256, 0, stream>>>(eattr, wE, edge_b,
                                         posOf, ea_s, nullptr, nullptr);
  k_dense<DN, H, false, true, false, true, false, false, false>
      <<<N_NODES / 64, 256, 0, stream>>>(x, wN, node_b,
                                         nullptr, hA16, nullptr, nullptr);

  // ---- conv layer 1 ----
  k_agg_csr<<<(N_NODES + 3) / 4, 256, 0, stream>>>(hA16, ea_s, eidsQ, startA, cntC, hsum16, sums);
  k_dense<H, H2, true, false, false, false, false, false, true>   // stats-only
      <<<N_NODES / 64, 256, 0, stream>>>(hsum16, w1a, nullptr,
                                         nullptr, nullptr, nullptr, sums);
  k_mlp2f<false><<<N_NODES / 64, 256, 0, stream>>>(hsum16, w1a, w2a, sums,
                                                   c1_g, c1_be, hB16, nullptr);
  k_edge_upd_srt<64, _Float16, 16, false>
      <<<N_EDGES / 1024, 256, 0, stream>>>(hB16, ea_s, eidsQ, wL1, l1_b, ea_s);  // in-place

  // ---- conv layer 2 ----
  k_agg_csr<<<(N_NODES + 3) / 4, 256, 0, stream>>>(hB16, ea_s, eidsQ, startA, cntC, hsum16, sums);
  k_dense<H, H2, true, false, false, false, false, false, true>   // stats-only
      <<<N_NODES / 64, 256, 0, stream>>>(hsum16, w1b, nullptr,
                                         nullptr, nullptr, nullptr, sums);
  k_mlp2f<true><<<N_NODES / 64, 256, 0, stream>>>(hsum16, w1b, w2b, sums,
                                                  c2_g, c2_be, hC16, h_out);
  k_edge_upd_srt<32, float, 16, true>
      <<<N_EDGES / 1024, 256, 0, stream>>>(hC16, ea_s, eidsQ, wL2, l2_b, ea_out);
}